// Round 2
// baseline (470.692 us; speedup 1.0000x reference)
//
#include <hip/hip_runtime.h>
#include <hip/hip_bf16.h>
#include <math.h>

// Problem constants
#define HW_N   16384
#define DIM    256
#define NSEL   4096
#define NQ     1024
#define NHEAD  8
#define HD     32
#define NP_    25
#define DFF_   1024

// Workspace layout (float offsets). ~76 MB total.
#define OFF_SELREF  8448LL          // 2*4096*7
#define OFF_SELSRC  65792LL         // 2*4096*256
#define OFF_SELPOS  2162944LL       // 2*4096*256 (later reused as boxout)
#define OFF_QUERY   4260096LL       // 2*4096*256 (later reused as src2)
#define OFF_BIG     6357248LL       // vproj bf16 [0,4194304) then ffnt bf16 same slot
#define OFF_WBF     10551552LL      // OFF_BIG+4194304: bf16 weights, 1079296 bf16
#define OFF_F       14745856LL      // multi-use region, 5177344 floats

__device__ __forceinline__ unsigned int f2s(float f) {
    unsigned int u = __float_as_uint(f);
    return (u & 0x80000000u) ? ~u : (u | 0x80000000u);
}

typedef __bf16 bf16x8 __attribute__((ext_vector_type(8)));
typedef __bf16 bf16x4 __attribute__((ext_vector_type(4)));
typedef float  f32x4  __attribute__((ext_vector_type(4)));

// ============ weight preconversion: 9 fp32 matrices -> one bf16 pool ============
// Segments (elems): in_proj 196608 | mha_out 65536 | value 65536 | lin_attn 51200
// | lin_box 8192 | samp_off 102400 | ca_out 65536 | lin1 262144 | lin2 262144
extern "C" __global__ __launch_bounds__(256)
void wcvt_kernel(const float* __restrict__ s0, const float* __restrict__ s1,
                 const float* __restrict__ s2, const float* __restrict__ s3,
                 const float* __restrict__ s4, const float* __restrict__ s5,
                 const float* __restrict__ s6, const float* __restrict__ s7,
                 const float* __restrict__ s8, __hip_bfloat16* __restrict__ dst) {
    const long long g = (long long)blockIdx.x * 256 + threadIdx.x;
    const float* s; long long base;
    if      (g < 196608)  { s = s0; base = 0; }
    else if (g < 262144)  { s = s1; base = 196608; }
    else if (g < 327680)  { s = s2; base = 262144; }
    else if (g < 378880)  { s = s3; base = 327680; }
    else if (g < 387072)  { s = s4; base = 378880; }
    else if (g < 489472)  { s = s5; base = 387072; }
    else if (g < 555008)  { s = s6; base = 489472; }
    else if (g < 817152)  { s = s7; base = 555008; }
    else                  { s = s8; base = 817152; }
    dst[g] = __float2bfloat16(s[g - base]);
}

// ================= top-k, grid-parallel (4 kernels) =================
extern "C" __global__ __launch_bounds__(512)
void topk_hist_kernel(const float* __restrict__ score, unsigned int* __restrict__ hist) {
    const int t = threadIdx.x, bx = blockIdx.x, bb = blockIdx.y;
    const int i = bx * 512 + t;
    unsigned int u = f2s(score[(long long)bb * HW_N + i]);
    atomicAdd(&hist[bb * 8192 + (u >> 19)], 1u);
}

extern "C" __global__ __launch_bounds__(1024)
void topk_scan_kernel(const unsigned int* __restrict__ hist, unsigned int* __restrict__ ctrl) {
    __shared__ unsigned int scan[1024];
    const int t = threadIdx.x, bb = blockIdx.x;
    unsigned int loc[8]; unsigned int lsum = 0u;
    #pragma unroll
    for (int k = 0; k < 8; ++k) { loc[k] = hist[bb * 8192 + t * 8 + k]; lsum += loc[k]; }
    scan[t] = lsum;
    __syncthreads();
    for (int off = 1; off < 1024; off <<= 1) {
        unsigned int v = (t + off < 1024) ? scan[t + off] : 0u;
        __syncthreads();
        scan[t] += v;
        __syncthreads();
    }
    unsigned int nxt = (t < 1023) ? scan[t + 1] : 0u;
    unsigned int run = nxt;
    for (int k = 7; k >= 0; --k) {
        run += loc[k];
        unsigned int above = run - loc[k];
        if (run >= 1024u && above < 1024u) { ctrl[bb * 16 + 0] = (unsigned)(t * 8 + k); ctrl[bb * 16 + 1] = 1024u - above; }
        if (run >= 4096u && above < 4096u) { ctrl[bb * 16 + 2] = (unsigned)(t * 8 + k); ctrl[bb * 16 + 3] = 4096u - above; }
    }
}

extern "C" __global__ __launch_bounds__(1024)
void topk_collect_kernel(const float* __restrict__ score, unsigned int* __restrict__ ctrl,
                         unsigned long long* __restrict__ list1,
                         unsigned long long* __restrict__ list2) {
    const int t = threadIdx.x, bx = blockIdx.x, bb = blockIdx.y;
    const int i = bx * 1024 + t;
    const unsigned int T1 = ctrl[bb * 16 + 0], T2 = ctrl[bb * 16 + 2];
    unsigned int u = f2s(score[(long long)bb * HW_N + i]);
    unsigned int bin = u >> 19;
    unsigned long long key = ((unsigned long long)u << 32) | (unsigned int)(~(unsigned int)i);
    if (bin == T1) {
        unsigned int p = atomicAdd(&ctrl[bb * 16 + 4], 1u);
        if (p < 2048u) list1[bb * 2048 + p] = key;
    }
    if (bin == T2 && T2 != T1) {
        unsigned int p = atomicAdd(&ctrl[bb * 16 + 5], 1u);
        if (p < 2048u) list2[bb * 2048 + p] = key;
    }
}

extern "C" __global__ __launch_bounds__(1024)
void topk_classify_kernel(const float* __restrict__ score, unsigned int* __restrict__ ctrl,
                          const unsigned long long* __restrict__ list1,
                          const unsigned long long* __restrict__ list2,
                          int* __restrict__ idx_out) {
    __shared__ unsigned int cA, cB, baseA, baseB;
    const int t = threadIdx.x, bx = blockIdx.x, bb = blockIdx.y;
    const int i = bx * 1024 + t;
    if (t == 0) { cA = 0u; cB = 0u; }
    __syncthreads();
    const unsigned int T1 = ctrl[bb * 16 + 0], need1 = ctrl[bb * 16 + 1];
    const unsigned int T2 = ctrl[bb * 16 + 2], need2 = ctrl[bb * 16 + 3];
    const unsigned int c1 = min(ctrl[bb * 16 + 4], 2048u);
    const unsigned int c2 = min(ctrl[bb * 16 + 5], 2048u);
    unsigned int u = f2s(score[(long long)bb * HW_N + i]);
    unsigned int bin = u >> 19;
    unsigned long long key = ((unsigned long long)u << 32) | (unsigned int)(~(unsigned int)i);
    bool inA = false, inB = false;
    if (bin > T1) {
        inA = true;
    } else if (bin == T1) {
        unsigned int r = 0;
        for (unsigned int q = 0; q < c1; ++q) r += (list1[bb * 2048 + q] > key) ? 1u : 0u;
        if (r < need1) inA = true;
        else if (T2 == T1) inB = (r < need2);
        else inB = true;
    } else if (bin > T2) {
        inB = true;
    } else if (bin == T2) {
        unsigned int r = 0;
        for (unsigned int q = 0; q < c2; ++q) r += (list2[bb * 2048 + q] > key) ? 1u : 0u;
        inB = (r < need2);
    }
    unsigned int sA = 0u, sB = 0u;
    if (inA) sA = atomicAdd(&cA, 1u);
    if (inB) sB = atomicAdd(&cB, 1u);
    __syncthreads();
    if (t == 0) {
        baseA = atomicAdd(&ctrl[bb * 16 + 6], cA);
        baseB = atomicAdd(&ctrl[bb * 16 + 7], cB);
    }
    __syncthreads();
    if (inA) idx_out[bb * NSEL + baseA + sA] = i;
    if (inB) idx_out[bb * NSEL + 1024 + baseB + sB] = i;
}

// ---------------- gather selected rows ----------------
extern "C" __global__ __launch_bounds__(256)
void gather_kernel(const float* __restrict__ src, const float* __restrict__ pos,
                   const float* __restrict__ refw, const int* __restrict__ idx,
                   float* __restrict__ selsrc, float* __restrict__ selpos,
                   float* __restrict__ selref, float* __restrict__ qk) {
    const int s = blockIdx.x, bb = blockIdx.y, t = threadIdx.x;
    const int i = idx[bb * NSEL + s];
    const long long so = ((long long)(bb * NSEL + s)) * DIM;
    const long long go = ((long long)(bb * HW_N + i)) * DIM;
    float sv = src[go + t], pv = pos[go + t];
    selsrc[so + t] = sv;
    selpos[so + t] = pv;
    if (s < NQ) qk[((long long)(bb * NQ + s)) * DIM + t] = sv + pv;
    if (t < 7)
        selref[(long long)(bb * NSEL + s) * 7 + t] = refw[(long long)(bb * HW_N + i) * 7 + t];
}

// ---------------- bf16 MFMA GEMM: C = act(A @ W^T + bias) ----------------
// W: PRE-CONVERTED bf16 [N][K]. A: fp32 (amode 0) or bf16 (amode 1), [z][M][K].
// omode: 0 fp32 out; 1 bf16 flat; 2 bf16 transposed (col*M+row);
//        3 bf16 head-planar: off = zoff + ((col>>5)*16384 + row)*32 + (col&31).
extern "C" __global__ __launch_bounds__(256)
void gemm_kernel(const void* __restrict__ Avp, long long sA,
                 const __hip_bfloat16* __restrict__ W, const float* __restrict__ bias,
                 float* __restrict__ C, long long sC,
                 int M, int N, int K, int relu, int omode, int amode) {
    __shared__ __hip_bfloat16 As[64][72];
    __shared__ __hip_bfloat16 Ws[64][72];
    const int t = threadIdx.x;
    const int n0 = blockIdx.x * 64, m0 = blockIdx.y * 64;
    const long long zoff = (long long)blockIdx.z * sC;
    const int lane = t & 63, wv = t >> 6;
    const int mw = (wv >> 1) * 32, nw = (wv & 1) * 32;
    const int fr = lane & 15;
    const int fk = (lane >> 4) * 8;
    const int sr = t >> 2;
    const int sk = (t & 3) * 16;

    f32x4 acc[2][2];
    #pragma unroll
    for (int i = 0; i < 2; ++i)
        #pragma unroll
        for (int j = 0; j < 2; ++j) acc[i][j] = {0.f, 0.f, 0.f, 0.f};

    const bool wok = (n0 + sr) < N;
    for (int k0 = 0; k0 < K; k0 += 64) {
        // stage W: straight 32B bf16 copy
        uint4 wa = make_uint4(0u, 0u, 0u, 0u), wb = make_uint4(0u, 0u, 0u, 0u);
        if (wok) {
            const __hip_bfloat16* wp = W + (long long)(n0 + sr) * K + k0 + sk;
            wa = *(const uint4*)wp;
            wb = *(const uint4*)(wp + 8);
        }
        if (amode) {
            const __hip_bfloat16* ap = (const __hip_bfloat16*)Avp
                + (long long)blockIdx.z * sA + (long long)(m0 + sr) * K + k0 + sk;
            uint4 aa = *(const uint4*)ap;
            uint4 ab = *(const uint4*)(ap + 8);
            __syncthreads();
            *(uint4*)&As[sr][sk] = aa;
            *(uint4*)&As[sr][sk + 8] = ab;
            *(uint4*)&Ws[sr][sk] = wa;
            *(uint4*)&Ws[sr][sk + 8] = wb;
        } else {
            const float* ap = (const float*)Avp
                + (long long)blockIdx.z * sA + (long long)(m0 + sr) * K + k0 + sk;
            float av[16];
            #pragma unroll
            for (int q = 0; q < 4; ++q) {
                float4 v = *(const float4*)(ap + q * 4);
                av[q * 4 + 0] = v.x; av[q * 4 + 1] = v.y; av[q * 4 + 2] = v.z; av[q * 4 + 3] = v.w;
            }
            __syncthreads();
            #pragma unroll
            for (int q = 0; q < 16; ++q) As[sr][sk + q] = __float2bfloat16(av[q]);
            *(uint4*)&Ws[sr][sk] = wa;
            *(uint4*)&Ws[sr][sk + 8] = wb;
        }
        __syncthreads();
        #pragma unroll
        for (int kk = 0; kk < 64; kk += 32) {
            bf16x8 a0 = *(const bf16x8*)&As[mw + fr][kk + fk];
            bf16x8 a1 = *(const bf16x8*)&As[mw + 16 + fr][kk + fk];
            bf16x8 b0 = *(const bf16x8*)&Ws[nw + fr][kk + fk];
            bf16x8 b1 = *(const bf16x8*)&Ws[nw + 16 + fr][kk + fk];
            acc[0][0] = __builtin_amdgcn_mfma_f32_16x16x32_bf16(a0, b0, acc[0][0], 0, 0, 0);
            acc[0][1] = __builtin_amdgcn_mfma_f32_16x16x32_bf16(a0, b1, acc[0][1], 0, 0, 0);
            acc[1][0] = __builtin_amdgcn_mfma_f32_16x16x32_bf16(a1, b0, acc[1][0], 0, 0, 0);
            acc[1][1] = __builtin_amdgcn_mfma_f32_16x16x32_bf16(a1, b1, acc[1][1], 0, 0, 0);
        }
    }
    const int crow = (lane >> 4) * 4;
    #pragma unroll
    for (int mi = 0; mi < 2; ++mi) {
        #pragma unroll
        for (int ni = 0; ni < 2; ++ni) {
            const int col = n0 + nw + ni * 16 + fr;
            if (col < N) {
                const float bv = bias ? bias[col] : 0.f;
                #pragma unroll
                for (int r = 0; r < 4; ++r) {
                    const int row = m0 + mw + mi * 16 + crow + r;
                    float v = acc[mi][ni][r] + bv;
                    if (relu) v = fmaxf(v, 0.f);
                    if (omode == 0) {
                        C[zoff + (long long)row * N + col] = v;
                    } else if (omode == 1) {
                        ((__hip_bfloat16*)C)[zoff + (long long)row * N + col] = __float2bfloat16(v);
                    } else if (omode == 2) {
                        ((__hip_bfloat16*)C)[zoff + (long long)col * M + row] = __float2bfloat16(v);
                    } else {
                        ((__hip_bfloat16*)C)[zoff + ((long long)(col >> 5) * 16384 + row) * 32 + (col & 31)]
                            = __float2bfloat16(v);
                    }
                }
            }
        }
    }
}

// ---------------- MHA via MFMA: 16 queries/block, S & softmax in registers ----
extern "C" __global__ __launch_bounds__(256)
void attn_kernel(const __hip_bfloat16* __restrict__ qkb,
                 const __hip_bfloat16* __restrict__ vT,
                 float* __restrict__ attout) {
    __shared__ __hip_bfloat16 pb[16][1048];
    __shared__ float redm[4][16];
    __shared__ float reds[4][16];
    __shared__ float redo[4][16][33];
    const int t = threadIdx.x;
    const int qt = blockIdx.x, h = blockIdx.y, bb = blockIdx.z;
    const int q0 = qt * 16;
    const int lane = t & 63, wv = t >> 6;
    const int fr = lane & 15, g = lane >> 4;
    const int kbase = wv * 256;
    const float scale = 0.17677669529663687f;

    bf16x8 qfrag = *(const bf16x8*)(qkb + ((long long)(bb * NQ + q0 + fr)) * 512 + h * HD + g * 8);

    f32x4 sfr[16];
    #pragma unroll
    for (int kt = 0; kt < 16; ++kt) {
        const int key0 = kbase + kt * 16;
        bf16x8 kf = *(const bf16x8*)(qkb + ((long long)(bb * NQ + key0 + fr)) * 512 + 256 + h * HD + g * 8);
        f32x4 z = {0.f, 0.f, 0.f, 0.f};
        sfr[kt] = __builtin_amdgcn_mfma_f32_16x16x32_bf16(qfrag, kf, z, 0, 0, 0);
    }
    #pragma unroll
    for (int kt = 0; kt < 16; ++kt)
        #pragma unroll
        for (int r = 0; r < 4; ++r) sfr[kt][r] *= scale;

    #pragma unroll
    for (int r = 0; r < 4; ++r) {
        float mx = -1e30f;
        #pragma unroll
        for (int kt = 0; kt < 16; ++kt) mx = fmaxf(mx, sfr[kt][r]);
        #pragma unroll
        for (int mm = 1; mm <= 8; mm <<= 1) mx = fmaxf(mx, __shfl_xor(mx, mm, 64));
        float sm = 0.f;
        #pragma unroll
        for (int kt = 0; kt < 16; ++kt) sm += expf(sfr[kt][r] - mx);
        #pragma unroll
        for (int mm = 1; mm <= 8; mm <<= 1) sm += __shfl_xor(sm, mm, 64);
        if (fr == 0) { redm[wv][4 * g + r] = mx; reds[wv][4 * g + r] = sm; }
    }
    __syncthreads();

    float gm[4], gl[4];
    #pragma unroll
    for (int r = 0; r < 4; ++r) {
        const int q = 4 * g + r;
        float mm = fmaxf(fmaxf(redm[0][q], redm[1][q]), fmaxf(redm[2][q], redm[3][q]));
        float ll = 0.f;
        #pragma unroll
        for (int w2 = 0; w2 < 4; ++w2) ll += reds[w2][q] * expf(redm[w2][q] - mm);
        gm[r] = mm; gl[r] = 1.f / ll;
    }
    #pragma unroll
    for (int kt = 0; kt < 16; ++kt) {
        #pragma unroll
        for (int r = 0; r < 4; ++r) {
            float p = expf(sfr[kt][r] - gm[r]) * gl[r];
            pb[4 * g + r][kbase + kt * 16 + fr] = __float2bfloat16(p);
        }
    }

    f32x4 o0 = {0.f, 0.f, 0.f, 0.f}, o1 = {0.f, 0.f, 0.f, 0.f};
    const __hip_bfloat16* vbase = vT + ((long long)bb * DIM + h * HD) * 1024;
    #pragma unroll
    for (int ks = 0; ks < 8; ++ks) {
        const int key0 = kbase + ks * 32 + g * 8;
        bf16x8 pf = *(const bf16x8*)&pb[fr][key0];
        bf16x8 v0 = *(const bf16x8*)(vbase + (long long)fr * 1024 + key0);
        bf16x8 v1 = *(const bf16x8*)(vbase + (long long)(16 + fr) * 1024 + key0);
        o0 = __builtin_amdgcn_mfma_f32_16x16x32_bf16(pf, v0, o0, 0, 0, 0);
        o1 = __builtin_amdgcn_mfma_f32_16x16x32_bf16(pf, v1, o1, 0, 0, 0);
    }

    #pragma unroll
    for (int r = 0; r < 4; ++r) {
        redo[wv][4 * g + r][fr] = o0[r];
        redo[wv][4 * g + r][16 + fr] = o1[r];
    }
    __syncthreads();
    #pragma unroll
    for (int i = 0; i < 2; ++i) {
        const int idx = t + i * 256;
        const int q = idx >> 5, d = idx & 31;
        float v = redo[0][q][d] + redo[1][q][d] + redo[2][q][d] + redo[3][q][d];
        attout[((long long)(bb * NQ + q0 + q)) * DIM + h * HD + d] = v;
    }
}

// ---------------- residual + LayerNorm (in-place capable) ----------------
extern "C" __global__ __launch_bounds__(256)
void ln_kernel(const float* __restrict__ X, long long sx,
               const float* __restrict__ R, long long sr,
               const float* __restrict__ g, const float* __restrict__ bta,
               float* __restrict__ O, long long so) {
    __shared__ float red[4];
    const int row = blockIdx.x, bb = blockIdx.y, t = threadIdx.x;
    float x = X[(long long)bb * sx + (long long)row * DIM + t]
            + R[(long long)bb * sr + (long long)row * DIM + t];
    float v = x;
    #pragma unroll
    for (int m = 32; m >= 1; m >>= 1) v += __shfl_xor(v, m, 64);
    if ((t & 63) == 0) red[t >> 6] = v;
    __syncthreads();
    float mean = (red[0] + red[1] + red[2] + red[3]) * (1.f / 256.f);
    __syncthreads();
    float d = x - mean;
    v = d * d;
    #pragma unroll
    for (int m = 32; m >= 1; m >>= 1) v += __shfl_xor(v, m, 64);
    if ((t & 63) == 0) red[t >> 6] = v;
    __syncthreads();
    float var = (red[0] + red[1] + red[2] + red[3]) * (1.f / 256.f);
    O[(long long)bb * so + (long long)row * DIM + t] = d * rsqrtf(var + 1e-5f) * g[t] + bta[t];
}

// ---------------- query = selsrc + selpos ----------------
extern "C" __global__ __launch_bounds__(256)
void addq_kernel(const float* __restrict__ a, const float* __restrict__ b2, float* __restrict__ o) {
    long long i = (long long)blockIdx.x * 256 + threadIdx.x;
    o[i] = a[i] + b2[i];
}

// ---------------- box attention ----------------
// vp is HEAD-PLANAR bf16: vp[((b*8+h)*16384 + pix)*32 + ch].
// Phase B (512 threads): lane = (head = t>>6 [one head per wave],
// oct = (t>>4)&3 [16B chunk of the 64B row], stream = t&15 [j-stream]).
// Each lane gathers <=7 bf16x8 rows — all 7 loads fit the compiler's ~8-deep
// load window -> one latency exposure. Stream reduction = 4 shfl_xor
// butterflies (stream == lane bits 0-3) -> no LDS reduction, no extra barrier.
extern "C" __global__ __launch_bounds__(512)
void boxattn_kernel(const float* __restrict__ aw, const float* __restrict__ ob,
                    const float* __restrict__ dgrid, const float* __restrict__ selref,
                    const __hip_bfloat16* __restrict__ vp, const float* __restrict__ kidx,
                    float* __restrict__ boxout) {
    __shared__ float aw_s[200];
    __shared__ float ob_s[32];
    __shared__ float ref_s[7];
    __shared__ float ki_s[50];
    __shared__ float box_s[8][6];
    __shared__ float mx_s[8];
    __shared__ float wq_s[200];
    __shared__ int   i4_s[800];
    __shared__ float w4_s[800];
    const int t = threadIdx.x;
    const int s = blockIdx.x, bb = blockIdx.y;
    const long long base = (long long)(bb * NSEL + s);
    if (t < 200) aw_s[t] = aw[base * 200 + t];
    if (t < 32)  ob_s[t] = ob[base * 32 + t];
    if (t < 7)   ref_s[t] = selref[base * 7 + t];
    if (t < 50)  ki_s[t] = kidx[t];
    __syncthreads();

    if (t < 8) {
        float mx = -1e30f;
        #pragma unroll
        for (int p = 0; p < NP_; ++p) mx = fmaxf(mx, aw_s[t * NP_ + p]);
        mx_s[t] = mx;
        const float r0 = ref_s[0], r1 = ref_s[1], r3 = ref_s[3], r4 = ref_s[4], r6 = ref_s[6];
        box_s[t][0] = r0 + ob_s[t * 4 + 0] * 0.125f * r3;
        box_s[t][1] = r1 + ob_s[t * 4 + 1] * 0.125f * r4;
        box_s[t][2] = fmaxf(r3 + ob_s[t * 4 + 2] * 0.125f * r3, 0.f);
        box_s[t][3] = fmaxf(r4 + ob_s[t * 4 + 3] * 0.125f * r4, 0.f);
        box_s[t][4] = cosf(r6);
        box_s[t][5] = sinf(r6);
    }
    __syncthreads();

    if (t < 200) {
        const int h = t / NP_, p = t - h * NP_;
        const float w = expf(aw_s[t] - mx_s[h]);
        wq_s[t] = w;
        const float cx = box_s[h][0], cy = box_s[h][1];
        const float sw = box_s[h][2], sh = box_s[h][3];
        const float ca = box_s[h][4], sa = box_s[h][5];
        const float fx = ki_s[p * 2 + 0] * sw;
        const float fy = ki_s[p * 2 + 1] * sh;
        const float gx = cx + ca * fx - sa * fy + dgrid[base * 400 + 2 * t + 0] * (1.f / 188.f);
        const float gy = cy + sa * fx + ca * fy + dgrid[base * 400 + 2 * t + 1] * (1.f / 188.f);
        const float x = gx * 128.f - 0.5f;
        const float y = gy * 128.f - 0.5f;
        const float x0f = floorf(x), y0f = floorf(y);
        const float lx = x - x0f, ly = y - y0f;
        const int x0 = (int)x0f, y0 = (int)y0f;
        #pragma unroll
        for (int c = 0; c < 4; ++c) {
            const int xi = x0 + (c & 1);
            const int yi = y0 + (c >> 1);
            const float wgt = ((c & 1) ? lx : 1.f - lx) * ((c >> 1) ? ly : 1.f - ly);
            const bool valid = (xi >= 0) & (xi < 128) & (yi >= 0) & (yi < 128);
            const int cxi = min(max(xi, 0), 127);
            const int cyi = min(max(yi, 0), 127);
            i4_s[t * 4 + c] = cyi * 128 + cxi;
            w4_s[t * 4 + c] = w * (valid ? wgt : 0.f);
        }
    }
    __syncthreads();

    // phase B
    {
        const int h2 = t >> 6;           // head == wave id
        const int oct = (t >> 4) & 3;    // which 16B chunk of the 64B pixel row
        const int stream = t & 15;       // j-stream
        const __hip_bfloat16* vb = vp + ((long long)(bb * 8 + h2) * 16384) * 32 + oct * 8;
        bf16x8 vv[7];
        float  wls[7];
        #pragma unroll
        for (int u = 0; u < 7; ++u) {
            const int j = stream + u * 16;
            const bool ok = (j < 100);
            const int e = h2 * 100 + (ok ? j : 0);
            vv[u]  = *(const bf16x8*)(vb + (long long)i4_s[e] * 32);
            wls[u] = ok ? w4_s[e] : 0.f;
        }
        float a[8] = {0.f, 0.f, 0.f, 0.f, 0.f, 0.f, 0.f, 0.f};
        #pragma unroll
        for (int u = 0; u < 7; ++u)
            #pragma unroll
            for (int k = 0; k < 8; ++k) a[k] += wls[u] * (float)vv[u][k];
        // butterfly over stream (lane bits 0-3)
        #pragma unroll
        for (int m = 1; m <= 8; m <<= 1)
            #pragma unroll
            for (int k = 0; k < 8; ++k) a[k] += __shfl_xor(a[k], m, 64);
        if (stream == 0) {
            float inv = 0.f;
            #pragma unroll
            for (int p = 0; p < NP_; ++p) inv += wq_s[h2 * NP_ + p];
            inv = 1.f / inv;
            #pragma unroll
            for (int k = 0; k < 8; ++k)
                boxout[base * DIM + h2 * HD + oct * 8 + k] = a[k] * inv;
        }
    }
}

// ---------------- scatter final rows back into out ----------------
extern "C" __global__ __launch_bounds__(256)
void scatter_kernel(const int* __restrict__ idx, const float* __restrict__ sel,
                    float* __restrict__ out) {
    const int s = blockIdx.x, bb = blockIdx.y, t = threadIdx.x;
    const int i = idx[bb * NSEL + s];
    out[((long long)(bb * HW_N + i)) * DIM + t] = sel[((long long)(bb * NSEL + s)) * DIM + t];
}

extern "C" void kernel_launch(void* const* d_in, const int* in_sizes, int n_in,
                              void* d_out, int out_size, void* d_ws, size_t ws_size,
                              hipStream_t stream) {
    const float* src          = (const float*)d_in[0];
    const float* pos          = (const float*)d_in[1];
    const float* refw         = (const float*)d_in[4];
    const float* score        = (const float*)d_in[5];
    const float* in_proj_w    = (const float*)d_in[6];
    const float* in_proj_b    = (const float*)d_in[7];
    const float* mha_out_w    = (const float*)d_in[8];
    const float* mha_out_b    = (const float*)d_in[9];
    const float* value_proj_w = (const float*)d_in[10];
    const float* value_proj_b = (const float*)d_in[11];
    const float* lin_attn_w   = (const float*)d_in[12];
    const float* lin_attn_b   = (const float*)d_in[13];
    const float* lin_box_w    = (const float*)d_in[14];
    const float* lin_box_b    = (const float*)d_in[15];
    const float* samp_off_w   = (const float*)d_in[16];
    const float* samp_off_b   = (const float*)d_in[17];
    const float* ca_out_w     = (const float*)d_in[18];
    const float* ca_out_b     = (const float*)d_in[19];
    const float* lin1_w       = (const float*)d_in[20];
    const float* lin1_b       = (const float*)d_in[21];
    const float* lin2_w       = (const float*)d_in[22];
    const float* lin2_b       = (const float*)d_in[23];
    const float* qn_g         = (const float*)d_in[24];
    const float* qn_b         = (const float*)d_in[25];
    const float* n1_g         = (const float*)d_in[26];
    const float* n1_b         = (const float*)d_in[27];
    const float* n2_g         = (const float*)d_in[28];
    const float* n2_b         = (const float*)d_in[29];
    const float* kidx         = (const float*)d_in[30];

    float* w = (float*)d_ws;
    int* idxp = (int*)d_ws;
    float* selref = w + OFF_SELREF;
    float* selsrc = w + OFF_SELSRC;
    float* selpos = w + OFF_SELPOS;
    float* boxout = w + OFF_SELPOS;   // reuse after selpos dead
    float* query  = w + OFF_QUERY;
    float* src2   = w + OFF_QUERY;    // reuse after query dead
    __hip_bfloat16* vproj  = (__hip_bfloat16*)(w + OFF_BIG);   // head-planar bf16
    __hip_bfloat16* ffntb  = (__hip_bfloat16*)(w + OFF_BIG);   // reuse after vproj dead
    __hip_bfloat16* wbf    = (__hip_bfloat16*)(w + OFF_WBF);   // bf16 weight pool
    float* qk     = w + OFF_F;
    __hip_bfloat16* qkb = (__hip_bfloat16*)(w + OFF_F + 524288);
    __hip_bfloat16* vT  = (__hip_bfloat16*)(w + OFF_F + 1572864);
    float* attout = w + OFF_F + 2097152;
    float* q2     = w + OFF_F + 2621440;
    float* aw     = w + OFF_F;              // reuse after MHA dead
    float* obuf   = w + OFF_F + 1638400;
    float* dgrid  = w + OFF_F + 1900544;
    float* ff     = w + OFF_F;              // reuse after box-attn dead
    unsigned int* hist2 = (unsigned int*)(w + OFF_F);          // topk scratch
    unsigned int* ctrl2 = hist2 + 16384;
    unsigned long long* list1 = (unsigned long long*)(hist2 + 16448);
    unsigned long long* list2 = list1 + 2 * 2048;
    float* out    = (float*)d_out;

    // bf16 weight pool offsets
    const long long W_INPROJ = 0, W_MHAOUT = 196608, W_VALUE = 262144,
                    W_LATTN = 327680, W_LBOX = 378880, W_SOFF = 387072,
                    W_CAOUT = 489472, W_LIN1 = 555008, W_LIN2 = 817152;

    hipMemcpyAsync(d_out, src, (size_t)2 * HW_N * DIM * sizeof(float),
                   hipMemcpyDeviceToDevice, stream);

    wcvt_kernel<<<4216, 256, 0, stream>>>(in_proj_w, mha_out_w, value_proj_w,
                                          lin_attn_w, lin_box_w, samp_off_w,
                                          ca_out_w, lin1_w, lin2_w, wbf);

    hipMemsetAsync(hist2, 0, 16448 * sizeof(unsigned int), stream);
    topk_hist_kernel<<<dim3(32, 2), 512, 0, stream>>>(score, hist2);
    topk_scan_kernel<<<2, 1024, 0, stream>>>(hist2, ctrl2);
    topk_collect_kernel<<<dim3(16, 2), 1024, 0, stream>>>(score, ctrl2, list1, list2);
    topk_classify_kernel<<<dim3(16, 2), 1024, 0, stream>>>(score, ctrl2, list1, list2, idxp);

    gather_kernel<<<dim3(NSEL, 2), 256, 0, stream>>>(src, pos, refw, idxp,
                                                     selsrc, selpos, selref, qk);
    gemm_kernel<<<dim3(8, 16, 2), 256, 0, stream>>>(qk, 262144LL, wbf + W_INPROJ, in_proj_b,
                                                    (float*)qkb, 524288LL, NQ, 512, 256, 0, 1, 0);
    gemm_kernel<<<dim3(4, 16, 2), 256, 0, stream>>>(selsrc, 1048576LL, wbf + W_INPROJ + 512 * 256,
                                                    in_proj_b + 512, (float*)vT, 262144LL, NQ, 256, 256, 0, 2, 0);
    attn_kernel<<<dim3(64, 8, 2), 256, 0, stream>>>(qkb, vT, attout);
    gemm_kernel<<<dim3(4, 16, 2), 256, 0, stream>>>(attout, 262144LL, wbf + W_MHAOUT, mha_out_b,
                                                    q2, 262144LL, NQ, 256, 256, 0, 0, 0);
    ln_kernel<<<dim3(NQ, 2), 256, 0, stream>>>(selsrc, 1048576LL, q2, 262144LL,
                                               qn_g, qn_b, selsrc, 1048576LL);
    addq_kernel<<<8192, 256, 0, stream>>>(selsrc, selpos, query);
    gemm_kernel<<<dim3(4, 256, 2), 256, 0, stream>>>(src, 4194304LL, wbf + W_VALUE, value_proj_b,
                                                     (float*)vproj, 4194304LL, HW_N, 256, 256, 0, 3, 0);
    gemm_kernel<<<dim3(4, 64, 2), 256, 0, stream>>>(query, 1048576LL, wbf + W_LATTN, lin_attn_b,
                                                    aw, 819200LL, NSEL, 200, 256, 0, 0, 0);
    gemm_kernel<<<dim3(1, 64, 2), 256, 0, stream>>>(query, 1048576LL, wbf + W_LBOX, lin_box_b,
                                                    obuf, 131072LL, NSEL, 32, 256, 0, 0, 0);
    gemm_kernel<<<dim3(7, 64, 2), 256, 0, stream>>>(query, 1048576LL, wbf + W_SOFF, samp_off_b,
                                                    dgrid, 1638400LL, NSEL, 400, 256, 0, 0, 0);
    boxattn_kernel<<<dim3(NSEL, 2), 512, 0, stream>>>(aw, obuf, dgrid, selref, vproj, kidx, boxout);
    gemm_kernel<<<dim3(4, 64, 2), 256, 0, stream>>>(boxout, 1048576LL, wbf + W_CAOUT, ca_out_b,
                                                    src2, 1048576LL, NSEL, 256, 256, 0, 0, 0);
    ln_kernel<<<dim3(NSEL, 2), 256, 0, stream>>>(selsrc, 1048576LL, src2, 1048576LL,
                                                 n1_g, n1_b, selsrc, 1048576LL);
    gemm_kernel<<<dim3(16, 64, 2), 256, 0, stream>>>(selsrc, 1048576LL, wbf + W_LIN1, lin1_b,
                                                     (float*)ffntb, 4194304LL, NSEL, DFF_, 256, 1, 1, 0);
    gemm_kernel<<<dim3(4, 64, 2), 256, 0, stream>>>(ffntb, 4194304LL, wbf + W_LIN2, lin2_b,
                                                    ff, 1048576LL, NSEL, 256, DFF_, 0, 0, 1);
    ln_kernel<<<dim3(NSEL, 2), 256, 0, stream>>>(selsrc, 1048576LL, ff, 1048576LL,
                                                 n2_g, n2_b, selsrc, 1048576LL);
    scatter_kernel<<<dim3(NSEL, 2), 256, 0, stream>>>(idxp, selsrc, out);
}

// Round 3
// 457.064 us; speedup vs baseline: 1.0298x; 1.0298x over previous
//
#include <hip/hip_runtime.h>
#include <hip/hip_bf16.h>
#include <math.h>

// Problem constants
#define HW_N   16384
#define DIM    256
#define NSEL   4096
#define NQ     1024
#define NHEAD  8
#define HD     32
#define NP_    25
#define DFF_   1024

// Workspace layout (float offsets). ~76 MB total.
#define OFF_SELREF  8448LL          // 2*4096*7
#define OFF_SELSRC  65792LL         // 2*4096*256
#define OFF_SELPOS  2162944LL       // 2*4096*256 (later reused as boxout)
#define OFF_QUERY   4260096LL       // 2*4096*256 (later reused as src2)
#define OFF_BIG     6357248LL       // vproj bf16 [0,4194304) then ffnt bf16 same slot
#define OFF_WBF     10551552LL      // OFF_BIG+4194304: bf16 weights, 1079296 bf16
#define OFF_F       14745856LL      // multi-use region, 5177344 floats

__device__ __forceinline__ unsigned int f2s(float f) {
    unsigned int u = __float_as_uint(f);
    return (u & 0x80000000u) ? ~u : (u | 0x80000000u);
}

typedef __bf16 bf16x8 __attribute__((ext_vector_type(8)));
typedef __bf16 bf16x4 __attribute__((ext_vector_type(4)));
typedef float  f32x4  __attribute__((ext_vector_type(4)));

// ============ weight preconversion: 9 fp32 matrices -> one bf16 pool ============
// Segments (elems): in_proj 196608 | mha_out 65536 | value 65536 | lin_attn 51200
// | lin_box 8192 | samp_off 102400 | ca_out 65536 | lin1 262144 | lin2 262144
extern "C" __global__ __launch_bounds__(256)
void wcvt_kernel(const float* __restrict__ s0, const float* __restrict__ s1,
                 const float* __restrict__ s2, const float* __restrict__ s3,
                 const float* __restrict__ s4, const float* __restrict__ s5,
                 const float* __restrict__ s6, const float* __restrict__ s7,
                 const float* __restrict__ s8, __hip_bfloat16* __restrict__ dst) {
    const long long g = (long long)blockIdx.x * 256 + threadIdx.x;
    const float* s; long long base;
    if      (g < 196608)  { s = s0; base = 0; }
    else if (g < 262144)  { s = s1; base = 196608; }
    else if (g < 327680)  { s = s2; base = 262144; }
    else if (g < 378880)  { s = s3; base = 327680; }
    else if (g < 387072)  { s = s4; base = 378880; }
    else if (g < 489472)  { s = s5; base = 387072; }
    else if (g < 555008)  { s = s6; base = 489472; }
    else if (g < 817152)  { s = s7; base = 555008; }
    else                  { s = s8; base = 817152; }
    dst[g] = __float2bfloat16(s[g - base]);
}

// ================= top-k, grid-parallel (4 kernels) =================
extern "C" __global__ __launch_bounds__(512)
void topk_hist_kernel(const float* __restrict__ score, unsigned int* __restrict__ hist) {
    const int t = threadIdx.x, bx = blockIdx.x, bb = blockIdx.y;
    const int i = bx * 512 + t;
    unsigned int u = f2s(score[(long long)bb * HW_N + i]);
    atomicAdd(&hist[bb * 8192 + (u >> 19)], 1u);
}

extern "C" __global__ __launch_bounds__(1024)
void topk_scan_kernel(const unsigned int* __restrict__ hist, unsigned int* __restrict__ ctrl) {
    __shared__ unsigned int scan[1024];
    const int t = threadIdx.x, bb = blockIdx.x;
    unsigned int loc[8]; unsigned int lsum = 0u;
    #pragma unroll
    for (int k = 0; k < 8; ++k) { loc[k] = hist[bb * 8192 + t * 8 + k]; lsum += loc[k]; }
    scan[t] = lsum;
    __syncthreads();
    for (int off = 1; off < 1024; off <<= 1) {
        unsigned int v = (t + off < 1024) ? scan[t + off] : 0u;
        __syncthreads();
        scan[t] += v;
        __syncthreads();
    }
    unsigned int nxt = (t < 1023) ? scan[t + 1] : 0u;
    unsigned int run = nxt;
    for (int k = 7; k >= 0; --k) {
        run += loc[k];
        unsigned int above = run - loc[k];
        if (run >= 1024u && above < 1024u) { ctrl[bb * 16 + 0] = (unsigned)(t * 8 + k); ctrl[bb * 16 + 1] = 1024u - above; }
        if (run >= 4096u && above < 4096u) { ctrl[bb * 16 + 2] = (unsigned)(t * 8 + k); ctrl[bb * 16 + 3] = 4096u - above; }
    }
}

extern "C" __global__ __launch_bounds__(1024)
void topk_collect_kernel(const float* __restrict__ score, unsigned int* __restrict__ ctrl,
                         unsigned long long* __restrict__ list1,
                         unsigned long long* __restrict__ list2) {
    const int t = threadIdx.x, bx = blockIdx.x, bb = blockIdx.y;
    const int i = bx * 1024 + t;
    const unsigned int T1 = ctrl[bb * 16 + 0], T2 = ctrl[bb * 16 + 2];
    unsigned int u = f2s(score[(long long)bb * HW_N + i]);
    unsigned int bin = u >> 19;
    unsigned long long key = ((unsigned long long)u << 32) | (unsigned int)(~(unsigned int)i);
    if (bin == T1) {
        unsigned int p = atomicAdd(&ctrl[bb * 16 + 4], 1u);
        if (p < 2048u) list1[bb * 2048 + p] = key;
    }
    if (bin == T2 && T2 != T1) {
        unsigned int p = atomicAdd(&ctrl[bb * 16 + 5], 1u);
        if (p < 2048u) list2[bb * 2048 + p] = key;
    }
}

extern "C" __global__ __launch_bounds__(1024)
void topk_classify_kernel(const float* __restrict__ score, unsigned int* __restrict__ ctrl,
                          const unsigned long long* __restrict__ list1,
                          const unsigned long long* __restrict__ list2,
                          int* __restrict__ idx_out) {
    __shared__ unsigned int cA, cB, baseA, baseB;
    const int t = threadIdx.x, bx = blockIdx.x, bb = blockIdx.y;
    const int i = bx * 1024 + t;
    if (t == 0) { cA = 0u; cB = 0u; }
    __syncthreads();
    const unsigned int T1 = ctrl[bb * 16 + 0], need1 = ctrl[bb * 16 + 1];
    const unsigned int T2 = ctrl[bb * 16 + 2], need2 = ctrl[bb * 16 + 3];
    const unsigned int c1 = min(ctrl[bb * 16 + 4], 2048u);
    const unsigned int c2 = min(ctrl[bb * 16 + 5], 2048u);
    unsigned int u = f2s(score[(long long)bb * HW_N + i]);
    unsigned int bin = u >> 19;
    unsigned long long key = ((unsigned long long)u << 32) | (unsigned int)(~(unsigned int)i);
    bool inA = false, inB = false;
    if (bin > T1) {
        inA = true;
    } else if (bin == T1) {
        unsigned int r = 0;
        for (unsigned int q = 0; q < c1; ++q) r += (list1[bb * 2048 + q] > key) ? 1u : 0u;
        if (r < need1) inA = true;
        else if (T2 == T1) inB = (r < need2);
        else inB = true;
    } else if (bin > T2) {
        inB = true;
    } else if (bin == T2) {
        unsigned int r = 0;
        for (unsigned int q = 0; q < c2; ++q) r += (list2[bb * 2048 + q] > key) ? 1u : 0u;
        inB = (r < need2);
    }
    unsigned int sA = 0u, sB = 0u;
    if (inA) sA = atomicAdd(&cA, 1u);
    if (inB) sB = atomicAdd(&cB, 1u);
    __syncthreads();
    if (t == 0) {
        baseA = atomicAdd(&ctrl[bb * 16 + 6], cA);
        baseB = atomicAdd(&ctrl[bb * 16 + 7], cB);
    }
    __syncthreads();
    if (inA) idx_out[bb * NSEL + baseA + sA] = i;
    if (inB) idx_out[bb * NSEL + 1024 + baseB + sB] = i;
}

// ---------------- gather selected rows ----------------
extern "C" __global__ __launch_bounds__(256)
void gather_kernel(const float* __restrict__ src, const float* __restrict__ pos,
                   const float* __restrict__ refw, const int* __restrict__ idx,
                   float* __restrict__ selsrc, float* __restrict__ selpos,
                   float* __restrict__ selref, float* __restrict__ qk) {
    const int s = blockIdx.x, bb = blockIdx.y, t = threadIdx.x;
    const int i = idx[bb * NSEL + s];
    const long long so = ((long long)(bb * NSEL + s)) * DIM;
    const long long go = ((long long)(bb * HW_N + i)) * DIM;
    float sv = src[go + t], pv = pos[go + t];
    selsrc[so + t] = sv;
    selpos[so + t] = pv;
    if (s < NQ) qk[((long long)(bb * NQ + s)) * DIM + t] = sv + pv;
    if (t < 7)
        selref[(long long)(bb * NSEL + s) * 7 + t] = refw[(long long)(bb * HW_N + i) * 7 + t];
}

// ---------------- bf16 MFMA GEMM: C = act(A @ W^T + bias) ----------------
// W: PRE-CONVERTED bf16 [N][K]. A: fp32 (amode 0) or bf16 (amode 1), [z][M][K].
// omode: 0 fp32 out; 1 bf16 flat; 2 bf16 transposed (col*M+row);
//        3 bf16 head-planar: off = zoff + ((col>>5)*16384 + row)*32 + (col&31).
extern "C" __global__ __launch_bounds__(256)
void gemm_kernel(const void* __restrict__ Avp, long long sA,
                 const __hip_bfloat16* __restrict__ W, const float* __restrict__ bias,
                 float* __restrict__ C, long long sC,
                 int M, int N, int K, int relu, int omode, int amode) {
    __shared__ __hip_bfloat16 As[64][72];
    __shared__ __hip_bfloat16 Ws[64][72];
    const int t = threadIdx.x;
    const int n0 = blockIdx.x * 64, m0 = blockIdx.y * 64;
    const long long zoff = (long long)blockIdx.z * sC;
    const int lane = t & 63, wv = t >> 6;
    const int mw = (wv >> 1) * 32, nw = (wv & 1) * 32;
    const int fr = lane & 15;
    const int fk = (lane >> 4) * 8;
    const int sr = t >> 2;
    const int sk = (t & 3) * 16;

    f32x4 acc[2][2];
    #pragma unroll
    for (int i = 0; i < 2; ++i)
        #pragma unroll
        for (int j = 0; j < 2; ++j) acc[i][j] = {0.f, 0.f, 0.f, 0.f};

    const bool wok = (n0 + sr) < N;
    for (int k0 = 0; k0 < K; k0 += 64) {
        // stage W: straight 32B bf16 copy
        uint4 wa = make_uint4(0u, 0u, 0u, 0u), wb = make_uint4(0u, 0u, 0u, 0u);
        if (wok) {
            const __hip_bfloat16* wp = W + (long long)(n0 + sr) * K + k0 + sk;
            wa = *(const uint4*)wp;
            wb = *(const uint4*)(wp + 8);
        }
        if (amode) {
            const __hip_bfloat16* ap = (const __hip_bfloat16*)Avp
                + (long long)blockIdx.z * sA + (long long)(m0 + sr) * K + k0 + sk;
            uint4 aa = *(const uint4*)ap;
            uint4 ab = *(const uint4*)(ap + 8);
            __syncthreads();
            *(uint4*)&As[sr][sk] = aa;
            *(uint4*)&As[sr][sk + 8] = ab;
            *(uint4*)&Ws[sr][sk] = wa;
            *(uint4*)&Ws[sr][sk + 8] = wb;
        } else {
            const float* ap = (const float*)Avp
                + (long long)blockIdx.z * sA + (long long)(m0 + sr) * K + k0 + sk;
            float av[16];
            #pragma unroll
            for (int q = 0; q < 4; ++q) {
                float4 v = *(const float4*)(ap + q * 4);
                av[q * 4 + 0] = v.x; av[q * 4 + 1] = v.y; av[q * 4 + 2] = v.z; av[q * 4 + 3] = v.w;
            }
            __syncthreads();
            #pragma unroll
            for (int q = 0; q < 16; ++q) As[sr][sk + q] = __float2bfloat16(av[q]);
            *(uint4*)&Ws[sr][sk] = wa;
            *(uint4*)&Ws[sr][sk + 8] = wb;
        }
        __syncthreads();
        #pragma unroll
        for (int kk = 0; kk < 64; kk += 32) {
            bf16x8 a0 = *(const bf16x8*)&As[mw + fr][kk + fk];
            bf16x8 a1 = *(const bf16x8*)&As[mw + 16 + fr][kk + fk];
            bf16x8 b0 = *(const bf16x8*)&Ws[nw + fr][kk + fk];
            bf16x8 b1 = *(const bf16x8*)&Ws[nw + 16 + fr][kk + fk];
            acc[0][0] = __builtin_amdgcn_mfma_f32_16x16x32_bf16(a0, b0, acc[0][0], 0, 0, 0);
            acc[0][1] = __builtin_amdgcn_mfma_f32_16x16x32_bf16(a0, b1, acc[0][1], 0, 0, 0);
            acc[1][0] = __builtin_amdgcn_mfma_f32_16x16x32_bf16(a1, b0, acc[1][0], 0, 0, 0);
            acc[1][1] = __builtin_amdgcn_mfma_f32_16x16x32_bf16(a1, b1, acc[1][1], 0, 0, 0);
        }
    }
    const int crow = (lane >> 4) * 4;
    #pragma unroll
    for (int mi = 0; mi < 2; ++mi) {
        #pragma unroll
        for (int ni = 0; ni < 2; ++ni) {
            const int col = n0 + nw + ni * 16 + fr;
            if (col < N) {
                const float bv = bias ? bias[col] : 0.f;
                #pragma unroll
                for (int r = 0; r < 4; ++r) {
                    const int row = m0 + mw + mi * 16 + crow + r;
                    float v = acc[mi][ni][r] + bv;
                    if (relu) v = fmaxf(v, 0.f);
                    if (omode == 0) {
                        C[zoff + (long long)row * N + col] = v;
                    } else if (omode == 1) {
                        ((__hip_bfloat16*)C)[zoff + (long long)row * N + col] = __float2bfloat16(v);
                    } else if (omode == 2) {
                        ((__hip_bfloat16*)C)[zoff + (long long)col * M + row] = __float2bfloat16(v);
                    } else {
                        ((__hip_bfloat16*)C)[zoff + ((long long)(col >> 5) * 16384 + row) * 32 + (col & 31)]
                            = __float2bfloat16(v);
                    }
                }
            }
        }
    }
}

// ---------------- MHA via MFMA: 16 queries/block, S & softmax in registers ----
extern "C" __global__ __launch_bounds__(256)
void attn_kernel(const __hip_bfloat16* __restrict__ qkb,
                 const __hip_bfloat16* __restrict__ vT,
                 float* __restrict__ attout) {
    __shared__ __hip_bfloat16 pb[16][1048];
    __shared__ float redm[4][16];
    __shared__ float reds[4][16];
    __shared__ float redo[4][16][33];
    const int t = threadIdx.x;
    const int qt = blockIdx.x, h = blockIdx.y, bb = blockIdx.z;
    const int q0 = qt * 16;
    const int lane = t & 63, wv = t >> 6;
    const int fr = lane & 15, g = lane >> 4;
    const int kbase = wv * 256;
    const float scale = 0.17677669529663687f;

    bf16x8 qfrag = *(const bf16x8*)(qkb + ((long long)(bb * NQ + q0 + fr)) * 512 + h * HD + g * 8);

    f32x4 sfr[16];
    #pragma unroll
    for (int kt = 0; kt < 16; ++kt) {
        const int key0 = kbase + kt * 16;
        bf16x8 kf = *(const bf16x8*)(qkb + ((long long)(bb * NQ + key0 + fr)) * 512 + 256 + h * HD + g * 8);
        f32x4 z = {0.f, 0.f, 0.f, 0.f};
        sfr[kt] = __builtin_amdgcn_mfma_f32_16x16x32_bf16(qfrag, kf, z, 0, 0, 0);
    }
    #pragma unroll
    for (int kt = 0; kt < 16; ++kt)
        #pragma unroll
        for (int r = 0; r < 4; ++r) sfr[kt][r] *= scale;

    #pragma unroll
    for (int r = 0; r < 4; ++r) {
        float mx = -1e30f;
        #pragma unroll
        for (int kt = 0; kt < 16; ++kt) mx = fmaxf(mx, sfr[kt][r]);
        #pragma unroll
        for (int mm = 1; mm <= 8; mm <<= 1) mx = fmaxf(mx, __shfl_xor(mx, mm, 64));
        float sm = 0.f;
        #pragma unroll
        for (int kt = 0; kt < 16; ++kt) sm += expf(sfr[kt][r] - mx);
        #pragma unroll
        for (int mm = 1; mm <= 8; mm <<= 1) sm += __shfl_xor(sm, mm, 64);
        if (fr == 0) { redm[wv][4 * g + r] = mx; reds[wv][4 * g + r] = sm; }
    }
    __syncthreads();

    float gm[4], gl[4];
    #pragma unroll
    for (int r = 0; r < 4; ++r) {
        const int q = 4 * g + r;
        float mm = fmaxf(fmaxf(redm[0][q], redm[1][q]), fmaxf(redm[2][q], redm[3][q]));
        float ll = 0.f;
        #pragma unroll
        for (int w2 = 0; w2 < 4; ++w2) ll += reds[w2][q] * expf(redm[w2][q] - mm);
        gm[r] = mm; gl[r] = 1.f / ll;
    }
    #pragma unroll
    for (int kt = 0; kt < 16; ++kt) {
        #pragma unroll
        for (int r = 0; r < 4; ++r) {
            float p = expf(sfr[kt][r] - gm[r]) * gl[r];
            pb[4 * g + r][kbase + kt * 16 + fr] = __float2bfloat16(p);
        }
    }

    f32x4 o0 = {0.f, 0.f, 0.f, 0.f}, o1 = {0.f, 0.f, 0.f, 0.f};
    const __hip_bfloat16* vbase = vT + ((long long)bb * DIM + h * HD) * 1024;
    #pragma unroll
    for (int ks = 0; ks < 8; ++ks) {
        const int key0 = kbase + ks * 32 + g * 8;
        bf16x8 pf = *(const bf16x8*)&pb[fr][key0];
        bf16x8 v0 = *(const bf16x8*)(vbase + (long long)fr * 1024 + key0);
        bf16x8 v1 = *(const bf16x8*)(vbase + (long long)(16 + fr) * 1024 + key0);
        o0 = __builtin_amdgcn_mfma_f32_16x16x32_bf16(pf, v0, o0, 0, 0, 0);
        o1 = __builtin_amdgcn_mfma_f32_16x16x32_bf16(pf, v1, o1, 0, 0, 0);
    }

    #pragma unroll
    for (int r = 0; r < 4; ++r) {
        redo[wv][4 * g + r][fr] = o0[r];
        redo[wv][4 * g + r][16 + fr] = o1[r];
    }
    __syncthreads();
    #pragma unroll
    for (int i = 0; i < 2; ++i) {
        const int idx = t + i * 256;
        const int q = idx >> 5, d = idx & 31;
        float v = redo[0][q][d] + redo[1][q][d] + redo[2][q][d] + redo[3][q][d];
        attout[((long long)(bb * NQ + q0 + q)) * DIM + h * HD + d] = v;
    }
}

// ---------------- residual + LayerNorm (in-place capable) ----------------
extern "C" __global__ __launch_bounds__(256)
void ln_kernel(const float* __restrict__ X, long long sx,
               const float* __restrict__ R, long long sr,
               const float* __restrict__ g, const float* __restrict__ bta,
               float* __restrict__ O, long long so) {
    __shared__ float red[4];
    const int row = blockIdx.x, bb = blockIdx.y, t = threadIdx.x;
    float x = X[(long long)bb * sx + (long long)row * DIM + t]
            + R[(long long)bb * sr + (long long)row * DIM + t];
    float v = x;
    #pragma unroll
    for (int m = 32; m >= 1; m >>= 1) v += __shfl_xor(v, m, 64);
    if ((t & 63) == 0) red[t >> 6] = v;
    __syncthreads();
    float mean = (red[0] + red[1] + red[2] + red[3]) * (1.f / 256.f);
    __syncthreads();
    float d = x - mean;
    v = d * d;
    #pragma unroll
    for (int m = 32; m >= 1; m >>= 1) v += __shfl_xor(v, m, 64);
    if ((t & 63) == 0) red[t >> 6] = v;
    __syncthreads();
    float var = (red[0] + red[1] + red[2] + red[3]) * (1.f / 256.f);
    O[(long long)bb * so + (long long)row * DIM + t] = d * rsqrtf(var + 1e-5f) * g[t] + bta[t];
}

// ---------------- query = selsrc + selpos ----------------
extern "C" __global__ __launch_bounds__(256)
void addq_kernel(const float* __restrict__ a, const float* __restrict__ b2, float* __restrict__ o) {
    long long i = (long long)blockIdx.x * 256 + threadIdx.x;
    o[i] = a[i] + b2[i];
}

// ---------------- box attention ----------------
// vp is HEAD-PLANAR bf16: vp[((b*8+h)*16384 + pix)*32 + ch].
// Phase B: 8 lanes/head x bf16x4 loads; 4 waves split the 100 (p,corner) pairs.
// The 25 gathers are forced fully in-flight: preload addresses+weights from
// LDS to registers, issue ALL 25 global loads, then a sched_barrier(0) fence
// before the FMA block. Without the fence the scheduler interleaves load/use
// pairs in an ~8-deep window (VGPR_Count stayed 36 across two rounds),
// leaving 3-4 serial latency exposures per wave.
extern "C" __global__ __launch_bounds__(256)
void boxattn_kernel(const float* __restrict__ aw, const float* __restrict__ ob,
                    const float* __restrict__ dgrid, const float* __restrict__ selref,
                    const __hip_bfloat16* __restrict__ vp, const float* __restrict__ kidx,
                    float* __restrict__ boxout) {
    __shared__ float aw_s[200];
    __shared__ float ob_s[32];
    __shared__ float ref_s[7];
    __shared__ float ki_s[50];
    __shared__ float box_s[8][6];
    __shared__ float mx_s[8];
    __shared__ float inv_s[8];
    __shared__ float wq_s[200];
    __shared__ int   i4_s[800];
    __shared__ float w4_s[800];
    __shared__ float red4[4][8][32];
    const int t = threadIdx.x;
    const int s = blockIdx.x, bb = blockIdx.y;
    const long long base = (long long)(bb * NSEL + s);
    if (t < 200) aw_s[t] = aw[base * 200 + t];
    if (t < 32)  ob_s[t] = ob[base * 32 + t];
    if (t < 7)   ref_s[t] = selref[base * 7 + t];
    if (t < 50)  ki_s[t] = kidx[t];
    __syncthreads();

    if (t < 8) {
        float mx = -1e30f;
        #pragma unroll
        for (int p = 0; p < NP_; ++p) mx = fmaxf(mx, aw_s[t * NP_ + p]);
        mx_s[t] = mx;
        const float r0 = ref_s[0], r1 = ref_s[1], r3 = ref_s[3], r4 = ref_s[4], r6 = ref_s[6];
        box_s[t][0] = r0 + ob_s[t * 4 + 0] * 0.125f * r3;
        box_s[t][1] = r1 + ob_s[t * 4 + 1] * 0.125f * r4;
        box_s[t][2] = fmaxf(r3 + ob_s[t * 4 + 2] * 0.125f * r3, 0.f);
        box_s[t][3] = fmaxf(r4 + ob_s[t * 4 + 3] * 0.125f * r4, 0.f);
        box_s[t][4] = cosf(r6);
        box_s[t][5] = sinf(r6);
    }
    __syncthreads();

    if (t < 200) {
        const int h = t / NP_, p = t - h * NP_;
        const float w = expf(aw_s[t] - mx_s[h]);
        wq_s[t] = w;
        const float cx = box_s[h][0], cy = box_s[h][1];
        const float sw = box_s[h][2], sh = box_s[h][3];
        const float ca = box_s[h][4], sa = box_s[h][5];
        const float fx = ki_s[p * 2 + 0] * sw;
        const float fy = ki_s[p * 2 + 1] * sh;
        const float gx = cx + ca * fx - sa * fy + dgrid[base * 400 + 2 * t + 0] * (1.f / 188.f);
        const float gy = cy + sa * fx + ca * fy + dgrid[base * 400 + 2 * t + 1] * (1.f / 188.f);
        const float x = gx * 128.f - 0.5f;
        const float y = gy * 128.f - 0.5f;
        const float x0f = floorf(x), y0f = floorf(y);
        const float lx = x - x0f, ly = y - y0f;
        const int x0 = (int)x0f, y0 = (int)y0f;
        #pragma unroll
        for (int c = 0; c < 4; ++c) {
            const int xi = x0 + (c & 1);
            const int yi = y0 + (c >> 1);
            const float wgt = ((c & 1) ? lx : 1.f - lx) * ((c >> 1) ? ly : 1.f - ly);
            const bool valid = (xi >= 0) & (xi < 128) & (yi >= 0) & (yi < 128);
            const int cxi = min(max(xi, 0), 127);
            const int cyi = min(max(yi, 0), 127);
            i4_s[t * 4 + c] = cyi * 128 + cxi;
            w4_s[t * 4 + c] = w * (valid ? wgt : 0.f);
        }
    }
    __syncthreads();
    if (t < 8) {
        float sm = 0.f;
        #pragma unroll
        for (int p = 0; p < NP_; ++p) sm += wq_s[t * NP_ + p];
        inv_s[t] = 1.f / sm;
    }
    __syncthreads();

    // phase B: preload addr/weight, force-issue all 25 loads, fence, accumulate
    {
        const int lane = t & 63, wv = t >> 6;
        const int h2 = lane >> 3, q = lane & 7;
        const __hip_bfloat16* vb = vp + ((long long)(bb * 8 + h2) * 16384) * 32 + q * 4;
        int   pix[25];
        float wls[25];
        #pragma unroll
        for (int u = 0; u < 25; ++u) {
            const int e = h2 * 100 + wv + u * 4;
            pix[u] = i4_s[e];
            wls[u] = w4_s[e];
        }
        bf16x4 vv[25];
        #pragma unroll
        for (int u = 0; u < 25; ++u)
            vv[u] = *(const bf16x4*)(vb + (long long)pix[u] * 32);
        __builtin_amdgcn_sched_barrier(0);   // all 25 loads issued before any use
        float a0 = 0.f, a1 = 0.f, a2 = 0.f, a3 = 0.f;
        #pragma unroll
        for (int u = 0; u < 25; ++u) {
            a0 += wls[u] * (float)vv[u][0];
            a1 += wls[u] * (float)vv[u][1];
            a2 += wls[u] * (float)vv[u][2];
            a3 += wls[u] * (float)vv[u][3];
        }
        red4[wv][h2][q * 4 + 0] = a0;
        red4[wv][h2][q * 4 + 1] = a1;
        red4[wv][h2][q * 4 + 2] = a2;
        red4[wv][h2][q * 4 + 3] = a3;
    }
    __syncthreads();
    {
        const int h = t >> 5, d = t & 31;
        float v = red4[0][h][d] + red4[1][h][d] + red4[2][h][d] + red4[3][h][d];
        boxout[base * DIM + h * HD + d] = v * inv_s[h];
    }
}

// ---------------- scatter final rows back into out ----------------
extern "C" __global__ __launch_bounds__(256)
void scatter_kernel(const int* __restrict__ idx, const float* __restrict__ sel,
                    float* __restrict__ out) {
    const int s = blockIdx.x, bb = blockIdx.y, t = threadIdx.x;
    const int i = idx[bb * NSEL + s];
    out[((long long)(bb * HW_N + i)) * DIM + t] = sel[((long long)(bb * NSEL + s)) * DIM + t];
}

extern "C" void kernel_launch(void* const* d_in, const int* in_sizes, int n_in,
                              void* d_out, int out_size, void* d_ws, size_t ws_size,
                              hipStream_t stream) {
    const float* src          = (const float*)d_in[0];
    const float* pos          = (const float*)d_in[1];
    const float* refw         = (const float*)d_in[4];
    const float* score        = (const float*)d_in[5];
    const float* in_proj_w    = (const float*)d_in[6];
    const float* in_proj_b    = (const float*)d_in[7];
    const float* mha_out_w    = (const float*)d_in[8];
    const float* mha_out_b    = (const float*)d_in[9];
    const float* value_proj_w = (const float*)d_in[10];
    const float* value_proj_b = (const float*)d_in[11];
    const float* lin_attn_w   = (const float*)d_in[12];
    const float* lin_attn_b   = (const float*)d_in[13];
    const float* lin_box_w    = (const float*)d_in[14];
    const float* lin_box_b    = (const float*)d_in[15];
    const float* samp_off_w   = (const float*)d_in[16];
    const float* samp_off_b   = (const float*)d_in[17];
    const float* ca_out_w     = (const float*)d_in[18];
    const float* ca_out_b     = (const float*)d_in[19];
    const float* lin1_w       = (const float*)d_in[20];
    const float* lin1_b       = (const float*)d_in[21];
    const float* lin2_w       = (const float*)d_in[22];
    const float* lin2_b       = (const float*)d_in[23];
    const float* qn_g         = (const float*)d_in[24];
    const float* qn_b         = (const float*)d_in[25];
    const float* n1_g         = (const float*)d_in[26];
    const float* n1_b         = (const float*)d_in[27];
    const float* n2_g         = (const float*)d_in[28];
    const float* n2_b         = (const float*)d_in[29];
    const float* kidx         = (const float*)d_in[30];

    float* w = (float*)d_ws;
    int* idxp = (int*)d_ws;
    float* selref = w + OFF_SELREF;
    float* selsrc = w + OFF_SELSRC;
    float* selpos = w + OFF_SELPOS;
    float* boxout = w + OFF_SELPOS;   // reuse after selpos dead
    float* query  = w + OFF_QUERY;
    float* src2   = w + OFF_QUERY;    // reuse after query dead
    __hip_bfloat16* vproj  = (__hip_bfloat16*)(w + OFF_BIG);   // head-planar bf16
    __hip_bfloat16* ffntb  = (__hip_bfloat16*)(w + OFF_BIG);   // reuse after vproj dead
    __hip_bfloat16* wbf    = (__hip_bfloat16*)(w + OFF_WBF);   // bf16 weight pool
    float* qk     = w + OFF_F;
    __hip_bfloat16* qkb = (__hip_bfloat16*)(w + OFF_F + 524288);
    __hip_bfloat16* vT  = (__hip_bfloat16*)(w + OFF_F + 1572864);
    float* attout = w + OFF_F + 2097152;
    float* q2     = w + OFF_F + 2621440;
    float* aw     = w + OFF_F;              // reuse after MHA dead
    float* obuf   = w + OFF_F + 1638400;
    float* dgrid  = w + OFF_F + 1900544;
    float* ff     = w + OFF_F;              // reuse after box-attn dead
    unsigned int* hist2 = (unsigned int*)(w + OFF_F);          // topk scratch
    unsigned int* ctrl2 = hist2 + 16384;
    unsigned long long* list1 = (unsigned long long*)(hist2 + 16448);
    unsigned long long* list2 = list1 + 2 * 2048;
    float* out    = (float*)d_out;

    // bf16 weight pool offsets
    const long long W_INPROJ = 0, W_MHAOUT = 196608, W_VALUE = 262144,
                    W_LATTN = 327680, W_LBOX = 378880, W_SOFF = 387072,
                    W_CAOUT = 489472, W_LIN1 = 555008, W_LIN2 = 817152;

    hipMemcpyAsync(d_out, src, (size_t)2 * HW_N * DIM * sizeof(float),
                   hipMemcpyDeviceToDevice, stream);

    wcvt_kernel<<<4216, 256, 0, stream>>>(in_proj_w, mha_out_w, value_proj_w,
                                          lin_attn_w, lin_box_w, samp_off_w,
                                          ca_out_w, lin1_w, lin2_w, wbf);

    hipMemsetAsync(hist2, 0, 16448 * sizeof(unsigned int), stream);
    topk_hist_kernel<<<dim3(32, 2), 512, 0, stream>>>(score, hist2);
    topk_scan_kernel<<<2, 1024, 0, stream>>>(hist2, ctrl2);
    topk_collect_kernel<<<dim3(16, 2), 1024, 0, stream>>>(score, ctrl2, list1, list2);
    topk_classify_kernel<<<dim3(16, 2), 1024, 0, stream>>>(score, ctrl2, list1, list2, idxp);

    gather_kernel<<<dim3(NSEL, 2), 256, 0, stream>>>(src, pos, refw, idxp,
                                                     selsrc, selpos, selref, qk);
    gemm_kernel<<<dim3(8, 16, 2), 256, 0, stream>>>(qk, 262144LL, wbf + W_INPROJ, in_proj_b,
                                                    (float*)qkb, 524288LL, NQ, 512, 256, 0, 1, 0);
    gemm_kernel<<<dim3(4, 16, 2), 256, 0, stream>>>(selsrc, 1048576LL, wbf + W_INPROJ + 512 * 256,
                                                    in_proj_b + 512, (float*)vT, 262144LL, NQ, 256, 256, 0, 2, 0);
    attn_kernel<<<dim3(64, 8, 2), 256, 0, stream>>>(qkb, vT, attout);
    gemm_kernel<<<dim3(4, 16, 2), 256, 0, stream>>>(attout, 262144LL, wbf + W_MHAOUT, mha_out_b,
                                                    q2, 262144LL, NQ, 256, 256, 0, 0, 0);
    ln_kernel<<<dim3(NQ, 2), 256, 0, stream>>>(selsrc, 1048576LL, q2, 262144LL,
                                               qn_g, qn_b, selsrc, 1048576LL);
    addq_kernel<<<8192, 256, 0, stream>>>(selsrc, selpos, query);
    gemm_kernel<<<dim3(4, 256, 2), 256, 0, stream>>>(src, 4194304LL, wbf + W_VALUE, value_proj_b,
                                                     (float*)vproj, 4194304LL, HW_N, 256, 256, 0, 3, 0);
    gemm_kernel<<<dim3(4, 64, 2), 256, 0, stream>>>(query, 1048576LL, wbf + W_LATTN, lin_attn_b,
                                                    aw, 819200LL, NSEL, 200, 256, 0, 0, 0);
    gemm_kernel<<<dim3(1, 64, 2), 256, 0, stream>>>(query, 1048576LL, wbf + W_LBOX, lin_box_b,
                                                    obuf, 131072LL, NSEL, 32, 256, 0, 0, 0);
    gemm_kernel<<<dim3(7, 64, 2), 256, 0, stream>>>(query, 1048576LL, wbf + W_SOFF, samp_off_b,
                                                    dgrid, 1638400LL, NSEL, 400, 256, 0, 0, 0);
    boxattn_kernel<<<dim3(NSEL, 2), 256, 0, stream>>>(aw, obuf, dgrid, selref, vproj, kidx, boxout);
    gemm_kernel<<<dim3(4, 64, 2), 256, 0, stream>>>(boxout, 1048576LL, wbf + W_CAOUT, ca_out_b,
                                                    src2, 1048576LL, NSEL, 256, 256, 0, 0, 0);
    ln_kernel<<<dim3(NSEL, 2), 256, 0, stream>>>(selsrc, 1048576LL, src2, 1048576LL,
                                                 n1_g, n1_b, selsrc, 1048576LL);
    gemm_kernel<<<dim3(16, 64, 2), 256, 0, stream>>>(selsrc, 1048576LL, wbf + W_LIN1, lin1_b,
                                                     (float*)ffntb, 4194304LL, NSEL, DFF_, 256, 1, 1, 0);
    gemm_kernel<<<dim3(4, 64, 2), 256, 0, stream>>>(ffntb, 4194304LL, wbf + W_LIN2, lin2_b,
                                                    ff, 1048576LL, NSEL, 256, DFF_, 0, 0, 1);
    ln_kernel<<<dim3(NSEL, 2), 256, 0, stream>>>(selsrc, 1048576LL, ff, 1048576LL,
                                                 n2_g, n2_b, selsrc, 1048576LL);
    scatter_kernel<<<dim3(NSEL, 2), 256, 0, stream>>>(idxp, selsrc, out);
}

// Round 4
// 442.333 us; speedup vs baseline: 1.0641x; 1.0333x over previous
//
#include <hip/hip_runtime.h>
#include <hip/hip_bf16.h>
#include <math.h>

// Problem constants
#define HW_N   16384
#define DIM    256
#define NSEL   4096
#define NQ     1024
#define NHEAD  8
#define HD     32
#define NP_    25
#define DFF_   1024

// Workspace layout (float offsets). ~76 MB total.
#define OFF_SELREF  8448LL          // 2*4096*7
#define OFF_SELSRC  65792LL         // 2*4096*256
#define OFF_SELPOS  2162944LL       // 2*4096*256 (later reused as boxout)
#define OFF_QUERY   4260096LL       // 2*4096*256 (later reused as src2)
#define OFF_BIG     6357248LL       // vproj bf16 [0,4194304) then ffnt bf16 same slot
#define OFF_WBF     10551552LL      // OFF_BIG+4194304: bf16 weights, 1079296 bf16
#define OFF_F       14745856LL      // multi-use region, 5177344 floats

__device__ __forceinline__ unsigned int f2s(float f) {
    unsigned int u = __float_as_uint(f);
    return (u & 0x80000000u) ? ~u : (u | 0x80000000u);
}

typedef __bf16 bf16x8 __attribute__((ext_vector_type(8)));
typedef __bf16 bf16x4 __attribute__((ext_vector_type(4)));
typedef float  f32x4  __attribute__((ext_vector_type(4)));

// ============ weight preconversion: 9 fp32 matrices -> one bf16 pool ============
// Segments (elems): in_proj 196608 | mha_out 65536 | value 65536 | lin_attn 51200
// | lin_box 8192 | samp_off 102400 | ca_out 65536 | lin1 262144 | lin2 262144
extern "C" __global__ __launch_bounds__(256)
void wcvt_kernel(const float* __restrict__ s0, const float* __restrict__ s1,
                 const float* __restrict__ s2, const float* __restrict__ s3,
                 const float* __restrict__ s4, const float* __restrict__ s5,
                 const float* __restrict__ s6, const float* __restrict__ s7,
                 const float* __restrict__ s8, __hip_bfloat16* __restrict__ dst) {
    const long long g = (long long)blockIdx.x * 256 + threadIdx.x;
    const float* s; long long base;
    if      (g < 196608)  { s = s0; base = 0; }
    else if (g < 262144)  { s = s1; base = 196608; }
    else if (g < 327680)  { s = s2; base = 262144; }
    else if (g < 378880)  { s = s3; base = 327680; }
    else if (g < 387072)  { s = s4; base = 378880; }
    else if (g < 489472)  { s = s5; base = 387072; }
    else if (g < 555008)  { s = s6; base = 489472; }
    else if (g < 817152)  { s = s7; base = 555008; }
    else                  { s = s8; base = 817152; }
    dst[g] = __float2bfloat16(s[g - base]);
}

// ================= top-k, grid-parallel (4 kernels) =================
extern "C" __global__ __launch_bounds__(512)
void topk_hist_kernel(const float* __restrict__ score, unsigned int* __restrict__ hist) {
    const int t = threadIdx.x, bx = blockIdx.x, bb = blockIdx.y;
    const int i = bx * 512 + t;
    unsigned int u = f2s(score[(long long)bb * HW_N + i]);
    atomicAdd(&hist[bb * 8192 + (u >> 19)], 1u);
}

extern "C" __global__ __launch_bounds__(1024)
void topk_scan_kernel(const unsigned int* __restrict__ hist, unsigned int* __restrict__ ctrl) {
    __shared__ unsigned int scan[1024];
    const int t = threadIdx.x, bb = blockIdx.x;
    unsigned int loc[8]; unsigned int lsum = 0u;
    #pragma unroll
    for (int k = 0; k < 8; ++k) { loc[k] = hist[bb * 8192 + t * 8 + k]; lsum += loc[k]; }
    scan[t] = lsum;
    __syncthreads();
    for (int off = 1; off < 1024; off <<= 1) {
        unsigned int v = (t + off < 1024) ? scan[t + off] : 0u;
        __syncthreads();
        scan[t] += v;
        __syncthreads();
    }
    unsigned int nxt = (t < 1023) ? scan[t + 1] : 0u;
    unsigned int run = nxt;
    for (int k = 7; k >= 0; --k) {
        run += loc[k];
        unsigned int above = run - loc[k];
        if (run >= 1024u && above < 1024u) { ctrl[bb * 16 + 0] = (unsigned)(t * 8 + k); ctrl[bb * 16 + 1] = 1024u - above; }
        if (run >= 4096u && above < 4096u) { ctrl[bb * 16 + 2] = (unsigned)(t * 8 + k); ctrl[bb * 16 + 3] = 4096u - above; }
    }
}

extern "C" __global__ __launch_bounds__(1024)
void topk_collect_kernel(const float* __restrict__ score, unsigned int* __restrict__ ctrl,
                         unsigned long long* __restrict__ list1,
                         unsigned long long* __restrict__ list2) {
    const int t = threadIdx.x, bx = blockIdx.x, bb = blockIdx.y;
    const int i = bx * 1024 + t;
    const unsigned int T1 = ctrl[bb * 16 + 0], T2 = ctrl[bb * 16 + 2];
    unsigned int u = f2s(score[(long long)bb * HW_N + i]);
    unsigned int bin = u >> 19;
    unsigned long long key = ((unsigned long long)u << 32) | (unsigned int)(~(unsigned int)i);
    if (bin == T1) {
        unsigned int p = atomicAdd(&ctrl[bb * 16 + 4], 1u);
        if (p < 2048u) list1[bb * 2048 + p] = key;
    }
    if (bin == T2 && T2 != T1) {
        unsigned int p = atomicAdd(&ctrl[bb * 16 + 5], 1u);
        if (p < 2048u) list2[bb * 2048 + p] = key;
    }
}

extern "C" __global__ __launch_bounds__(1024)
void topk_classify_kernel(const float* __restrict__ score, unsigned int* __restrict__ ctrl,
                          const unsigned long long* __restrict__ list1,
                          const unsigned long long* __restrict__ list2,
                          int* __restrict__ idx_out) {
    __shared__ unsigned int cA, cB, baseA, baseB;
    const int t = threadIdx.x, bx = blockIdx.x, bb = blockIdx.y;
    const int i = bx * 1024 + t;
    if (t == 0) { cA = 0u; cB = 0u; }
    __syncthreads();
    const unsigned int T1 = ctrl[bb * 16 + 0], need1 = ctrl[bb * 16 + 1];
    const unsigned int T2 = ctrl[bb * 16 + 2], need2 = ctrl[bb * 16 + 3];
    const unsigned int c1 = min(ctrl[bb * 16 + 4], 2048u);
    const unsigned int c2 = min(ctrl[bb * 16 + 5], 2048u);
    unsigned int u = f2s(score[(long long)bb * HW_N + i]);
    unsigned int bin = u >> 19;
    unsigned long long key = ((unsigned long long)u << 32) | (unsigned int)(~(unsigned int)i);
    bool inA = false, inB = false;
    if (bin > T1) {
        inA = true;
    } else if (bin == T1) {
        unsigned int r = 0;
        for (unsigned int q = 0; q < c1; ++q) r += (list1[bb * 2048 + q] > key) ? 1u : 0u;
        if (r < need1) inA = true;
        else if (T2 == T1) inB = (r < need2);
        else inB = true;
    } else if (bin > T2) {
        inB = true;
    } else if (bin == T2) {
        unsigned int r = 0;
        for (unsigned int q = 0; q < c2; ++q) r += (list2[bb * 2048 + q] > key) ? 1u : 0u;
        inB = (r < need2);
    }
    unsigned int sA = 0u, sB = 0u;
    if (inA) sA = atomicAdd(&cA, 1u);
    if (inB) sB = atomicAdd(&cB, 1u);
    __syncthreads();
    if (t == 0) {
        baseA = atomicAdd(&ctrl[bb * 16 + 6], cA);
        baseB = atomicAdd(&ctrl[bb * 16 + 7], cB);
    }
    __syncthreads();
    if (inA) idx_out[bb * NSEL + baseA + sA] = i;
    if (inB) idx_out[bb * NSEL + 1024 + baseB + sB] = i;
}

// ---------------- gather selected rows ----------------
extern "C" __global__ __launch_bounds__(256)
void gather_kernel(const float* __restrict__ src, const float* __restrict__ pos,
                   const float* __restrict__ refw, const int* __restrict__ idx,
                   float* __restrict__ selsrc, float* __restrict__ selpos,
                   float* __restrict__ selref, float* __restrict__ qk) {
    const int s = blockIdx.x, bb = blockIdx.y, t = threadIdx.x;
    const int i = idx[bb * NSEL + s];
    const long long so = ((long long)(bb * NSEL + s)) * DIM;
    const long long go = ((long long)(bb * HW_N + i)) * DIM;
    float sv = src[go + t], pv = pos[go + t];
    selsrc[so + t] = sv;
    selpos[so + t] = pv;
    if (s < NQ) qk[((long long)(bb * NQ + s)) * DIM + t] = sv + pv;
    if (t < 7)
        selref[(long long)(bb * NSEL + s) * 7 + t] = refw[(long long)(bb * HW_N + i) * 7 + t];
}

// ---------------- bf16 MFMA GEMM: C = act(A @ W^T + bias) ----------------
// W: PRE-CONVERTED bf16 [N][K]. A: fp32 (amode 0) or bf16 (amode 1), [z][M][K].
// omode: 0 fp32 out; 1 bf16 flat; 2 bf16 transposed (col*M+row);
//        3 bf16 head-planar: off = zoff + ((col>>5)*16384 + row)*32 + (col&31).
extern "C" __global__ __launch_bounds__(256)
void gemm_kernel(const void* __restrict__ Avp, long long sA,
                 const __hip_bfloat16* __restrict__ W, const float* __restrict__ bias,
                 float* __restrict__ C, long long sC,
                 int M, int N, int K, int relu, int omode, int amode) {
    __shared__ __hip_bfloat16 As[64][72];
    __shared__ __hip_bfloat16 Ws[64][72];
    const int t = threadIdx.x;
    const int n0 = blockIdx.x * 64, m0 = blockIdx.y * 64;
    const long long zoff = (long long)blockIdx.z * sC;
    const int lane = t & 63, wv = t >> 6;
    const int mw = (wv >> 1) * 32, nw = (wv & 1) * 32;
    const int fr = lane & 15;
    const int fk = (lane >> 4) * 8;
    const int sr = t >> 2;
    const int sk = (t & 3) * 16;

    f32x4 acc[2][2];
    #pragma unroll
    for (int i = 0; i < 2; ++i)
        #pragma unroll
        for (int j = 0; j < 2; ++j) acc[i][j] = {0.f, 0.f, 0.f, 0.f};

    const bool wok = (n0 + sr) < N;
    for (int k0 = 0; k0 < K; k0 += 64) {
        // stage W: straight 32B bf16 copy
        uint4 wa = make_uint4(0u, 0u, 0u, 0u), wb = make_uint4(0u, 0u, 0u, 0u);
        if (wok) {
            const __hip_bfloat16* wp = W + (long long)(n0 + sr) * K + k0 + sk;
            wa = *(const uint4*)wp;
            wb = *(const uint4*)(wp + 8);
        }
        if (amode) {
            const __hip_bfloat16* ap = (const __hip_bfloat16*)Avp
                + (long long)blockIdx.z * sA + (long long)(m0 + sr) * K + k0 + sk;
            uint4 aa = *(const uint4*)ap;
            uint4 ab = *(const uint4*)(ap + 8);
            __syncthreads();
            *(uint4*)&As[sr][sk] = aa;
            *(uint4*)&As[sr][sk + 8] = ab;
            *(uint4*)&Ws[sr][sk] = wa;
            *(uint4*)&Ws[sr][sk + 8] = wb;
        } else {
            const float* ap = (const float*)Avp
                + (long long)blockIdx.z * sA + (long long)(m0 + sr) * K + k0 + sk;
            float av[16];
            #pragma unroll
            for (int q = 0; q < 4; ++q) {
                float4 v = *(const float4*)(ap + q * 4);
                av[q * 4 + 0] = v.x; av[q * 4 + 1] = v.y; av[q * 4 + 2] = v.z; av[q * 4 + 3] = v.w;
            }
            __syncthreads();
            #pragma unroll
            for (int q = 0; q < 16; ++q) As[sr][sk + q] = __float2bfloat16(av[q]);
            *(uint4*)&Ws[sr][sk] = wa;
            *(uint4*)&Ws[sr][sk + 8] = wb;
        }
        __syncthreads();
        #pragma unroll
        for (int kk = 0; kk < 64; kk += 32) {
            bf16x8 a0 = *(const bf16x8*)&As[mw + fr][kk + fk];
            bf16x8 a1 = *(const bf16x8*)&As[mw + 16 + fr][kk + fk];
            bf16x8 b0 = *(const bf16x8*)&Ws[nw + fr][kk + fk];
            bf16x8 b1 = *(const bf16x8*)&Ws[nw + 16 + fr][kk + fk];
            acc[0][0] = __builtin_amdgcn_mfma_f32_16x16x32_bf16(a0, b0, acc[0][0], 0, 0, 0);
            acc[0][1] = __builtin_amdgcn_mfma_f32_16x16x32_bf16(a0, b1, acc[0][1], 0, 0, 0);
            acc[1][0] = __builtin_amdgcn_mfma_f32_16x16x32_bf16(a1, b0, acc[1][0], 0, 0, 0);
            acc[1][1] = __builtin_amdgcn_mfma_f32_16x16x32_bf16(a1, b1, acc[1][1], 0, 0, 0);
        }
    }
    const int crow = (lane >> 4) * 4;
    #pragma unroll
    for (int mi = 0; mi < 2; ++mi) {
        #pragma unroll
        for (int ni = 0; ni < 2; ++ni) {
            const int col = n0 + nw + ni * 16 + fr;
            if (col < N) {
                const float bv = bias ? bias[col] : 0.f;
                #pragma unroll
                for (int r = 0; r < 4; ++r) {
                    const int row = m0 + mw + mi * 16 + crow + r;
                    float v = acc[mi][ni][r] + bv;
                    if (relu) v = fmaxf(v, 0.f);
                    if (omode == 0) {
                        C[zoff + (long long)row * N + col] = v;
                    } else if (omode == 1) {
                        ((__hip_bfloat16*)C)[zoff + (long long)row * N + col] = __float2bfloat16(v);
                    } else if (omode == 2) {
                        ((__hip_bfloat16*)C)[zoff + (long long)col * M + row] = __float2bfloat16(v);
                    } else {
                        ((__hip_bfloat16*)C)[zoff + ((long long)(col >> 5) * 16384 + row) * 32 + (col & 31)]
                            = __float2bfloat16(v);
                    }
                }
            }
        }
    }
}

// ---------------- MHA via MFMA: 16 queries/block, S & softmax in registers ----
// Rework vs previous: (1) kf loads batched 8-deep + sched_barrier(0) before
// the MFMA cluster (same MLP fix that took boxattn off the top-5);
// (2) PV preloads pf+v in groups of 4 ks + sched_barrier(0);
// (3) softmax stores e=exp(s-mx) in-place, rescale with ONE __expf per row
// (removes ~64 expf/thread); (4) pb and redo share one LDS buffer
// (42.5KB -> ~33.8KB => 4 blocks/CU instead of 3; extra barrier guards the
// pb-read -> redo-write reuse).
extern "C" __global__ __launch_bounds__(256, 4)
void attn_kernel(const __hip_bfloat16* __restrict__ qkb,
                 const __hip_bfloat16* __restrict__ vT,
                 float* __restrict__ attout) {
    __shared__ float sbuf[8256];                 // 33024 B: pb (bf16 16x1032) / redo union
    __shared__ float redm[4][16];
    __shared__ float reds[4][16];
    __hip_bfloat16 (*pb)[1032] = (__hip_bfloat16 (*)[1032])sbuf;
    float (*redo)[16][33] = (float (*)[16][33])sbuf;
    const int t = threadIdx.x;
    const int qt = blockIdx.x, h = blockIdx.y, bb = blockIdx.z;
    const int q0 = qt * 16;
    const int lane = t & 63, wv = t >> 6;
    const int fr = lane & 15, g = lane >> 4;
    const int kbase = wv * 256;
    const float scale = 0.17677669529663687f;

    bf16x8 qfrag = *(const bf16x8*)(qkb + ((long long)(bb * NQ + q0 + fr)) * 512 + h * HD + g * 8);

    f32x4 sfr[16];
    #pragma unroll
    for (int half = 0; half < 2; ++half) {
        bf16x8 kf[8];
        #pragma unroll
        for (int j = 0; j < 8; ++j) {
            const int key0 = kbase + (half * 8 + j) * 16;
            kf[j] = *(const bf16x8*)(qkb + ((long long)(bb * NQ + key0 + fr)) * 512 + 256 + h * HD + g * 8);
        }
        __builtin_amdgcn_sched_barrier(0);   // all 8 loads in flight before first use
        #pragma unroll
        for (int j = 0; j < 8; ++j) {
            f32x4 z = {0.f, 0.f, 0.f, 0.f};
            sfr[half * 8 + j] = __builtin_amdgcn_mfma_f32_16x16x32_bf16(qfrag, kf[j], z, 0, 0, 0);
        }
    }
    #pragma unroll
    for (int kt = 0; kt < 16; ++kt)
        #pragma unroll
        for (int r = 0; r < 4; ++r) sfr[kt][r] *= scale;

    float mxr[4];
    #pragma unroll
    for (int r = 0; r < 4; ++r) {
        float mx = -1e30f;
        #pragma unroll
        for (int kt = 0; kt < 16; ++kt) mx = fmaxf(mx, sfr[kt][r]);
        #pragma unroll
        for (int mm = 1; mm <= 8; mm <<= 1) mx = fmaxf(mx, __shfl_xor(mx, mm, 64));
        float sm = 0.f;
        #pragma unroll
        for (int kt = 0; kt < 16; ++kt) {
            float e = __expf(sfr[kt][r] - mx);
            sfr[kt][r] = e;                 // keep e, rescale later
            sm += e;
        }
        #pragma unroll
        for (int mm = 1; mm <= 8; mm <<= 1) sm += __shfl_xor(sm, mm, 64);
        mxr[r] = mx;
        if (fr == 0) { redm[wv][4 * g + r] = mx; reds[wv][4 * g + r] = sm; }
    }
    __syncthreads();

    float scl[4];
    #pragma unroll
    for (int r = 0; r < 4; ++r) {
        const int q = 4 * g + r;
        float mm = fmaxf(fmaxf(redm[0][q], redm[1][q]), fmaxf(redm[2][q], redm[3][q]));
        float ll = 0.f;
        #pragma unroll
        for (int w2 = 0; w2 < 4; ++w2) ll += reds[w2][q] * __expf(redm[w2][q] - mm);
        scl[r] = __expf(mxr[r] - mm) / ll;   // e * scl == exp(s-gm)*gl
    }
    #pragma unroll
    for (int kt = 0; kt < 16; ++kt) {
        #pragma unroll
        for (int r = 0; r < 4; ++r) {
            pb[4 * g + r][kbase + kt * 16 + fr] = __float2bfloat16(sfr[kt][r] * scl[r]);
        }
    }

    f32x4 o0 = {0.f, 0.f, 0.f, 0.f}, o1 = {0.f, 0.f, 0.f, 0.f};
    const __hip_bfloat16* vbase = vT + ((long long)bb * DIM + h * HD) * 1024;
    #pragma unroll
    for (int ksb = 0; ksb < 2; ++ksb) {
        bf16x8 pf[4], v0[4], v1[4];
        #pragma unroll
        for (int j = 0; j < 4; ++j) {
            const int key0 = kbase + (ksb * 4 + j) * 32 + g * 8;
            pf[j] = *(const bf16x8*)&pb[fr][key0];
            v0[j] = *(const bf16x8*)(vbase + (long long)fr * 1024 + key0);
            v1[j] = *(const bf16x8*)(vbase + (long long)(16 + fr) * 1024 + key0);
        }
        __builtin_amdgcn_sched_barrier(0);   // 8 global + 4 LDS loads in flight
        #pragma unroll
        for (int j = 0; j < 4; ++j) {
            o0 = __builtin_amdgcn_mfma_f32_16x16x32_bf16(pf[j], v0[j], o0, 0, 0, 0);
            o1 = __builtin_amdgcn_mfma_f32_16x16x32_bf16(pf[j], v1[j], o1, 0, 0, 0);
        }
    }

    __syncthreads();   // all waves done reading pb before redo overwrites it
    #pragma unroll
    for (int r = 0; r < 4; ++r) {
        redo[wv][4 * g + r][fr] = o0[r];
        redo[wv][4 * g + r][16 + fr] = o1[r];
    }
    __syncthreads();
    #pragma unroll
    for (int i = 0; i < 2; ++i) {
        const int idx = t + i * 256;
        const int q = idx >> 5, d = idx & 31;
        float v = redo[0][q][d] + redo[1][q][d] + redo[2][q][d] + redo[3][q][d];
        attout[((long long)(bb * NQ + q0 + q)) * DIM + h * HD + d] = v;
    }
}

// ---------------- residual + LayerNorm (in-place capable) ----------------
extern "C" __global__ __launch_bounds__(256)
void ln_kernel(const float* __restrict__ X, long long sx,
               const float* __restrict__ R, long long sr,
               const float* __restrict__ g, const float* __restrict__ bta,
               float* __restrict__ O, long long so) {
    __shared__ float red[4];
    const int row = blockIdx.x, bb = blockIdx.y, t = threadIdx.x;
    float x = X[(long long)bb * sx + (long long)row * DIM + t]
            + R[(long long)bb * sr + (long long)row * DIM + t];
    float v = x;
    #pragma unroll
    for (int m = 32; m >= 1; m >>= 1) v += __shfl_xor(v, m, 64);
    if ((t & 63) == 0) red[t >> 6] = v;
    __syncthreads();
    float mean = (red[0] + red[1] + red[2] + red[3]) * (1.f / 256.f);
    __syncthreads();
    float d = x - mean;
    v = d * d;
    #pragma unroll
    for (int m = 32; m >= 1; m >>= 1) v += __shfl_xor(v, m, 64);
    if ((t & 63) == 0) red[t >> 6] = v;
    __syncthreads();
    float var = (red[0] + red[1] + red[2] + red[3]) * (1.f / 256.f);
    O[(long long)bb * so + (long long)row * DIM + t] = d * rsqrtf(var + 1e-5f) * g[t] + bta[t];
}

// ---------------- query = selsrc + selpos ----------------
extern "C" __global__ __launch_bounds__(256)
void addq_kernel(const float* __restrict__ a, const float* __restrict__ b2, float* __restrict__ o) {
    long long i = (long long)blockIdx.x * 256 + threadIdx.x;
    o[i] = a[i] + b2[i];
}

// ---------------- box attention ----------------
// vp is HEAD-PLANAR bf16: vp[((b*8+h)*16384 + pix)*32 + ch].
// Phase B: 8 lanes/head x bf16x4 loads; 4 waves split the 100 (p,corner) pairs.
// The 25 gathers are forced fully in-flight: preload addresses+weights from
// LDS to registers, issue ALL 25 global loads, then a sched_barrier(0) fence
// before the FMA block.
extern "C" __global__ __launch_bounds__(256)
void boxattn_kernel(const float* __restrict__ aw, const float* __restrict__ ob,
                    const float* __restrict__ dgrid, const float* __restrict__ selref,
                    const __hip_bfloat16* __restrict__ vp, const float* __restrict__ kidx,
                    float* __restrict__ boxout) {
    __shared__ float aw_s[200];
    __shared__ float ob_s[32];
    __shared__ float ref_s[7];
    __shared__ float ki_s[50];
    __shared__ float box_s[8][6];
    __shared__ float mx_s[8];
    __shared__ float inv_s[8];
    __shared__ float wq_s[200];
    __shared__ int   i4_s[800];
    __shared__ float w4_s[800];
    __shared__ float red4[4][8][32];
    const int t = threadIdx.x;
    const int s = blockIdx.x, bb = blockIdx.y;
    const long long base = (long long)(bb * NSEL + s);
    if (t < 200) aw_s[t] = aw[base * 200 + t];
    if (t < 32)  ob_s[t] = ob[base * 32 + t];
    if (t < 7)   ref_s[t] = selref[base * 7 + t];
    if (t < 50)  ki_s[t] = kidx[t];
    __syncthreads();

    if (t < 8) {
        float mx = -1e30f;
        #pragma unroll
        for (int p = 0; p < NP_; ++p) mx = fmaxf(mx, aw_s[t * NP_ + p]);
        mx_s[t] = mx;
        const float r0 = ref_s[0], r1 = ref_s[1], r3 = ref_s[3], r4 = ref_s[4], r6 = ref_s[6];
        box_s[t][0] = r0 + ob_s[t * 4 + 0] * 0.125f * r3;
        box_s[t][1] = r1 + ob_s[t * 4 + 1] * 0.125f * r4;
        box_s[t][2] = fmaxf(r3 + ob_s[t * 4 + 2] * 0.125f * r3, 0.f);
        box_s[t][3] = fmaxf(r4 + ob_s[t * 4 + 3] * 0.125f * r4, 0.f);
        box_s[t][4] = cosf(r6);
        box_s[t][5] = sinf(r6);
    }
    __syncthreads();

    if (t < 200) {
        const int h = t / NP_, p = t - h * NP_;
        const float w = expf(aw_s[t] - mx_s[h]);
        wq_s[t] = w;
        const float cx = box_s[h][0], cy = box_s[h][1];
        const float sw = box_s[h][2], sh = box_s[h][3];
        const float ca = box_s[h][4], sa = box_s[h][5];
        const float fx = ki_s[p * 2 + 0] * sw;
        const float fy = ki_s[p * 2 + 1] * sh;
        const float gx = cx + ca * fx - sa * fy + dgrid[base * 400 + 2 * t + 0] * (1.f / 188.f);
        const float gy = cy + sa * fx + ca * fy + dgrid[base * 400 + 2 * t + 1] * (1.f / 188.f);
        const float x = gx * 128.f - 0.5f;
        const float y = gy * 128.f - 0.5f;
        const float x0f = floorf(x), y0f = floorf(y);
        const float lx = x - x0f, ly = y - y0f;
        const int x0 = (int)x0f, y0 = (int)y0f;
        #pragma unroll
        for (int c = 0; c < 4; ++c) {
            const int xi = x0 + (c & 1);
            const int yi = y0 + (c >> 1);
            const float wgt = ((c & 1) ? lx : 1.f - lx) * ((c >> 1) ? ly : 1.f - ly);
            const bool valid = (xi >= 0) & (xi < 128) & (yi >= 0) & (yi < 128);
            const int cxi = min(max(xi, 0), 127);
            const int cyi = min(max(yi, 0), 127);
            i4_s[t * 4 + c] = cyi * 128 + cxi;
            w4_s[t * 4 + c] = w * (valid ? wgt : 0.f);
        }
    }
    __syncthreads();
    if (t < 8) {
        float sm = 0.f;
        #pragma unroll
        for (int p = 0; p < NP_; ++p) sm += wq_s[t * NP_ + p];
        inv_s[t] = 1.f / sm;
    }
    __syncthreads();

    // phase B: preload addr/weight, force-issue all 25 loads, fence, accumulate
    {
        const int lane = t & 63, wv = t >> 6;
        const int h2 = lane >> 3, q = lane & 7;
        const __hip_bfloat16* vb = vp + ((long long)(bb * 8 + h2) * 16384) * 32 + q * 4;
        int   pix[25];
        float wls[25];
        #pragma unroll
        for (int u = 0; u < 25; ++u) {
            const int e = h2 * 100 + wv + u * 4;
            pix[u] = i4_s[e];
            wls[u] = w4_s[e];
        }
        bf16x4 vv[25];
        #pragma unroll
        for (int u = 0; u < 25; ++u)
            vv[u] = *(const bf16x4*)(vb + (long long)pix[u] * 32);
        __builtin_amdgcn_sched_barrier(0);   // all 25 loads issued before any use
        float a0 = 0.f, a1 = 0.f, a2 = 0.f, a3 = 0.f;
        #pragma unroll
        for (int u = 0; u < 25; ++u) {
            a0 += wls[u] * (float)vv[u][0];
            a1 += wls[u] * (float)vv[u][1];
            a2 += wls[u] * (float)vv[u][2];
            a3 += wls[u] * (float)vv[u][3];
        }
        red4[wv][h2][q * 4 + 0] = a0;
        red4[wv][h2][q * 4 + 1] = a1;
        red4[wv][h2][q * 4 + 2] = a2;
        red4[wv][h2][q * 4 + 3] = a3;
    }
    __syncthreads();
    {
        const int h = t >> 5, d = t & 31;
        float v = red4[0][h][d] + red4[1][h][d] + red4[2][h][d] + red4[3][h][d];
        boxout[base * DIM + h * HD + d] = v * inv_s[h];
    }
}

// ---------------- scatter final rows back into out ----------------
extern "C" __global__ __launch_bounds__(256)
void scatter_kernel(const int* __restrict__ idx, const float* __restrict__ sel,
                    float* __restrict__ out) {
    const int s = blockIdx.x, bb = blockIdx.y, t = threadIdx.x;
    const int i = idx[bb * NSEL + s];
    out[((long long)(bb * HW_N + i)) * DIM + t] = sel[((long long)(bb * NSEL + s)) * DIM + t];
}

extern "C" void kernel_launch(void* const* d_in, const int* in_sizes, int n_in,
                              void* d_out, int out_size, void* d_ws, size_t ws_size,
                              hipStream_t stream) {
    const float* src          = (const float*)d_in[0];
    const float* pos          = (const float*)d_in[1];
    const float* refw         = (const float*)d_in[4];
    const float* score        = (const float*)d_in[5];
    const float* in_proj_w    = (const float*)d_in[6];
    const float* in_proj_b    = (const float*)d_in[7];
    const float* mha_out_w    = (const float*)d_in[8];
    const float* mha_out_b    = (const float*)d_in[9];
    const float* value_proj_w = (const float*)d_in[10];
    const float* value_proj_b = (const float*)d_in[11];
    const float* lin_attn_w   = (const float*)d_in[12];
    const float* lin_attn_b   = (const float*)d_in[13];
    const float* lin_box_w    = (const float*)d_in[14];
    const float* lin_box_b    = (const float*)d_in[15];
    const float* samp_off_w   = (const float*)d_in[16];
    const float* samp_off_b   = (const float*)d_in[17];
    const float* ca_out_w     = (const float*)d_in[18];
    const float* ca_out_b     = (const float*)d_in[19];
    const float* lin1_w       = (const float*)d_in[20];
    const float* lin1_b       = (const float*)d_in[21];
    const float* lin2_w       = (const float*)d_in[22];
    const float* lin2_b       = (const float*)d_in[23];
    const float* qn_g         = (const float*)d_in[24];
    const float* qn_b         = (const float*)d_in[25];
    const float* n1_g         = (const float*)d_in[26];
    const float* n1_b         = (const float*)d_in[27];
    const float* n2_g         = (const float*)d_in[28];
    const float* n2_b         = (const float*)d_in[29];
    const float* kidx         = (const float*)d_in[30];

    float* w = (float*)d_ws;
    int* idxp = (int*)d_ws;
    float* selref = w + OFF_SELREF;
    float* selsrc = w + OFF_SELSRC;
    float* selpos = w + OFF_SELPOS;
    float* boxout = w + OFF_SELPOS;   // reuse after selpos dead
    float* query  = w + OFF_QUERY;
    float* src2   = w + OFF_QUERY;    // reuse after query dead
    __hip_bfloat16* vproj  = (__hip_bfloat16*)(w + OFF_BIG);   // head-planar bf16
    __hip_bfloat16* ffntb  = (__hip_bfloat16*)(w + OFF_BIG);   // reuse after vproj dead
    __hip_bfloat16* wbf    = (__hip_bfloat16*)(w + OFF_WBF);   // bf16 weight pool
    float* qk     = w + OFF_F;
    __hip_bfloat16* qkb = (__hip_bfloat16*)(w + OFF_F + 524288);
    __hip_bfloat16* vT  = (__hip_bfloat16*)(w + OFF_F + 1572864);
    float* attout = w + OFF_F + 2097152;
    float* q2     = w + OFF_F + 2621440;
    float* aw     = w + OFF_F;              // reuse after MHA dead
    float* obuf   = w + OFF_F + 1638400;
    float* dgrid  = w + OFF_F + 1900544;
    float* ff     = w + OFF_F;              // reuse after box-attn dead
    unsigned int* hist2 = (unsigned int*)(w + OFF_F);          // topk scratch
    unsigned int* ctrl2 = hist2 + 16384;
    unsigned long long* list1 = (unsigned long long*)(hist2 + 16448);
    unsigned long long* list2 = list1 + 2 * 2048;
    float* out    = (float*)d_out;

    // bf16 weight pool offsets
    const long long W_INPROJ = 0, W_MHAOUT = 196608, W_VALUE = 262144,
                    W_LATTN = 327680, W_LBOX = 378880, W_SOFF = 387072,
                    W_CAOUT = 489472, W_LIN1 = 555008, W_LIN2 = 817152;

    hipMemcpyAsync(d_out, src, (size_t)2 * HW_N * DIM * sizeof(float),
                   hipMemcpyDeviceToDevice, stream);

    wcvt_kernel<<<4216, 256, 0, stream>>>(in_proj_w, mha_out_w, value_proj_w,
                                          lin_attn_w, lin_box_w, samp_off_w,
                                          ca_out_w, lin1_w, lin2_w, wbf);

    hipMemsetAsync(hist2, 0, 16448 * sizeof(unsigned int), stream);
    topk_hist_kernel<<<dim3(32, 2), 512, 0, stream>>>(score, hist2);
    topk_scan_kernel<<<2, 1024, 0, stream>>>(hist2, ctrl2);
    topk_collect_kernel<<<dim3(16, 2), 1024, 0, stream>>>(score, ctrl2, list1, list2);
    topk_classify_kernel<<<dim3(16, 2), 1024, 0, stream>>>(score, ctrl2, list1, list2, idxp);

    gather_kernel<<<dim3(NSEL, 2), 256, 0, stream>>>(src, pos, refw, idxp,
                                                     selsrc, selpos, selref, qk);
    gemm_kernel<<<dim3(8, 16, 2), 256, 0, stream>>>(qk, 262144LL, wbf + W_INPROJ, in_proj_b,
                                                    (float*)qkb, 524288LL, NQ, 512, 256, 0, 1, 0);
    gemm_kernel<<<dim3(4, 16, 2), 256, 0, stream>>>(selsrc, 1048576LL, wbf + W_INPROJ + 512 * 256,
                                                    in_proj_b + 512, (float*)vT, 262144LL, NQ, 256, 256, 0, 2, 0);
    attn_kernel<<<dim3(64, 8, 2), 256, 0, stream>>>(qkb, vT, attout);
    gemm_kernel<<<dim3(4, 16, 2), 256, 0, stream>>>(attout, 262144LL, wbf + W_MHAOUT, mha_out_b,
                                                    q2, 262144LL, NQ, 256, 256, 0, 0, 0);
    ln_kernel<<<dim3(NQ, 2), 256, 0, stream>>>(selsrc, 1048576LL, q2, 262144LL,
                                               qn_g, qn_b, selsrc, 1048576LL);
    addq_kernel<<<8192, 256, 0, stream>>>(selsrc, selpos, query);
    gemm_kernel<<<dim3(4, 256, 2), 256, 0, stream>>>(src, 4194304LL, wbf + W_VALUE, value_proj_b,
                                                     (float*)vproj, 4194304LL, HW_N, 256, 256, 0, 3, 0);
    gemm_kernel<<<dim3(4, 64, 2), 256, 0, stream>>>(query, 1048576LL, wbf + W_LATTN, lin_attn_b,
                                                    aw, 819200LL, NSEL, 200, 256, 0, 0, 0);
    gemm_kernel<<<dim3(1, 64, 2), 256, 0, stream>>>(query, 1048576LL, wbf + W_LBOX, lin_box_b,
                                                    obuf, 131072LL, NSEL, 32, 256, 0, 0, 0);
    gemm_kernel<<<dim3(7, 64, 2), 256, 0, stream>>>(query, 1048576LL, wbf + W_SOFF, samp_off_b,
                                                    dgrid, 1638400LL, NSEL, 400, 256, 0, 0, 0);
    boxattn_kernel<<<dim3(NSEL, 2), 256, 0, stream>>>(aw, obuf, dgrid, selref, vproj, kidx, boxout);
    gemm_kernel<<<dim3(4, 64, 2), 256, 0, stream>>>(boxout, 1048576LL, wbf + W_CAOUT, ca_out_b,
                                                    src2, 1048576LL, NSEL, 256, 256, 0, 0, 0);
    ln_kernel<<<dim3(NSEL, 2), 256, 0, stream>>>(selsrc, 1048576LL, src2, 1048576LL,
                                                 n1_g, n1_b, selsrc, 1048576LL);
    gemm_kernel<<<dim3(16, 64, 2), 256, 0, stream>>>(selsrc, 1048576LL, wbf + W_LIN1, lin1_b,
                                                     (float*)ffntb, 4194304LL, NSEL, DFF_, 256, 1, 1, 0);
    gemm_kernel<<<dim3(4, 64, 2), 256, 0, stream>>>(ffntb, 4194304LL, wbf + W_LIN2, lin2_b,
                                                    ff, 1048576LL, NSEL, 256, DFF_, 0, 0, 1);
    ln_kernel<<<dim3(NSEL, 2), 256, 0, stream>>>(selsrc, 1048576LL, ff, 1048576LL,
                                                 n2_g, n2_b, selsrc, 1048576LL);
    scatter_kernel<<<dim3(NSEL, 2), 256, 0, stream>>>(idxp, selsrc, out);
}

// Round 5
// 437.185 us; speedup vs baseline: 1.0766x; 1.0118x over previous
//
#include <hip/hip_runtime.h>
#include <hip/hip_bf16.h>
#include <math.h>

// Problem constants
#define HW_N   16384
#define DIM    256
#define NSEL   4096
#define NQ     1024
#define NHEAD  8
#define HD     32
#define NP_    25
#define DFF_   1024

// Workspace layout (float offsets). ~76 MB total.
#define OFF_SELREF  8448LL          // 2*4096*7
#define OFF_SELSRC  65792LL         // 2*4096*256
#define OFF_SELPOS  2162944LL       // 2*4096*256 (later reused as boxout)
#define OFF_QUERY   4260096LL       // 2*4096*256 (later reused as src2)
#define OFF_BIG     6357248LL       // vproj bf16 [0,4194304) then ffnt bf16 same slot
#define OFF_WBF     10551552LL      // OFF_BIG+4194304: bf16 weights, 1079296 bf16
#define OFF_F       14745856LL      // multi-use region, 5177344 floats

__device__ __forceinline__ unsigned int f2s(float f) {
    unsigned int u = __float_as_uint(f);
    return (u & 0x80000000u) ? ~u : (u | 0x80000000u);
}

typedef __bf16 bf16x8 __attribute__((ext_vector_type(8)));
typedef __bf16 bf16x4 __attribute__((ext_vector_type(4)));
typedef float  f32x4  __attribute__((ext_vector_type(4)));

// ============ weight preconversion: 9 fp32 matrices -> one bf16 pool ============
// Segments (elems): in_proj 196608 | mha_out 65536 | value 65536 | lin_attn 51200
// | lin_box 8192 | samp_off 102400 | ca_out 65536 | lin1 262144 | lin2 262144
extern "C" __global__ __launch_bounds__(256)
void wcvt_kernel(const float* __restrict__ s0, const float* __restrict__ s1,
                 const float* __restrict__ s2, const float* __restrict__ s3,
                 const float* __restrict__ s4, const float* __restrict__ s5,
                 const float* __restrict__ s6, const float* __restrict__ s7,
                 const float* __restrict__ s8, __hip_bfloat16* __restrict__ dst) {
    const long long g = (long long)blockIdx.x * 256 + threadIdx.x;
    const float* s; long long base;
    if      (g < 196608)  { s = s0; base = 0; }
    else if (g < 262144)  { s = s1; base = 196608; }
    else if (g < 327680)  { s = s2; base = 262144; }
    else if (g < 378880)  { s = s3; base = 327680; }
    else if (g < 387072)  { s = s4; base = 378880; }
    else if (g < 489472)  { s = s5; base = 387072; }
    else if (g < 555008)  { s = s6; base = 489472; }
    else if (g < 817152)  { s = s7; base = 555008; }
    else                  { s = s8; base = 817152; }
    dst[g] = __float2bfloat16(s[g - base]);
}

// ================= top-k, grid-parallel (4 kernels) =================
extern "C" __global__ __launch_bounds__(512)
void topk_hist_kernel(const float* __restrict__ score, unsigned int* __restrict__ hist) {
    const int t = threadIdx.x, bx = blockIdx.x, bb = blockIdx.y;
    const int i = bx * 512 + t;
    unsigned int u = f2s(score[(long long)bb * HW_N + i]);
    atomicAdd(&hist[bb * 8192 + (u >> 19)], 1u);
}

extern "C" __global__ __launch_bounds__(1024)
void topk_scan_kernel(const unsigned int* __restrict__ hist, unsigned int* __restrict__ ctrl) {
    __shared__ unsigned int scan[1024];
    const int t = threadIdx.x, bb = blockIdx.x;
    unsigned int loc[8]; unsigned int lsum = 0u;
    #pragma unroll
    for (int k = 0; k < 8; ++k) { loc[k] = hist[bb * 8192 + t * 8 + k]; lsum += loc[k]; }
    scan[t] = lsum;
    __syncthreads();
    for (int off = 1; off < 1024; off <<= 1) {
        unsigned int v = (t + off < 1024) ? scan[t + off] : 0u;
        __syncthreads();
        scan[t] += v;
        __syncthreads();
    }
    unsigned int nxt = (t < 1023) ? scan[t + 1] : 0u;
    unsigned int run = nxt;
    for (int k = 7; k >= 0; --k) {
        run += loc[k];
        unsigned int above = run - loc[k];
        if (run >= 1024u && above < 1024u) { ctrl[bb * 16 + 0] = (unsigned)(t * 8 + k); ctrl[bb * 16 + 1] = 1024u - above; }
        if (run >= 4096u && above < 4096u) { ctrl[bb * 16 + 2] = (unsigned)(t * 8 + k); ctrl[bb * 16 + 3] = 4096u - above; }
    }
}

extern "C" __global__ __launch_bounds__(1024)
void topk_collect_kernel(const float* __restrict__ score, unsigned int* __restrict__ ctrl,
                         unsigned long long* __restrict__ list1,
                         unsigned long long* __restrict__ list2) {
    const int t = threadIdx.x, bx = blockIdx.x, bb = blockIdx.y;
    const int i = bx * 1024 + t;
    const unsigned int T1 = ctrl[bb * 16 + 0], T2 = ctrl[bb * 16 + 2];
    unsigned int u = f2s(score[(long long)bb * HW_N + i]);
    unsigned int bin = u >> 19;
    unsigned long long key = ((unsigned long long)u << 32) | (unsigned int)(~(unsigned int)i);
    if (bin == T1) {
        unsigned int p = atomicAdd(&ctrl[bb * 16 + 4], 1u);
        if (p < 2048u) list1[bb * 2048 + p] = key;
    }
    if (bin == T2 && T2 != T1) {
        unsigned int p = atomicAdd(&ctrl[bb * 16 + 5], 1u);
        if (p < 2048u) list2[bb * 2048 + p] = key;
    }
}

extern "C" __global__ __launch_bounds__(1024)
void topk_classify_kernel(const float* __restrict__ score, unsigned int* __restrict__ ctrl,
                          const unsigned long long* __restrict__ list1,
                          const unsigned long long* __restrict__ list2,
                          int* __restrict__ idx_out) {
    __shared__ unsigned int cA, cB, baseA, baseB;
    const int t = threadIdx.x, bx = blockIdx.x, bb = blockIdx.y;
    const int i = bx * 1024 + t;
    if (t == 0) { cA = 0u; cB = 0u; }
    __syncthreads();
    const unsigned int T1 = ctrl[bb * 16 + 0], need1 = ctrl[bb * 16 + 1];
    const unsigned int T2 = ctrl[bb * 16 + 2], need2 = ctrl[bb * 16 + 3];
    const unsigned int c1 = min(ctrl[bb * 16 + 4], 2048u);
    const unsigned int c2 = min(ctrl[bb * 16 + 5], 2048u);
    unsigned int u = f2s(score[(long long)bb * HW_N + i]);
    unsigned int bin = u >> 19;
    unsigned long long key = ((unsigned long long)u << 32) | (unsigned int)(~(unsigned int)i);
    bool inA = false, inB = false;
    if (bin > T1) {
        inA = true;
    } else if (bin == T1) {
        unsigned int r = 0;
        for (unsigned int q = 0; q < c1; ++q) r += (list1[bb * 2048 + q] > key) ? 1u : 0u;
        if (r < need1) inA = true;
        else if (T2 == T1) inB = (r < need2);
        else inB = true;
    } else if (bin > T2) {
        inB = true;
    } else if (bin == T2) {
        unsigned int r = 0;
        for (unsigned int q = 0; q < c2; ++q) r += (list2[bb * 2048 + q] > key) ? 1u : 0u;
        inB = (r < need2);
    }
    unsigned int sA = 0u, sB = 0u;
    if (inA) sA = atomicAdd(&cA, 1u);
    if (inB) sB = atomicAdd(&cB, 1u);
    __syncthreads();
    if (t == 0) {
        baseA = atomicAdd(&ctrl[bb * 16 + 6], cA);
        baseB = atomicAdd(&ctrl[bb * 16 + 7], cB);
    }
    __syncthreads();
    if (inA) idx_out[bb * NSEL + baseA + sA] = i;
    if (inB) idx_out[bb * NSEL + 1024 + baseB + sB] = i;
}

// ---------------- gather selected rows ----------------
extern "C" __global__ __launch_bounds__(256)
void gather_kernel(const float* __restrict__ src, const float* __restrict__ pos,
                   const float* __restrict__ refw, const int* __restrict__ idx,
                   float* __restrict__ selsrc, float* __restrict__ selpos,
                   float* __restrict__ selref, float* __restrict__ qk) {
    const int s = blockIdx.x, bb = blockIdx.y, t = threadIdx.x;
    const int i = idx[bb * NSEL + s];
    const long long so = ((long long)(bb * NSEL + s)) * DIM;
    const long long go = ((long long)(bb * HW_N + i)) * DIM;
    float sv = src[go + t], pv = pos[go + t];
    selsrc[so + t] = sv;
    selpos[so + t] = pv;
    if (s < NQ) qk[((long long)(bb * NQ + s)) * DIM + t] = sv + pv;
    if (t < 7)
        selref[(long long)(bb * NSEL + s) * 7 + t] = refw[(long long)(bb * HW_N + i) * 7 + t];
}

// ---------------- bf16 MFMA GEMM: C = act(A @ W^T + bias) ----------------
// W: PRE-CONVERTED bf16 [N][K]. A: fp32 (amode 0) or bf16 (amode 1), [z][M][K].
// omode: 0 fp32 out; 1 bf16 flat; 2 bf16 transposed (col*M+row);
//        3 bf16 head-planar: off = zoff + ((col>>5)*16384 + row)*32 + (col&31).
extern "C" __global__ __launch_bounds__(256)
void gemm_kernel(const void* __restrict__ Avp, long long sA,
                 const __hip_bfloat16* __restrict__ W, const float* __restrict__ bias,
                 float* __restrict__ C, long long sC,
                 int M, int N, int K, int relu, int omode, int amode) {
    __shared__ __hip_bfloat16 As[64][72];
    __shared__ __hip_bfloat16 Ws[64][72];
    const int t = threadIdx.x;
    const int n0 = blockIdx.x * 64, m0 = blockIdx.y * 64;
    const long long zoff = (long long)blockIdx.z * sC;
    const int lane = t & 63, wv = t >> 6;
    const int mw = (wv >> 1) * 32, nw = (wv & 1) * 32;
    const int fr = lane & 15;
    const int fk = (lane >> 4) * 8;
    const int sr = t >> 2;
    const int sk = (t & 3) * 16;

    f32x4 acc[2][2];
    #pragma unroll
    for (int i = 0; i < 2; ++i)
        #pragma unroll
        for (int j = 0; j < 2; ++j) acc[i][j] = {0.f, 0.f, 0.f, 0.f};

    const bool wok = (n0 + sr) < N;
    for (int k0 = 0; k0 < K; k0 += 64) {
        // stage W: straight 32B bf16 copy
        uint4 wa = make_uint4(0u, 0u, 0u, 0u), wb = make_uint4(0u, 0u, 0u, 0u);
        if (wok) {
            const __hip_bfloat16* wp = W + (long long)(n0 + sr) * K + k0 + sk;
            wa = *(const uint4*)wp;
            wb = *(const uint4*)(wp + 8);
        }
        if (amode) {
            const __hip_bfloat16* ap = (const __hip_bfloat16*)Avp
                + (long long)blockIdx.z * sA + (long long)(m0 + sr) * K + k0 + sk;
            uint4 aa = *(const uint4*)ap;
            uint4 ab = *(const uint4*)(ap + 8);
            __syncthreads();
            *(uint4*)&As[sr][sk] = aa;
            *(uint4*)&As[sr][sk + 8] = ab;
            *(uint4*)&Ws[sr][sk] = wa;
            *(uint4*)&Ws[sr][sk + 8] = wb;
        } else {
            const float* ap = (const float*)Avp
                + (long long)blockIdx.z * sA + (long long)(m0 + sr) * K + k0 + sk;
            float av[16];
            #pragma unroll
            for (int q = 0; q < 4; ++q) {
                float4 v = *(const float4*)(ap + q * 4);
                av[q * 4 + 0] = v.x; av[q * 4 + 1] = v.y; av[q * 4 + 2] = v.z; av[q * 4 + 3] = v.w;
            }
            __syncthreads();
            #pragma unroll
            for (int q = 0; q < 16; ++q) As[sr][sk + q] = __float2bfloat16(av[q]);
            *(uint4*)&Ws[sr][sk] = wa;
            *(uint4*)&Ws[sr][sk + 8] = wb;
        }
        __syncthreads();
        #pragma unroll
        for (int kk = 0; kk < 64; kk += 32) {
            bf16x8 a0 = *(const bf16x8*)&As[mw + fr][kk + fk];
            bf16x8 a1 = *(const bf16x8*)&As[mw + 16 + fr][kk + fk];
            bf16x8 b0 = *(const bf16x8*)&Ws[nw + fr][kk + fk];
            bf16x8 b1 = *(const bf16x8*)&Ws[nw + 16 + fr][kk + fk];
            acc[0][0] = __builtin_amdgcn_mfma_f32_16x16x32_bf16(a0, b0, acc[0][0], 0, 0, 0);
            acc[0][1] = __builtin_amdgcn_mfma_f32_16x16x32_bf16(a0, b1, acc[0][1], 0, 0, 0);
            acc[1][0] = __builtin_amdgcn_mfma_f32_16x16x32_bf16(a1, b0, acc[1][0], 0, 0, 0);
            acc[1][1] = __builtin_amdgcn_mfma_f32_16x16x32_bf16(a1, b1, acc[1][1], 0, 0, 0);
        }
    }
    const int crow = (lane >> 4) * 4;
    #pragma unroll
    for (int mi = 0; mi < 2; ++mi) {
        #pragma unroll
        for (int ni = 0; ni < 2; ++ni) {
            const int col = n0 + nw + ni * 16 + fr;
            if (col < N) {
                const float bv = bias ? bias[col] : 0.f;
                #pragma unroll
                for (int r = 0; r < 4; ++r) {
                    const int row = m0 + mw + mi * 16 + crow + r;
                    float v = acc[mi][ni][r] + bv;
                    if (relu) v = fmaxf(v, 0.f);
                    if (omode == 0) {
                        C[zoff + (long long)row * N + col] = v;
                    } else if (omode == 1) {
                        ((__hip_bfloat16*)C)[zoff + (long long)row * N + col] = __float2bfloat16(v);
                    } else if (omode == 2) {
                        ((__hip_bfloat16*)C)[zoff + (long long)col * M + row] = __float2bfloat16(v);
                    } else {
                        ((__hip_bfloat16*)C)[zoff + ((long long)(col >> 5) * 16384 + row) * 32 + (col & 31)]
                            = __float2bfloat16(v);
                    }
                }
            }
        }
    }
}

// ---------------- MHA via MFMA: 16 queries/block, S & softmax in registers ----
extern "C" __global__ __launch_bounds__(256, 4)
void attn_kernel(const __hip_bfloat16* __restrict__ qkb,
                 const __hip_bfloat16* __restrict__ vT,
                 float* __restrict__ attout) {
    __shared__ float sbuf[8256];                 // 33024 B: pb (bf16 16x1032) / redo union
    __shared__ float redm[4][16];
    __shared__ float reds[4][16];
    __hip_bfloat16 (*pb)[1032] = (__hip_bfloat16 (*)[1032])sbuf;
    float (*redo)[16][33] = (float (*)[16][33])sbuf;
    const int t = threadIdx.x;
    const int qt = blockIdx.x, h = blockIdx.y, bb = blockIdx.z;
    const int q0 = qt * 16;
    const int lane = t & 63, wv = t >> 6;
    const int fr = lane & 15, g = lane >> 4;
    const int kbase = wv * 256;
    const float scale = 0.17677669529663687f;

    bf16x8 qfrag = *(const bf16x8*)(qkb + ((long long)(bb * NQ + q0 + fr)) * 512 + h * HD + g * 8);

    f32x4 sfr[16];
    #pragma unroll
    for (int half = 0; half < 2; ++half) {
        bf16x8 kf[8];
        #pragma unroll
        for (int j = 0; j < 8; ++j) {
            const int key0 = kbase + (half * 8 + j) * 16;
            kf[j] = *(const bf16x8*)(qkb + ((long long)(bb * NQ + key0 + fr)) * 512 + 256 + h * HD + g * 8);
        }
        __builtin_amdgcn_sched_barrier(0);   // all 8 loads in flight before first use
        #pragma unroll
        for (int j = 0; j < 8; ++j) {
            f32x4 z = {0.f, 0.f, 0.f, 0.f};
            sfr[half * 8 + j] = __builtin_amdgcn_mfma_f32_16x16x32_bf16(qfrag, kf[j], z, 0, 0, 0);
        }
    }
    #pragma unroll
    for (int kt = 0; kt < 16; ++kt)
        #pragma unroll
        for (int r = 0; r < 4; ++r) sfr[kt][r] *= scale;

    float mxr[4];
    #pragma unroll
    for (int r = 0; r < 4; ++r) {
        float mx = -1e30f;
        #pragma unroll
        for (int kt = 0; kt < 16; ++kt) mx = fmaxf(mx, sfr[kt][r]);
        #pragma unroll
        for (int mm = 1; mm <= 8; mm <<= 1) mx = fmaxf(mx, __shfl_xor(mx, mm, 64));
        float sm = 0.f;
        #pragma unroll
        for (int kt = 0; kt < 16; ++kt) {
            float e = __expf(sfr[kt][r] - mx);
            sfr[kt][r] = e;                 // keep e, rescale later
            sm += e;
        }
        #pragma unroll
        for (int mm = 1; mm <= 8; mm <<= 1) sm += __shfl_xor(sm, mm, 64);
        mxr[r] = mx;
        if (fr == 0) { redm[wv][4 * g + r] = mx; reds[wv][4 * g + r] = sm; }
    }
    __syncthreads();

    float scl[4];
    #pragma unroll
    for (int r = 0; r < 4; ++r) {
        const int q = 4 * g + r;
        float mm = fmaxf(fmaxf(redm[0][q], redm[1][q]), fmaxf(redm[2][q], redm[3][q]));
        float ll = 0.f;
        #pragma unroll
        for (int w2 = 0; w2 < 4; ++w2) ll += reds[w2][q] * __expf(redm[w2][q] - mm);
        scl[r] = __expf(mxr[r] - mm) / ll;   // e * scl == exp(s-gm)*gl
    }
    #pragma unroll
    for (int kt = 0; kt < 16; ++kt) {
        #pragma unroll
        for (int r = 0; r < 4; ++r) {
            pb[4 * g + r][kbase + kt * 16 + fr] = __float2bfloat16(sfr[kt][r] * scl[r]);
        }
    }

    f32x4 o0 = {0.f, 0.f, 0.f, 0.f}, o1 = {0.f, 0.f, 0.f, 0.f};
    const __hip_bfloat16* vbase = vT + ((long long)bb * DIM + h * HD) * 1024;
    #pragma unroll
    for (int ksb = 0; ksb < 2; ++ksb) {
        bf16x8 pf[4], v0[4], v1[4];
        #pragma unroll
        for (int j = 0; j < 4; ++j) {
            const int key0 = kbase + (ksb * 4 + j) * 32 + g * 8;
            pf[j] = *(const bf16x8*)&pb[fr][key0];
            v0[j] = *(const bf16x8*)(vbase + (long long)fr * 1024 + key0);
            v1[j] = *(const bf16x8*)(vbase + (long long)(16 + fr) * 1024 + key0);
        }
        __builtin_amdgcn_sched_barrier(0);   // 8 global + 4 LDS loads in flight
        #pragma unroll
        for (int j = 0; j < 4; ++j) {
            o0 = __builtin_amdgcn_mfma_f32_16x16x32_bf16(pf[j], v0[j], o0, 0, 0, 0);
            o1 = __builtin_amdgcn_mfma_f32_16x16x32_bf16(pf[j], v1[j], o1, 0, 0, 0);
        }
    }

    __syncthreads();   // all waves done reading pb before redo overwrites it
    #pragma unroll
    for (int r = 0; r < 4; ++r) {
        redo[wv][4 * g + r][fr] = o0[r];
        redo[wv][4 * g + r][16 + fr] = o1[r];
    }
    __syncthreads();
    #pragma unroll
    for (int i = 0; i < 2; ++i) {
        const int idx = t + i * 256;
        const int q = idx >> 5, d = idx & 31;
        float v = redo[0][q][d] + redo[1][q][d] + redo[2][q][d] + redo[3][q][d];
        attout[((long long)(bb * NQ + q0 + q)) * DIM + h * HD + d] = v;
    }
}

// ---------------- residual + LayerNorm (in-place capable) ----------------
extern "C" __global__ __launch_bounds__(256)
void ln_kernel(const float* __restrict__ X, long long sx,
               const float* __restrict__ R, long long sr,
               const float* __restrict__ g, const float* __restrict__ bta,
               float* __restrict__ O, long long so) {
    __shared__ float red[4];
    const int row = blockIdx.x, bb = blockIdx.y, t = threadIdx.x;
    float x = X[(long long)bb * sx + (long long)row * DIM + t]
            + R[(long long)bb * sr + (long long)row * DIM + t];
    float v = x;
    #pragma unroll
    for (int m = 32; m >= 1; m >>= 1) v += __shfl_xor(v, m, 64);
    if ((t & 63) == 0) red[t >> 6] = v;
    __syncthreads();
    float mean = (red[0] + red[1] + red[2] + red[3]) * (1.f / 256.f);
    __syncthreads();
    float d = x - mean;
    v = d * d;
    #pragma unroll
    for (int m = 32; m >= 1; m >>= 1) v += __shfl_xor(v, m, 64);
    if ((t & 63) == 0) red[t >> 6] = v;
    __syncthreads();
    float var = (red[0] + red[1] + red[2] + red[3]) * (1.f / 256.f);
    O[(long long)bb * so + (long long)row * DIM + t] = d * rsqrtf(var + 1e-5f) * g[t] + bta[t];
}

// ---------------- query = selsrc + selpos ----------------
extern "C" __global__ __launch_bounds__(256)
void addq_kernel(const float* __restrict__ a, const float* __restrict__ b2, float* __restrict__ o) {
    long long i = (long long)blockIdx.x * 256 + threadIdx.x;
    o[i] = a[i] + b2[i];
}

// ---------------- box attention ----------------
// vp is HEAD-PLANAR bf16: vp[((b*8+h)*16384 + pix)*32 + ch].
// Phase B: 16B (bf16x8) gathers, 4 chunk-lanes/head-entry, 2 entry-streams
// per head per wave -> 13 guarded loads/lane (vs 25x8B before). Half the
// load instructions halves the latency exposures through the scheduler's
// ~8-deep natural load window. NO sched_barrier here: R3/R4 showed forcing
// 25-deep batching spills to scratch (VGPR stuck at 48 < 50 needed) and
// regresses 48 -> 59.5us. Stream reduction = 1 shfl_xor(4); cross-wave
// reduction via red4[4][8][33] (33-pad -> conflict-free writes).
extern "C" __global__ __launch_bounds__(256)
void boxattn_kernel(const float* __restrict__ aw, const float* __restrict__ ob,
                    const float* __restrict__ dgrid, const float* __restrict__ selref,
                    const __hip_bfloat16* __restrict__ vp, const float* __restrict__ kidx,
                    float* __restrict__ boxout) {
    __shared__ float aw_s[200];
    __shared__ float ob_s[32];
    __shared__ float ref_s[7];
    __shared__ float ki_s[50];
    __shared__ float box_s[8][6];
    __shared__ float mx_s[8];
    __shared__ float inv_s[8];
    __shared__ float wq_s[200];
    __shared__ int   i4_s[800];
    __shared__ float w4_s[800];
    __shared__ float red4[4][8][33];
    const int t = threadIdx.x;
    const int s = blockIdx.x, bb = blockIdx.y;
    const long long base = (long long)(bb * NSEL + s);
    if (t < 200) aw_s[t] = aw[base * 200 + t];
    if (t < 32)  ob_s[t] = ob[base * 32 + t];
    if (t < 7)   ref_s[t] = selref[base * 7 + t];
    if (t < 50)  ki_s[t] = kidx[t];
    __syncthreads();

    if (t < 8) {
        float mx = -1e30f;
        #pragma unroll
        for (int p = 0; p < NP_; ++p) mx = fmaxf(mx, aw_s[t * NP_ + p]);
        mx_s[t] = mx;
        const float r0 = ref_s[0], r1 = ref_s[1], r3 = ref_s[3], r4 = ref_s[4], r6 = ref_s[6];
        box_s[t][0] = r0 + ob_s[t * 4 + 0] * 0.125f * r3;
        box_s[t][1] = r1 + ob_s[t * 4 + 1] * 0.125f * r4;
        box_s[t][2] = fmaxf(r3 + ob_s[t * 4 + 2] * 0.125f * r3, 0.f);
        box_s[t][3] = fmaxf(r4 + ob_s[t * 4 + 3] * 0.125f * r4, 0.f);
        box_s[t][4] = cosf(r6);
        box_s[t][5] = sinf(r6);
    }
    __syncthreads();

    if (t < 200) {
        const int h = t / NP_, p = t - h * NP_;
        const float w = expf(aw_s[t] - mx_s[h]);
        wq_s[t] = w;
        const float cx = box_s[h][0], cy = box_s[h][1];
        const float sw = box_s[h][2], sh = box_s[h][3];
        const float ca = box_s[h][4], sa = box_s[h][5];
        const float fx = ki_s[p * 2 + 0] * sw;
        const float fy = ki_s[p * 2 + 1] * sh;
        const float gx = cx + ca * fx - sa * fy + dgrid[base * 400 + 2 * t + 0] * (1.f / 188.f);
        const float gy = cy + sa * fx + ca * fy + dgrid[base * 400 + 2 * t + 1] * (1.f / 188.f);
        const float x = gx * 128.f - 0.5f;
        const float y = gy * 128.f - 0.5f;
        const float x0f = floorf(x), y0f = floorf(y);
        const float lx = x - x0f, ly = y - y0f;
        const int x0 = (int)x0f, y0 = (int)y0f;
        #pragma unroll
        for (int c = 0; c < 4; ++c) {
            const int xi = x0 + (c & 1);
            const int yi = y0 + (c >> 1);
            const float wgt = ((c & 1) ? lx : 1.f - lx) * ((c >> 1) ? ly : 1.f - ly);
            const bool valid = (xi >= 0) & (xi < 128) & (yi >= 0) & (yi < 128);
            const int cxi = min(max(xi, 0), 127);
            const int cyi = min(max(yi, 0), 127);
            i4_s[t * 4 + c] = cyi * 128 + cxi;
            w4_s[t * 4 + c] = w * (valid ? wgt : 0.f);
        }
    }
    __syncthreads();
    // inv_s overlaps phase B (phase B doesn't read it); visibility to the
    // final tail is guaranteed by the __syncthreads after red4 writes.
    if (t < 8) {
        float sm = 0.f;
        #pragma unroll
        for (int p = 0; p < NP_; ++p) sm += wq_s[t * NP_ + p];
        inv_s[t] = 1.f / sm;
    }

    // phase B: 13 x bf16x8 gathers per lane, natural scheduling
    {
        const int lane = t & 63, wv = t >> 6;
        const int h2 = lane >> 3;          // head
        const int j2 = (lane >> 2) & 1;    // stream-within-wave
        const int q2 = lane & 3;           // 8-channel chunk
        const int stream = wv * 2 + j2;    // 0..7
        const __hip_bfloat16* vb = vp + ((long long)(bb * 8 + h2) * 16384) * 32 + q2 * 8;
        float a[8] = {0.f, 0.f, 0.f, 0.f, 0.f, 0.f, 0.f, 0.f};
        #pragma unroll
        for (int u = 0; u < 13; ++u) {
            const int j = stream + u * 8;
            const bool ok = (j < 100);
            const int e = h2 * 100 + (ok ? j : 0);
            bf16x8 v = *(const bf16x8*)(vb + (long long)i4_s[e] * 32);
            const float w = ok ? w4_s[e] : 0.f;
            #pragma unroll
            for (int k = 0; k < 8; ++k) a[k] += w * (float)v[k];
        }
        #pragma unroll
        for (int k = 0; k < 8; ++k) a[k] += __shfl_xor(a[k], 4, 64);
        if (j2 == 0) {
            #pragma unroll
            for (int k = 0; k < 8; ++k) red4[wv][h2][q2 * 8 + k] = a[k];
        }
    }
    __syncthreads();
    {
        const int h = t >> 5, d = t & 31;
        float v = red4[0][h][d] + red4[1][h][d] + red4[2][h][d] + red4[3][h][d];
        boxout[base * DIM + h * HD + d] = v * inv_s[h];
    }
}

// ---------------- scatter final rows back into out ----------------
extern "C" __global__ __launch_bounds__(256)
void scatter_kernel(const int* __restrict__ idx, const float* __restrict__ sel,
                    float* __restrict__ out) {
    const int s = blockIdx.x, bb = blockIdx.y, t = threadIdx.x;
    const int i = idx[bb * NSEL + s];
    out[((long long)(bb * HW_N + i)) * DIM + t] = sel[((long long)(bb * NSEL + s)) * DIM + t];
}

extern "C" void kernel_launch(void* const* d_in, const int* in_sizes, int n_in,
                              void* d_out, int out_size, void* d_ws, size_t ws_size,
                              hipStream_t stream) {
    const float* src          = (const float*)d_in[0];
    const float* pos          = (const float*)d_in[1];
    const float* refw         = (const float*)d_in[4];
    const float* score        = (const float*)d_in[5];
    const float* in_proj_w    = (const float*)d_in[6];
    const float* in_proj_b    = (const float*)d_in[7];
    const float* mha_out_w    = (const float*)d_in[8];
    const float* mha_out_b    = (const float*)d_in[9];
    const float* value_proj_w = (const float*)d_in[10];
    const float* value_proj_b = (const float*)d_in[11];
    const float* lin_attn_w   = (const float*)d_in[12];
    const float* lin_attn_b   = (const float*)d_in[13];
    const float* lin_box_w    = (const float*)d_in[14];
    const float* lin_box_b    = (const float*)d_in[15];
    const float* samp_off_w   = (const float*)d_in[16];
    const float* samp_off_b   = (const float*)d_in[17];
    const float* ca_out_w     = (const float*)d_in[18];
    const float* ca_out_b     = (const float*)d_in[19];
    const float* lin1_w       = (const float*)d_in[20];
    const float* lin1_b       = (const float*)d_in[21];
    const float* lin2_w       = (const float*)d_in[22];
    const float* lin2_b       = (const float*)d_in[23];
    const float* qn_g         = (const float*)d_in[24];
    const float* qn_b         = (const float*)d_in[25];
    const float* n1_g         = (const float*)d_in[26];
    const float* n1_b         = (const float*)d_in[27];
    const float* n2_g         = (const float*)d_in[28];
    const float* n2_b         = (const float*)d_in[29];
    const float* kidx         = (const float*)d_in[30];

    float* w = (float*)d_ws;
    int* idxp = (int*)d_ws;
    float* selref = w + OFF_SELREF;
    float* selsrc = w + OFF_SELSRC;
    float* selpos = w + OFF_SELPOS;
    float* boxout = w + OFF_SELPOS;   // reuse after selpos dead
    float* query  = w + OFF_QUERY;
    float* src2   = w + OFF_QUERY;    // reuse after query dead
    __hip_bfloat16* vproj  = (__hip_bfloat16*)(w + OFF_BIG);   // head-planar bf16
    __hip_bfloat16* ffntb  = (__hip_bfloat16*)(w + OFF_BIG);   // reuse after vproj dead
    __hip_bfloat16* wbf    = (__hip_bfloat16*)(w + OFF_WBF);   // bf16 weight pool
    float* qk     = w + OFF_F;
    __hip_bfloat16* qkb = (__hip_bfloat16*)(w + OFF_F + 524288);
    __hip_bfloat16* vT  = (__hip_bfloat16*)(w + OFF_F + 1572864);
    float* attout = w + OFF_F + 2097152;
    float* q2     = w + OFF_F + 2621440;
    float* aw     = w + OFF_F;              // reuse after MHA dead
    float* obuf   = w + OFF_F + 1638400;
    float* dgrid  = w + OFF_F + 1900544;
    float* ff     = w + OFF_F;              // reuse after box-attn dead
    unsigned int* hist2 = (unsigned int*)(w + OFF_F);          // topk scratch
    unsigned int* ctrl2 = hist2 + 16384;
    unsigned long long* list1 = (unsigned long long*)(hist2 + 16448);
    unsigned long long* list2 = list1 + 2 * 2048;
    float* out    = (float*)d_out;

    // bf16 weight pool offsets
    const long long W_INPROJ = 0, W_MHAOUT = 196608, W_VALUE = 262144,
                    W_LATTN = 327680, W_LBOX = 378880, W_SOFF = 387072,
                    W_CAOUT = 489472, W_LIN1 = 555008, W_LIN2 = 817152;

    hipMemcpyAsync(d_out, src, (size_t)2 * HW_N * DIM * sizeof(float),
                   hipMemcpyDeviceToDevice, stream);

    wcvt_kernel<<<4216, 256, 0, stream>>>(in_proj_w, mha_out_w, value_proj_w,
                                          lin_attn_w, lin_box_w, samp_off_w,
                                          ca_out_w, lin1_w, lin2_w, wbf);

    hipMemsetAsync(hist2, 0, 16448 * sizeof(unsigned int), stream);
    topk_hist_kernel<<<dim3(32, 2), 512, 0, stream>>>(score, hist2);
    topk_scan_kernel<<<2, 1024, 0, stream>>>(hist2, ctrl2);
    topk_collect_kernel<<<dim3(16, 2), 1024, 0, stream>>>(score, ctrl2, list1, list2);
    topk_classify_kernel<<<dim3(16, 2), 1024, 0, stream>>>(score, ctrl2, list1, list2, idxp);

    gather_kernel<<<dim3(NSEL, 2), 256, 0, stream>>>(src, pos, refw, idxp,
                                                     selsrc, selpos, selref, qk);
    gemm_kernel<<<dim3(8, 16, 2), 256, 0, stream>>>(qk, 262144LL, wbf + W_INPROJ, in_proj_b,
                                                    (float*)qkb, 524288LL, NQ, 512, 256, 0, 1, 0);
    gemm_kernel<<<dim3(4, 16, 2), 256, 0, stream>>>(selsrc, 1048576LL, wbf + W_INPROJ + 512 * 256,
                                                    in_proj_b + 512, (float*)vT, 262144LL, NQ, 256, 256, 0, 2, 0);
    attn_kernel<<<dim3(64, 8, 2), 256, 0, stream>>>(qkb, vT, attout);
    gemm_kernel<<<dim3(4, 16, 2), 256, 0, stream>>>(attout, 262144LL, wbf + W_MHAOUT, mha_out_b,
                                                    q2, 262144LL, NQ, 256, 256, 0, 0, 0);
    ln_kernel<<<dim3(NQ, 2), 256, 0, stream>>>(selsrc, 1048576LL, q2, 262144LL,
                                               qn_g, qn_b, selsrc, 1048576LL);
    addq_kernel<<<8192, 256, 0, stream>>>(selsrc, selpos, query);
    gemm_kernel<<<dim3(4, 256, 2), 256, 0, stream>>>(src, 4194304LL, wbf + W_VALUE, value_proj_b,
                                                     (float*)vproj, 4194304LL, HW_N, 256, 256, 0, 3, 0);
    gemm_kernel<<<dim3(4, 64, 2), 256, 0, stream>>>(query, 1048576LL, wbf + W_LATTN, lin_attn_b,
                                                    aw, 819200LL, NSEL, 200, 256, 0, 0, 0);
    gemm_kernel<<<dim3(1, 64, 2), 256, 0, stream>>>(query, 1048576LL, wbf + W_LBOX, lin_box_b,
                                                    obuf, 131072LL, NSEL, 32, 256, 0, 0, 0);
    gemm_kernel<<<dim3(7, 64, 2), 256, 0, stream>>>(query, 1048576LL, wbf + W_SOFF, samp_off_b,
                                                    dgrid, 1638400LL, NSEL, 400, 256, 0, 0, 0);
    boxattn_kernel<<<dim3(NSEL, 2), 256, 0, stream>>>(aw, obuf, dgrid, selref, vproj, kidx, boxout);
    gemm_kernel<<<dim3(4, 64, 2), 256, 0, stream>>>(boxout, 1048576LL, wbf + W_CAOUT, ca_out_b,
                                                    src2, 1048576LL, NSEL, 256, 256, 0, 0, 0);
    ln_kernel<<<dim3(NSEL, 2), 256, 0, stream>>>(selsrc, 1048576LL, src2, 1048576LL,
                                                 n1_g, n1_b, selsrc, 1048576LL);
    gemm_kernel<<<dim3(16, 64, 2), 256, 0, stream>>>(selsrc, 1048576LL, wbf + W_LIN1, lin1_b,
                                                     (float*)ffntb, 4194304LL, NSEL, DFF_, 256, 1, 1, 0);
    gemm_kernel<<<dim3(4, 64, 2), 256, 0, stream>>>(ffntb, 4194304LL, wbf + W_LIN2, lin2_b,
                                                    ff, 1048576LL, NSEL, 256, DFF_, 0, 0, 1);
    ln_kernel<<<dim3(NSEL, 2), 256, 0, stream>>>(selsrc, 1048576LL, ff, 1048576LL,
                                                 n2_g, n2_b, selsrc, 1048576LL);
    scatter_kernel<<<dim3(NSEL, 2), 256, 0, stream>>>(idxp, selsrc, out);
}

// Round 6
// 419.656 us; speedup vs baseline: 1.1216x; 1.0418x over previous
//
#include <hip/hip_runtime.h>
#include <hip/hip_bf16.h>
#include <math.h>

// Problem constants
#define HW_N   16384
#define DIM    256
#define NSEL   4096
#define NQ     1024
#define NHEAD  8
#define HD     32
#define NP_    25
#define DFF_   1024

// Workspace layout (float offsets). ~76 MB total.
#define OFF_SELREF  8448LL          // 2*4096*7
#define OFF_SELSRC  65792LL         // 2*4096*256
#define OFF_SELPOS  2162944LL       // 2*4096*256 (later reused as boxout)
#define OFF_QUERY   4260096LL       // 2*4096*256 (later reused as src2)
#define OFF_BIG     6357248LL       // vproj bf16 [0,4194304) then ffnt bf16 same slot
#define OFF_WBF     10551552LL      // OFF_BIG+4194304: bf16 weights, 1079296 bf16
#define OFF_F       14745856LL      // multi-use region, 5177344 floats

__device__ __forceinline__ unsigned int f2s(float f) {
    unsigned int u = __float_as_uint(f);
    return (u & 0x80000000u) ? ~u : (u | 0x80000000u);
}

typedef __bf16 bf16x8 __attribute__((ext_vector_type(8)));
typedef __bf16 bf16x4 __attribute__((ext_vector_type(4)));
typedef float  f32x4  __attribute__((ext_vector_type(4)));

// ============ weight preconversion: 9 fp32 matrices -> one bf16 pool ============
// Segments (elems): in_proj 196608 | mha_out 65536 | value 65536 | lin_attn 51200
// | lin_box 8192 | samp_off 102400 | ca_out 65536 | lin1 262144 | lin2 262144
extern "C" __global__ __launch_bounds__(256)
void wcvt_kernel(const float* __restrict__ s0, const float* __restrict__ s1,
                 const float* __restrict__ s2, const float* __restrict__ s3,
                 const float* __restrict__ s4, const float* __restrict__ s5,
                 const float* __restrict__ s6, const float* __restrict__ s7,
                 const float* __restrict__ s8, __hip_bfloat16* __restrict__ dst) {
    const long long g = (long long)blockIdx.x * 256 + threadIdx.x;
    const float* s; long long base;
    if      (g < 196608)  { s = s0; base = 0; }
    else if (g < 262144)  { s = s1; base = 196608; }
    else if (g < 327680)  { s = s2; base = 262144; }
    else if (g < 378880)  { s = s3; base = 327680; }
    else if (g < 387072)  { s = s4; base = 378880; }
    else if (g < 489472)  { s = s5; base = 387072; }
    else if (g < 555008)  { s = s6; base = 489472; }
    else if (g < 817152)  { s = s7; base = 555008; }
    else                  { s = s8; base = 817152; }
    dst[g] = __float2bfloat16(s[g - base]);
}

// ================= top-k, grid-parallel (4 kernels) =================
extern "C" __global__ __launch_bounds__(512)
void topk_hist_kernel(const float* __restrict__ score, unsigned int* __restrict__ hist) {
    const int t = threadIdx.x, bx = blockIdx.x, bb = blockIdx.y;
    const int i = bx * 512 + t;
    unsigned int u = f2s(score[(long long)bb * HW_N + i]);
    atomicAdd(&hist[bb * 8192 + (u >> 19)], 1u);
}

extern "C" __global__ __launch_bounds__(1024)
void topk_scan_kernel(const unsigned int* __restrict__ hist, unsigned int* __restrict__ ctrl) {
    __shared__ unsigned int scan[1024];
    const int t = threadIdx.x, bb = blockIdx.x;
    unsigned int loc[8]; unsigned int lsum = 0u;
    #pragma unroll
    for (int k = 0; k < 8; ++k) { loc[k] = hist[bb * 8192 + t * 8 + k]; lsum += loc[k]; }
    scan[t] = lsum;
    __syncthreads();
    for (int off = 1; off < 1024; off <<= 1) {
        unsigned int v = (t + off < 1024) ? scan[t + off] : 0u;
        __syncthreads();
        scan[t] += v;
        __syncthreads();
    }
    unsigned int nxt = (t < 1023) ? scan[t + 1] : 0u;
    unsigned int run = nxt;
    for (int k = 7; k >= 0; --k) {
        run += loc[k];
        unsigned int above = run - loc[k];
        if (run >= 1024u && above < 1024u) { ctrl[bb * 16 + 0] = (unsigned)(t * 8 + k); ctrl[bb * 16 + 1] = 1024u - above; }
        if (run >= 4096u && above < 4096u) { ctrl[bb * 16 + 2] = (unsigned)(t * 8 + k); ctrl[bb * 16 + 3] = 4096u - above; }
    }
}

extern "C" __global__ __launch_bounds__(1024)
void topk_collect_kernel(const float* __restrict__ score, unsigned int* __restrict__ ctrl,
                         unsigned long long* __restrict__ list1,
                         unsigned long long* __restrict__ list2) {
    const int t = threadIdx.x, bx = blockIdx.x, bb = blockIdx.y;
    const int i = bx * 1024 + t;
    const unsigned int T1 = ctrl[bb * 16 + 0], T2 = ctrl[bb * 16 + 2];
    unsigned int u = f2s(score[(long long)bb * HW_N + i]);
    unsigned int bin = u >> 19;
    unsigned long long key = ((unsigned long long)u << 32) | (unsigned int)(~(unsigned int)i);
    if (bin == T1) {
        unsigned int p = atomicAdd(&ctrl[bb * 16 + 4], 1u);
        if (p < 2048u) list1[bb * 2048 + p] = key;
    }
    if (bin == T2 && T2 != T1) {
        unsigned int p = atomicAdd(&ctrl[bb * 16 + 5], 1u);
        if (p < 2048u) list2[bb * 2048 + p] = key;
    }
}

extern "C" __global__ __launch_bounds__(1024)
void topk_classify_kernel(const float* __restrict__ score, unsigned int* __restrict__ ctrl,
                          const unsigned long long* __restrict__ list1,
                          const unsigned long long* __restrict__ list2,
                          int* __restrict__ idx_out) {
    __shared__ unsigned int cA, cB, baseA, baseB;
    const int t = threadIdx.x, bx = blockIdx.x, bb = blockIdx.y;
    const int i = bx * 1024 + t;
    if (t == 0) { cA = 0u; cB = 0u; }
    __syncthreads();
    const unsigned int T1 = ctrl[bb * 16 + 0], need1 = ctrl[bb * 16 + 1];
    const unsigned int T2 = ctrl[bb * 16 + 2], need2 = ctrl[bb * 16 + 3];
    const unsigned int c1 = min(ctrl[bb * 16 + 4], 2048u);
    const unsigned int c2 = min(ctrl[bb * 16 + 5], 2048u);
    unsigned int u = f2s(score[(long long)bb * HW_N + i]);
    unsigned int bin = u >> 19;
    unsigned long long key = ((unsigned long long)u << 32) | (unsigned int)(~(unsigned int)i);
    bool inA = false, inB = false;
    if (bin > T1) {
        inA = true;
    } else if (bin == T1) {
        unsigned int r = 0;
        for (unsigned int q = 0; q < c1; ++q) r += (list1[bb * 2048 + q] > key) ? 1u : 0u;
        if (r < need1) inA = true;
        else if (T2 == T1) inB = (r < need2);
        else inB = true;
    } else if (bin > T2) {
        inB = true;
    } else if (bin == T2) {
        unsigned int r = 0;
        for (unsigned int q = 0; q < c2; ++q) r += (list2[bb * 2048 + q] > key) ? 1u : 0u;
        inB = (r < need2);
    }
    unsigned int sA = 0u, sB = 0u;
    if (inA) sA = atomicAdd(&cA, 1u);
    if (inB) sB = atomicAdd(&cB, 1u);
    __syncthreads();
    if (t == 0) {
        baseA = atomicAdd(&ctrl[bb * 16 + 6], cA);
        baseB = atomicAdd(&ctrl[bb * 16 + 7], cB);
    }
    __syncthreads();
    if (inA) idx_out[bb * NSEL + baseA + sA] = i;
    if (inB) idx_out[bb * NSEL + 1024 + baseB + sB] = i;
}

// ---------------- gather selected rows ----------------
extern "C" __global__ __launch_bounds__(256)
void gather_kernel(const float* __restrict__ src, const float* __restrict__ pos,
                   const float* __restrict__ refw, const int* __restrict__ idx,
                   float* __restrict__ selsrc, float* __restrict__ selpos,
                   float* __restrict__ selref, float* __restrict__ qk) {
    const int s = blockIdx.x, bb = blockIdx.y, t = threadIdx.x;
    const int i = idx[bb * NSEL + s];
    const long long so = ((long long)(bb * NSEL + s)) * DIM;
    const long long go = ((long long)(bb * HW_N + i)) * DIM;
    float sv = src[go + t], pv = pos[go + t];
    selsrc[so + t] = sv;
    selpos[so + t] = pv;
    if (s < NQ) qk[((long long)(bb * NQ + s)) * DIM + t] = sv + pv;
    if (t < 7)
        selref[(long long)(bb * NSEL + s) * 7 + t] = refw[(long long)(bb * HW_N + i) * 7 + t];
}

// ---------------- bf16 MFMA GEMM: C = act(A @ W^T + bias) ----------------
// W: PRE-CONVERTED bf16 [N][K]. A: fp32 (amode 0) or bf16 (amode 1), [z][M][K].
// omode: 0 fp32 out; 1 bf16 flat; 2 bf16 transposed (col*M+row);
//        3 bf16 head-planar: off = zoff + ((col>>5)*16384 + row)*32 + (col&31).
extern "C" __global__ __launch_bounds__(256)
void gemm_kernel(const void* __restrict__ Avp, long long sA,
                 const __hip_bfloat16* __restrict__ W, const float* __restrict__ bias,
                 float* __restrict__ C, long long sC,
                 int M, int N, int K, int relu, int omode, int amode) {
    __shared__ __hip_bfloat16 As[64][72];
    __shared__ __hip_bfloat16 Ws[64][72];
    const int t = threadIdx.x;
    const int n0 = blockIdx.x * 64, m0 = blockIdx.y * 64;
    const long long zoff = (long long)blockIdx.z * sC;
    const int lane = t & 63, wv = t >> 6;
    const int mw = (wv >> 1) * 32, nw = (wv & 1) * 32;
    const int fr = lane & 15;
    const int fk = (lane >> 4) * 8;
    const int sr = t >> 2;
    const int sk = (t & 3) * 16;

    f32x4 acc[2][2];
    #pragma unroll
    for (int i = 0; i < 2; ++i)
        #pragma unroll
        for (int j = 0; j < 2; ++j) acc[i][j] = {0.f, 0.f, 0.f, 0.f};

    const bool wok = (n0 + sr) < N;
    for (int k0 = 0; k0 < K; k0 += 64) {
        // stage W: straight 32B bf16 copy
        uint4 wa = make_uint4(0u, 0u, 0u, 0u), wb = make_uint4(0u, 0u, 0u, 0u);
        if (wok) {
            const __hip_bfloat16* wp = W + (long long)(n0 + sr) * K + k0 + sk;
            wa = *(const uint4*)wp;
            wb = *(const uint4*)(wp + 8);
        }
        if (amode) {
            const __hip_bfloat16* ap = (const __hip_bfloat16*)Avp
                + (long long)blockIdx.z * sA + (long long)(m0 + sr) * K + k0 + sk;
            uint4 aa = *(const uint4*)ap;
            uint4 ab = *(const uint4*)(ap + 8);
            __syncthreads();
            *(uint4*)&As[sr][sk] = aa;
            *(uint4*)&As[sr][sk + 8] = ab;
            *(uint4*)&Ws[sr][sk] = wa;
            *(uint4*)&Ws[sr][sk + 8] = wb;
        } else {
            const float* ap = (const float*)Avp
                + (long long)blockIdx.z * sA + (long long)(m0 + sr) * K + k0 + sk;
            float av[16];
            #pragma unroll
            for (int q = 0; q < 4; ++q) {
                float4 v = *(const float4*)(ap + q * 4);
                av[q * 4 + 0] = v.x; av[q * 4 + 1] = v.y; av[q * 4 + 2] = v.z; av[q * 4 + 3] = v.w;
            }
            __syncthreads();
            #pragma unroll
            for (int q = 0; q < 16; ++q) As[sr][sk + q] = __float2bfloat16(av[q]);
            *(uint4*)&Ws[sr][sk] = wa;
            *(uint4*)&Ws[sr][sk + 8] = wb;
        }
        __syncthreads();
        #pragma unroll
        for (int kk = 0; kk < 64; kk += 32) {
            bf16x8 a0 = *(const bf16x8*)&As[mw + fr][kk + fk];
            bf16x8 a1 = *(const bf16x8*)&As[mw + 16 + fr][kk + fk];
            bf16x8 b0 = *(const bf16x8*)&Ws[nw + fr][kk + fk];
            bf16x8 b1 = *(const bf16x8*)&Ws[nw + 16 + fr][kk + fk];
            acc[0][0] = __builtin_amdgcn_mfma_f32_16x16x32_bf16(a0, b0, acc[0][0], 0, 0, 0);
            acc[0][1] = __builtin_amdgcn_mfma_f32_16x16x32_bf16(a0, b1, acc[0][1], 0, 0, 0);
            acc[1][0] = __builtin_amdgcn_mfma_f32_16x16x32_bf16(a1, b0, acc[1][0], 0, 0, 0);
            acc[1][1] = __builtin_amdgcn_mfma_f32_16x16x32_bf16(a1, b1, acc[1][1], 0, 0, 0);
        }
    }
    const int crow = (lane >> 4) * 4;
    #pragma unroll
    for (int mi = 0; mi < 2; ++mi) {
        #pragma unroll
        for (int ni = 0; ni < 2; ++ni) {
            const int col = n0 + nw + ni * 16 + fr;
            if (col < N) {
                const float bv = bias ? bias[col] : 0.f;
                #pragma unroll
                for (int r = 0; r < 4; ++r) {
                    const int row = m0 + mw + mi * 16 + crow + r;
                    float v = acc[mi][ni][r] + bv;
                    if (relu) v = fmaxf(v, 0.f);
                    if (omode == 0) {
                        C[zoff + (long long)row * N + col] = v;
                    } else if (omode == 1) {
                        ((__hip_bfloat16*)C)[zoff + (long long)row * N + col] = __float2bfloat16(v);
                    } else if (omode == 2) {
                        ((__hip_bfloat16*)C)[zoff + (long long)col * M + row] = __float2bfloat16(v);
                    } else {
                        ((__hip_bfloat16*)C)[zoff + ((long long)(col >> 5) * 16384 + row) * 32 + (col & 31)]
                            = __float2bfloat16(v);
                    }
                }
            }
        }
    }
}

// ---------------- MHA via MFMA: 16 queries/block, S & softmax in registers ----
extern "C" __global__ __launch_bounds__(256, 4)
void attn_kernel(const __hip_bfloat16* __restrict__ qkb,
                 const __hip_bfloat16* __restrict__ vT,
                 float* __restrict__ attout) {
    __shared__ float sbuf[8256];                 // 33024 B: pb (bf16 16x1032) / redo union
    __shared__ float redm[4][16];
    __shared__ float reds[4][16];
    __hip_bfloat16 (*pb)[1032] = (__hip_bfloat16 (*)[1032])sbuf;
    float (*redo)[16][33] = (float (*)[16][33])sbuf;
    const int t = threadIdx.x;
    const int qt = blockIdx.x, h = blockIdx.y, bb = blockIdx.z;
    const int q0 = qt * 16;
    const int lane = t & 63, wv = t >> 6;
    const int fr = lane & 15, g = lane >> 4;
    const int kbase = wv * 256;
    const float scale = 0.17677669529663687f;

    bf16x8 qfrag = *(const bf16x8*)(qkb + ((long long)(bb * NQ + q0 + fr)) * 512 + h * HD + g * 8);

    f32x4 sfr[16];
    #pragma unroll
    for (int half = 0; half < 2; ++half) {
        bf16x8 kf[8];
        #pragma unroll
        for (int j = 0; j < 8; ++j) {
            const int key0 = kbase + (half * 8 + j) * 16;
            kf[j] = *(const bf16x8*)(qkb + ((long long)(bb * NQ + key0 + fr)) * 512 + 256 + h * HD + g * 8);
        }
        __builtin_amdgcn_sched_barrier(0);   // all 8 loads in flight before first use
        #pragma unroll
        for (int j = 0; j < 8; ++j) {
            f32x4 z = {0.f, 0.f, 0.f, 0.f};
            sfr[half * 8 + j] = __builtin_amdgcn_mfma_f32_16x16x32_bf16(qfrag, kf[j], z, 0, 0, 0);
        }
    }
    #pragma unroll
    for (int kt = 0; kt < 16; ++kt)
        #pragma unroll
        for (int r = 0; r < 4; ++r) sfr[kt][r] *= scale;

    float mxr[4];
    #pragma unroll
    for (int r = 0; r < 4; ++r) {
        float mx = -1e30f;
        #pragma unroll
        for (int kt = 0; kt < 16; ++kt) mx = fmaxf(mx, sfr[kt][r]);
        #pragma unroll
        for (int mm = 1; mm <= 8; mm <<= 1) mx = fmaxf(mx, __shfl_xor(mx, mm, 64));
        float sm = 0.f;
        #pragma unroll
        for (int kt = 0; kt < 16; ++kt) {
            float e = __expf(sfr[kt][r] - mx);
            sfr[kt][r] = e;                 // keep e, rescale later
            sm += e;
        }
        #pragma unroll
        for (int mm = 1; mm <= 8; mm <<= 1) sm += __shfl_xor(sm, mm, 64);
        mxr[r] = mx;
        if (fr == 0) { redm[wv][4 * g + r] = mx; reds[wv][4 * g + r] = sm; }
    }
    __syncthreads();

    float scl[4];
    #pragma unroll
    for (int r = 0; r < 4; ++r) {
        const int q = 4 * g + r;
        float mm = fmaxf(fmaxf(redm[0][q], redm[1][q]), fmaxf(redm[2][q], redm[3][q]));
        float ll = 0.f;
        #pragma unroll
        for (int w2 = 0; w2 < 4; ++w2) ll += reds[w2][q] * __expf(redm[w2][q] - mm);
        scl[r] = __expf(mxr[r] - mm) / ll;   // e * scl == exp(s-gm)*gl
    }
    #pragma unroll
    for (int kt = 0; kt < 16; ++kt) {
        #pragma unroll
        for (int r = 0; r < 4; ++r) {
            pb[4 * g + r][kbase + kt * 16 + fr] = __float2bfloat16(sfr[kt][r] * scl[r]);
        }
    }

    f32x4 o0 = {0.f, 0.f, 0.f, 0.f}, o1 = {0.f, 0.f, 0.f, 0.f};
    const __hip_bfloat16* vbase = vT + ((long long)bb * DIM + h * HD) * 1024;
    #pragma unroll
    for (int ksb = 0; ksb < 2; ++ksb) {
        bf16x8 pf[4], v0[4], v1[4];
        #pragma unroll
        for (int j = 0; j < 4; ++j) {
            const int key0 = kbase + (ksb * 4 + j) * 32 + g * 8;
            pf[j] = *(const bf16x8*)&pb[fr][key0];
            v0[j] = *(const bf16x8*)(vbase + (long long)fr * 1024 + key0);
            v1[j] = *(const bf16x8*)(vbase + (long long)(16 + fr) * 1024 + key0);
        }
        __builtin_amdgcn_sched_barrier(0);   // 8 global + 4 LDS loads in flight
        #pragma unroll
        for (int j = 0; j < 4; ++j) {
            o0 = __builtin_amdgcn_mfma_f32_16x16x32_bf16(pf[j], v0[j], o0, 0, 0, 0);
            o1 = __builtin_amdgcn_mfma_f32_16x16x32_bf16(pf[j], v1[j], o1, 0, 0, 0);
        }
    }

    __syncthreads();   // all waves done reading pb before redo overwrites it
    #pragma unroll
    for (int r = 0; r < 4; ++r) {
        redo[wv][4 * g + r][fr] = o0[r];
        redo[wv][4 * g + r][16 + fr] = o1[r];
    }
    __syncthreads();
    #pragma unroll
    for (int i = 0; i < 2; ++i) {
        const int idx = t + i * 256;
        const int q = idx >> 5, d = idx & 31;
        float v = redo[0][q][d] + redo[1][q][d] + redo[2][q][d] + redo[3][q][d];
        attout[((long long)(bb * NQ + q0 + q)) * DIM + h * HD + d] = v;
    }
}

// ---------------- residual + LayerNorm (in-place capable) ----------------
extern "C" __global__ __launch_bounds__(256)
void ln_kernel(const float* __restrict__ X, long long sx,
               const float* __restrict__ R, long long sr,
               const float* __restrict__ g, const float* __restrict__ bta,
               float* __restrict__ O, long long so) {
    __shared__ float red[4];
    const int row = blockIdx.x, bb = blockIdx.y, t = threadIdx.x;
    float x = X[(long long)bb * sx + (long long)row * DIM + t]
            + R[(long long)bb * sr + (long long)row * DIM + t];
    float v = x;
    #pragma unroll
    for (int m = 32; m >= 1; m >>= 1) v += __shfl_xor(v, m, 64);
    if ((t & 63) == 0) red[t >> 6] = v;
    __syncthreads();
    float mean = (red[0] + red[1] + red[2] + red[3]) * (1.f / 256.f);
    __syncthreads();
    float d = x - mean;
    v = d * d;
    #pragma unroll
    for (int m = 32; m >= 1; m >>= 1) v += __shfl_xor(v, m, 64);
    if ((t & 63) == 0) red[t >> 6] = v;
    __syncthreads();
    float var = (red[0] + red[1] + red[2] + red[3]) * (1.f / 256.f);
    O[(long long)bb * so + (long long)row * DIM + t] = d * rsqrtf(var + 1e-5f) * g[t] + bta[t];
}

// ---------------- query = selsrc + selpos ----------------
extern "C" __global__ __launch_bounds__(256)
void addq_kernel(const float* __restrict__ a, const float* __restrict__ b2, float* __restrict__ o) {
    long long i = (long long)blockIdx.x * 256 + threadIdx.x;
    o[i] = a[i] + b2[i];
}

// ---------------- box attention, L2-local (one head-plane per block) ----------
// vp is HEAD-PLANAR bf16: vp[((b*8+h)*16384 + pix)*32 + ch].
// Grid (16 combos = b*8+h, 256 chunks of 16 s). HIP linear block id = x-fastest
// and XCDs are round-robin on linear id, so all 256 blocks of a combo land on
// XCD combo%8 -> each XCD serves 2 head-planes (2 MB) from its private L2.
// Previous all-heads-per-block layout re-fetched the 16.8 MB vproj ~8x from L3
// (FETCH_SIZE 139 MB). The per-head softmax (25 points) makes this split exact.
// Phase B: 16 threads per s (4 corner-streams x 4 16B-chunks), 25 loads/thread,
// reduction = 2 shfl_xor (no LDS reduction).
extern "C" __global__ __launch_bounds__(256)
void boxattn_kernel(const float* __restrict__ aw, const float* __restrict__ ob,
                    const float* __restrict__ dgrid, const float* __restrict__ selref,
                    const __hip_bfloat16* __restrict__ vp, const float* __restrict__ kidx,
                    float* __restrict__ boxout) {
    __shared__ float aw_s[400];
    __shared__ float ob_s[64];
    __shared__ float ref_s[112];
    __shared__ float ki_s[50];
    __shared__ float dg_s[800];
    __shared__ float box_s[16][6];
    __shared__ float mx_s[16];
    __shared__ float inv_s[16];
    __shared__ float wq_s[400];
    __shared__ int   i4_s[1600];
    __shared__ float w4_s[1600];
    const int t = threadIdx.x;
    const int combo = blockIdx.x;            // b*8 + h
    const int bb = combo >> 3, h = combo & 7;
    const int s0 = blockIdx.y * 16;
    const long long base = (long long)bb * NSEL + s0;   // global row of local s=0

    // loads (per-head slices)
    #pragma unroll
    for (int e = t; e < 400; e += 256) {
        const int s = e / 25, p = e - s * 25;
        aw_s[e] = aw[(base + s) * 200 + h * 25 + p];
    }
    if (t < 64)  ob_s[t] = ob[(base + (t >> 2)) * 32 + h * 4 + (t & 3)];
    if (t < 112) ref_s[t] = selref[base * 7 + t];       // 16 rows x 7, contiguous
    if (t < 50)  ki_s[t] = kidx[t];
    #pragma unroll
    for (int e = t; e < 800; e += 256) {
        const int s = e / 50, r = e - s * 50;
        dg_s[e] = dgrid[(base + s) * 400 + h * 50 + r];
    }
    __syncthreads();

    if (t < 16) {
        float mx = -1e30f;
        #pragma unroll
        for (int p = 0; p < NP_; ++p) mx = fmaxf(mx, aw_s[t * NP_ + p]);
        mx_s[t] = mx;
        const float r0 = ref_s[t * 7 + 0], r1 = ref_s[t * 7 + 1];
        const float r3 = ref_s[t * 7 + 3], r4 = ref_s[t * 7 + 4], r6 = ref_s[t * 7 + 6];
        box_s[t][0] = r0 + ob_s[t * 4 + 0] * 0.125f * r3;
        box_s[t][1] = r1 + ob_s[t * 4 + 1] * 0.125f * r4;
        box_s[t][2] = fmaxf(r3 + ob_s[t * 4 + 2] * 0.125f * r3, 0.f);
        box_s[t][3] = fmaxf(r4 + ob_s[t * 4 + 3] * 0.125f * r4, 0.f);
        box_s[t][4] = cosf(r6);
        box_s[t][5] = sinf(r6);
    }
    __syncthreads();

    #pragma unroll
    for (int e = t; e < 400; e += 256) {
        const int s = e / 25, p = e - s * 25;
        const float w = __expf(aw_s[e] - mx_s[s]);
        wq_s[e] = w;
        const float cx = box_s[s][0], cy = box_s[s][1];
        const float sw = box_s[s][2], sh = box_s[s][3];
        const float ca = box_s[s][4], sa = box_s[s][5];
        const float fx = ki_s[p * 2 + 0] * sw;
        const float fy = ki_s[p * 2 + 1] * sh;
        const float gx = cx + ca * fx - sa * fy + dg_s[s * 50 + 2 * p + 0] * (1.f / 188.f);
        const float gy = cy + sa * fx + ca * fy + dg_s[s * 50 + 2 * p + 1] * (1.f / 188.f);
        const float x = gx * 128.f - 0.5f;
        const float y = gy * 128.f - 0.5f;
        const float x0f = floorf(x), y0f = floorf(y);
        const float lx = x - x0f, ly = y - y0f;
        const int x0 = (int)x0f, y0 = (int)y0f;
        #pragma unroll
        for (int c = 0; c < 4; ++c) {
            const int xi = x0 + (c & 1);
            const int yi = y0 + (c >> 1);
            const float wgt = ((c & 1) ? lx : 1.f - lx) * ((c >> 1) ? ly : 1.f - ly);
            const bool valid = (xi >= 0) & (xi < 128) & (yi >= 0) & (yi < 128);
            const int cxi = min(max(xi, 0), 127);
            const int cyi = min(max(yi, 0), 127);
            i4_s[e * 4 + c] = cyi * 128 + cxi;
            w4_s[e * 4 + c] = w * (valid ? wgt : 0.f);
        }
    }
    __syncthreads();

    // denominators overlap phase B; visibility guaranteed by the barrier below
    if (t < 16) {
        float sm = 0.f;
        #pragma unroll
        for (int p = 0; p < NP_; ++p) sm += wq_s[t * NP_ + p];
        inv_s[t] = 1.f / sm;
    }

    // phase B: 25 x 16B gathers per thread, one head-plane (L2-resident)
    {
        const int lane = t & 63;
        const int s_loc = t >> 4;            // 0..15
        const int j2 = (lane >> 2) & 3;      // corner stream
        const int q2 = lane & 3;             // 16B chunk of the 64B row
        const __hip_bfloat16* vb = vp + ((long long)(bb * 8 + h) * 16384) * 32 + q2 * 8;
        const int ebase = s_loc * 100;
        float a[8] = {0.f, 0.f, 0.f, 0.f, 0.f, 0.f, 0.f, 0.f};
        #pragma unroll
        for (int u = 0; u < 25; ++u) {
            const int ii = ebase + j2 + 4 * u;
            bf16x8 v = *(const bf16x8*)(vb + (long long)i4_s[ii] * 32);
            const float w = w4_s[ii];
            #pragma unroll
            for (int k = 0; k < 8; ++k) a[k] += w * (float)v[k];
        }
        #pragma unroll
        for (int k = 0; k < 8; ++k) a[k] += __shfl_xor(a[k], 4, 64);
        #pragma unroll
        for (int k = 0; k < 8; ++k) a[k] += __shfl_xor(a[k], 8, 64);
        __syncthreads();   // inv_s visible to all
        if (j2 == 0) {
            const float inv = inv_s[s_loc];
            float* op = boxout + (base + s_loc) * DIM + h * HD + q2 * 8;
            float4 o0 = {a[0] * inv, a[1] * inv, a[2] * inv, a[3] * inv};
            float4 o1 = {a[4] * inv, a[5] * inv, a[6] * inv, a[7] * inv};
            *(float4*)op = o0;
            *(float4*)(op + 4) = o1;
        }
    }
}

// ---------------- scatter final rows back into out ----------------
extern "C" __global__ __launch_bounds__(256)
void scatter_kernel(const int* __restrict__ idx, const float* __restrict__ sel,
                    float* __restrict__ out) {
    const int s = blockIdx.x, bb = blockIdx.y, t = threadIdx.x;
    const int i = idx[bb * NSEL + s];
    out[((long long)(bb * HW_N + i)) * DIM + t] = sel[((long long)(bb * NSEL + s)) * DIM + t];
}

extern "C" void kernel_launch(void* const* d_in, const int* in_sizes, int n_in,
                              void* d_out, int out_size, void* d_ws, size_t ws_size,
                              hipStream_t stream) {
    const float* src          = (const float*)d_in[0];
    const float* pos          = (const float*)d_in[1];
    const float* refw         = (const float*)d_in[4];
    const float* score        = (const float*)d_in[5];
    const float* in_proj_w    = (const float*)d_in[6];
    const float* in_proj_b    = (const float*)d_in[7];
    const float* mha_out_w    = (const float*)d_in[8];
    const float* mha_out_b    = (const float*)d_in[9];
    const float* value_proj_w = (const float*)d_in[10];
    const float* value_proj_b = (const float*)d_in[11];
    const float* lin_attn_w   = (const float*)d_in[12];
    const float* lin_attn_b   = (const float*)d_in[13];
    const float* lin_box_w    = (const float*)d_in[14];
    const float* lin_box_b    = (const float*)d_in[15];
    const float* samp_off_w   = (const float*)d_in[16];
    const float* samp_off_b   = (const float*)d_in[17];
    const float* ca_out_w     = (const float*)d_in[18];
    const float* ca_out_b     = (const float*)d_in[19];
    const float* lin1_w       = (const float*)d_in[20];
    const float* lin1_b       = (const float*)d_in[21];
    const float* lin2_w       = (const float*)d_in[22];
    const float* lin2_b       = (const float*)d_in[23];
    const float* qn_g         = (const float*)d_in[24];
    const float* qn_b         = (const float*)d_in[25];
    const float* n1_g         = (const float*)d_in[26];
    const float* n1_b         = (const float*)d_in[27];
    const float* n2_g         = (const float*)d_in[28];
    const float* n2_b         = (const float*)d_in[29];
    const float* kidx         = (const float*)d_in[30];

    float* w = (float*)d_ws;
    int* idxp = (int*)d_ws;
    float* selref = w + OFF_SELREF;
    float* selsrc = w + OFF_SELSRC;
    float* selpos = w + OFF_SELPOS;
    float* boxout = w + OFF_SELPOS;   // reuse after selpos dead
    float* query  = w + OFF_QUERY;
    float* src2   = w + OFF_QUERY;    // reuse after query dead
    __hip_bfloat16* vproj  = (__hip_bfloat16*)(w + OFF_BIG);   // head-planar bf16
    __hip_bfloat16* ffntb  = (__hip_bfloat16*)(w + OFF_BIG);   // reuse after vproj dead
    __hip_bfloat16* wbf    = (__hip_bfloat16*)(w + OFF_WBF);   // bf16 weight pool
    float* qk     = w + OFF_F;
    __hip_bfloat16* qkb = (__hip_bfloat16*)(w + OFF_F + 524288);
    __hip_bfloat16* vT  = (__hip_bfloat16*)(w + OFF_F + 1572864);
    float* attout = w + OFF_F + 2097152;
    float* q2     = w + OFF_F + 2621440;
    float* aw     = w + OFF_F;              // reuse after MHA dead
    float* obuf   = w + OFF_F + 1638400;
    float* dgrid  = w + OFF_F + 1900544;
    float* ff     = w + OFF_F;              // reuse after box-attn dead
    unsigned int* hist2 = (unsigned int*)(w + OFF_F);          // topk scratch
    unsigned int* ctrl2 = hist2 + 16384;
    unsigned long long* list1 = (unsigned long long*)(hist2 + 16448);
    unsigned long long* list2 = list1 + 2 * 2048;
    float* out    = (float*)d_out;

    // bf16 weight pool offsets
    const long long W_INPROJ = 0, W_MHAOUT = 196608, W_VALUE = 262144,
                    W_LATTN = 327680, W_LBOX = 378880, W_SOFF = 387072,
                    W_CAOUT = 489472, W_LIN1 = 555008, W_LIN2 = 817152;

    hipMemcpyAsync(d_out, src, (size_t)2 * HW_N * DIM * sizeof(float),
                   hipMemcpyDeviceToDevice, stream);

    wcvt_kernel<<<4216, 256, 0, stream>>>(in_proj_w, mha_out_w, value_proj_w,
                                          lin_attn_w, lin_box_w, samp_off_w,
                                          ca_out_w, lin1_w, lin2_w, wbf);

    hipMemsetAsync(hist2, 0, 16448 * sizeof(unsigned int), stream);
    topk_hist_kernel<<<dim3(32, 2), 512, 0, stream>>>(score, hist2);
    topk_scan_kernel<<<2, 1024, 0, stream>>>(hist2, ctrl2);
    topk_collect_kernel<<<dim3(16, 2), 1024, 0, stream>>>(score, ctrl2, list1, list2);
    topk_classify_kernel<<<dim3(16, 2), 1024, 0, stream>>>(score, ctrl2, list1, list2, idxp);

    gather_kernel<<<dim3(NSEL, 2), 256, 0, stream>>>(src, pos, refw, idxp,
                                                     selsrc, selpos, selref, qk);
    gemm_kernel<<<dim3(8, 16, 2), 256, 0, stream>>>(qk, 262144LL, wbf + W_INPROJ, in_proj_b,
                                                    (float*)qkb, 524288LL, NQ, 512, 256, 0, 1, 0);
    gemm_kernel<<<dim3(4, 16, 2), 256, 0, stream>>>(selsrc, 1048576LL, wbf + W_INPROJ + 512 * 256,
                                                    in_proj_b + 512, (float*)vT, 262144LL, NQ, 256, 256, 0, 2, 0);
    attn_kernel<<<dim3(64, 8, 2), 256, 0, stream>>>(qkb, vT, attout);
    gemm_kernel<<<dim3(4, 16, 2), 256, 0, stream>>>(attout, 262144LL, wbf + W_MHAOUT, mha_out_b,
                                                    q2, 262144LL, NQ, 256, 256, 0, 0, 0);
    ln_kernel<<<dim3(NQ, 2), 256, 0, stream>>>(selsrc, 1048576LL, q2, 262144LL,
                                               qn_g, qn_b, selsrc, 1048576LL);
    addq_kernel<<<8192, 256, 0, stream>>>(selsrc, selpos, query);
    gemm_kernel<<<dim3(4, 256, 2), 256, 0, stream>>>(src, 4194304LL, wbf + W_VALUE, value_proj_b,
                                                     (float*)vproj, 4194304LL, HW_N, 256, 256, 0, 3, 0);
    gemm_kernel<<<dim3(4, 64, 2), 256, 0, stream>>>(query, 1048576LL, wbf + W_LATTN, lin_attn_b,
                                                    aw, 819200LL, NSEL, 200, 256, 0, 0, 0);
    gemm_kernel<<<dim3(1, 64, 2), 256, 0, stream>>>(query, 1048576LL, wbf + W_LBOX, lin_box_b,
                                                    obuf, 131072LL, NSEL, 32, 256, 0, 0, 0);
    gemm_kernel<<<dim3(7, 64, 2), 256, 0, stream>>>(query, 1048576LL, wbf + W_SOFF, samp_off_b,
                                                    dgrid, 1638400LL, NSEL, 400, 256, 0, 0, 0);
    boxattn_kernel<<<dim3(16, 256), 256, 0, stream>>>(aw, obuf, dgrid, selref, vproj, kidx, boxout);
    gemm_kernel<<<dim3(4, 64, 2), 256, 0, stream>>>(boxout, 1048576LL, wbf + W_CAOUT, ca_out_b,
                                                    src2, 1048576LL, NSEL, 256, 256, 0, 0, 0);
    ln_kernel<<<dim3(NSEL, 2), 256, 0, stream>>>(selsrc, 1048576LL, src2, 1048576LL,
                                                 n1_g, n1_b, selsrc, 1048576LL);
    gemm_kernel<<<dim3(16, 64, 2), 256, 0, stream>>>(selsrc, 1048576LL, wbf + W_LIN1, lin1_b,
                                                     (float*)ffntb, 4194304LL, NSEL, DFF_, 256, 1, 1, 0);
    gemm_kernel<<<dim3(4, 64, 2), 256, 0, stream>>>(ffntb, 4194304LL, wbf + W_LIN2, lin2_b,
                                                    ff, 1048576LL, NSEL, 256, DFF_, 0, 0, 1);
    ln_kernel<<<dim3(NSEL, 2), 256, 0, stream>>>(selsrc, 1048576LL, ff, 1048576LL,
                                                 n2_g, n2_b, selsrc, 1048576LL);
    scatter_kernel<<<dim3(NSEL, 2), 256, 0, stream>>>(idxp, selsrc, out);
}

// Round 7
// 404.821 us; speedup vs baseline: 1.1627x; 1.0366x over previous
//
#include <hip/hip_runtime.h>
#include <hip/hip_bf16.h>
#include <math.h>

// Problem constants
#define HW_N   16384
#define DIM    256
#define NSEL   4096
#define NQ     1024
#define NHEAD  8
#define HD     32
#define NP_    25
#define DFF_   1024

// Workspace layout (float offsets). ~76 MB total.
#define OFF_SELREF  8448LL          // 2*4096*7
#define OFF_SELSRC  65792LL         // 2*4096*256
#define OFF_SELPOS  2162944LL       // 2*4096*256 (later reused as boxout bf16)
#define OFF_QUERY   4260096LL       // 2*4096*256 (query bf16, later src2 fp32)
#define OFF_BIG     6357248LL       // vproj bf16 [0,4194304) then ffnt bf16 same slot
#define OFF_WBF     10551552LL      // OFF_BIG+4194304: bf16 weights, 1079296 bf16
#define OFF_F       14745856LL      // multi-use region, 5177344 floats

__device__ __forceinline__ unsigned int f2s(float f) {
    unsigned int u = __float_as_uint(f);
    return (u & 0x80000000u) ? ~u : (u | 0x80000000u);
}

typedef __bf16 bf16x8 __attribute__((ext_vector_type(8)));
typedef __bf16 bf16x4 __attribute__((ext_vector_type(4)));
typedef float  f32x4  __attribute__((ext_vector_type(4)));

// ============ weight preconversion: 9 fp32 matrices -> one bf16 pool ============
extern "C" __global__ __launch_bounds__(256)
void wcvt_kernel(const float* __restrict__ s0, const float* __restrict__ s1,
                 const float* __restrict__ s2, const float* __restrict__ s3,
                 const float* __restrict__ s4, const float* __restrict__ s5,
                 const float* __restrict__ s6, const float* __restrict__ s7,
                 const float* __restrict__ s8, __hip_bfloat16* __restrict__ dst) {
    const long long g = (long long)blockIdx.x * 256 + threadIdx.x;
    const float* s; long long base;
    if      (g < 196608)  { s = s0; base = 0; }
    else if (g < 262144)  { s = s1; base = 196608; }
    else if (g < 327680)  { s = s2; base = 262144; }
    else if (g < 378880)  { s = s3; base = 327680; }
    else if (g < 387072)  { s = s4; base = 378880; }
    else if (g < 489472)  { s = s5; base = 387072; }
    else if (g < 555008)  { s = s6; base = 489472; }
    else if (g < 817152)  { s = s7; base = 555008; }
    else                  { s = s8; base = 817152; }
    dst[g] = __float2bfloat16(s[g - base]);
}

// ================= top-k, grid-parallel (4 kernels) =================
extern "C" __global__ __launch_bounds__(512)
void topk_hist_kernel(const float* __restrict__ score, unsigned int* __restrict__ hist) {
    const int t = threadIdx.x, bx = blockIdx.x, bb = blockIdx.y;
    const int i = bx * 512 + t;
    unsigned int u = f2s(score[(long long)bb * HW_N + i]);
    atomicAdd(&hist[bb * 8192 + (u >> 19)], 1u);
}

extern "C" __global__ __launch_bounds__(1024)
void topk_scan_kernel(const unsigned int* __restrict__ hist, unsigned int* __restrict__ ctrl) {
    __shared__ unsigned int scan[1024];
    const int t = threadIdx.x, bb = blockIdx.x;
    unsigned int loc[8]; unsigned int lsum = 0u;
    #pragma unroll
    for (int k = 0; k < 8; ++k) { loc[k] = hist[bb * 8192 + t * 8 + k]; lsum += loc[k]; }
    scan[t] = lsum;
    __syncthreads();
    for (int off = 1; off < 1024; off <<= 1) {
        unsigned int v = (t + off < 1024) ? scan[t + off] : 0u;
        __syncthreads();
        scan[t] += v;
        __syncthreads();
    }
    unsigned int nxt = (t < 1023) ? scan[t + 1] : 0u;
    unsigned int run = nxt;
    for (int k = 7; k >= 0; --k) {
        run += loc[k];
        unsigned int above = run - loc[k];
        if (run >= 1024u && above < 1024u) { ctrl[bb * 16 + 0] = (unsigned)(t * 8 + k); ctrl[bb * 16 + 1] = 1024u - above; }
        if (run >= 4096u && above < 4096u) { ctrl[bb * 16 + 2] = (unsigned)(t * 8 + k); ctrl[bb * 16 + 3] = 4096u - above; }
    }
}

extern "C" __global__ __launch_bounds__(1024)
void topk_collect_kernel(const float* __restrict__ score, unsigned int* __restrict__ ctrl,
                         unsigned long long* __restrict__ list1,
                         unsigned long long* __restrict__ list2) {
    const int t = threadIdx.x, bx = blockIdx.x, bb = blockIdx.y;
    const int i = bx * 1024 + t;
    const unsigned int T1 = ctrl[bb * 16 + 0], T2 = ctrl[bb * 16 + 2];
    unsigned int u = f2s(score[(long long)bb * HW_N + i]);
    unsigned int bin = u >> 19;
    unsigned long long key = ((unsigned long long)u << 32) | (unsigned int)(~(unsigned int)i);
    if (bin == T1) {
        unsigned int p = atomicAdd(&ctrl[bb * 16 + 4], 1u);
        if (p < 2048u) list1[bb * 2048 + p] = key;
    }
    if (bin == T2 && T2 != T1) {
        unsigned int p = atomicAdd(&ctrl[bb * 16 + 5], 1u);
        if (p < 2048u) list2[bb * 2048 + p] = key;
    }
}

extern "C" __global__ __launch_bounds__(1024)
void topk_classify_kernel(const float* __restrict__ score, unsigned int* __restrict__ ctrl,
                          const unsigned long long* __restrict__ list1,
                          const unsigned long long* __restrict__ list2,
                          int* __restrict__ idx_out) {
    __shared__ unsigned int cA, cB, baseA, baseB;
    const int t = threadIdx.x, bx = blockIdx.x, bb = blockIdx.y;
    const int i = bx * 1024 + t;
    if (t == 0) { cA = 0u; cB = 0u; }
    __syncthreads();
    const unsigned int T1 = ctrl[bb * 16 + 0], need1 = ctrl[bb * 16 + 1];
    const unsigned int T2 = ctrl[bb * 16 + 2], need2 = ctrl[bb * 16 + 3];
    const unsigned int c1 = min(ctrl[bb * 16 + 4], 2048u);
    const unsigned int c2 = min(ctrl[bb * 16 + 5], 2048u);
    unsigned int u = f2s(score[(long long)bb * HW_N + i]);
    unsigned int bin = u >> 19;
    unsigned long long key = ((unsigned long long)u << 32) | (unsigned int)(~(unsigned int)i);
    bool inA = false, inB = false;
    if (bin > T1) {
        inA = true;
    } else if (bin == T1) {
        unsigned int r = 0;
        for (unsigned int q = 0; q < c1; ++q) r += (list1[bb * 2048 + q] > key) ? 1u : 0u;
        if (r < need1) inA = true;
        else if (T2 == T1) inB = (r < need2);
        else inB = true;
    } else if (bin > T2) {
        inB = true;
    } else if (bin == T2) {
        unsigned int r = 0;
        for (unsigned int q = 0; q < c2; ++q) r += (list2[bb * 2048 + q] > key) ? 1u : 0u;
        inB = (r < need2);
    }
    unsigned int sA = 0u, sB = 0u;
    if (inA) sA = atomicAdd(&cA, 1u);
    if (inB) sB = atomicAdd(&cB, 1u);
    __syncthreads();
    if (t == 0) {
        baseA = atomicAdd(&ctrl[bb * 16 + 6], cA);
        baseB = atomicAdd(&ctrl[bb * 16 + 7], cB);
    }
    __syncthreads();
    if (inA) idx_out[bb * NSEL + baseA + sA] = i;
    if (inB) idx_out[bb * NSEL + 1024 + baseB + sB] = i;
}

// ---------------- gather selected rows (+ bf16 copies for MFMA A-operands) ----
extern "C" __global__ __launch_bounds__(256)
void gather_kernel(const float* __restrict__ src, const float* __restrict__ pos,
                   const float* __restrict__ refw, const int* __restrict__ idx,
                   float* __restrict__ selsrc, float* __restrict__ selpos,
                   float* __restrict__ selref,
                   __hip_bfloat16* __restrict__ qkb16,
                   __hip_bfloat16* __restrict__ selsrcb) {
    const int s = blockIdx.x, bb = blockIdx.y, t = threadIdx.x;
    const int i = idx[bb * NSEL + s];
    const long long so = ((long long)(bb * NSEL + s)) * DIM;
    const long long go = ((long long)(bb * HW_N + i)) * DIM;
    float sv = src[go + t], pv = pos[go + t];
    selsrc[so + t] = sv;
    selpos[so + t] = pv;
    if (s < NQ) {
        const long long qo = ((long long)(bb * NQ + s)) * DIM + t;
        qkb16[qo] = __float2bfloat16(sv + pv);
        selsrcb[qo] = __float2bfloat16(sv);
    }
    if (t < 7)
        selref[(long long)(bb * NSEL + s) * 7 + t] = refw[(long long)(bb * HW_N + i) * 7 + t];
}

// ---------------- bf16 MFMA GEMM: C = act(A @ W^T + bias) ----------------
// W: PRE-CONVERTED bf16 [N][K]. A: fp32 (amode 0) or bf16 (amode 1), [z][M][K].
// omode: 0 fp32 out; 1 bf16 flat; 2 bf16 transposed (col*M+row);
//        3 bf16 head-planar: off = zoff + ((col>>5)*16384 + row)*32 + (col&31).
extern "C" __global__ __launch_bounds__(256)
void gemm_kernel(const void* __restrict__ Avp, long long sA,
                 const __hip_bfloat16* __restrict__ W, const float* __restrict__ bias,
                 float* __restrict__ C, long long sC,
                 int M, int N, int K, int relu, int omode, int amode) {
    __shared__ __hip_bfloat16 As[64][72];
    __shared__ __hip_bfloat16 Ws[64][72];
    const int t = threadIdx.x;
    const int n0 = blockIdx.x * 64, m0 = blockIdx.y * 64;
    const long long zoff = (long long)blockIdx.z * sC;
    const int lane = t & 63, wv = t >> 6;
    const int mw = (wv >> 1) * 32, nw = (wv & 1) * 32;
    const int fr = lane & 15;
    const int fk = (lane >> 4) * 8;
    const int sr = t >> 2;
    const int sk = (t & 3) * 16;

    f32x4 acc[2][2];
    #pragma unroll
    for (int i = 0; i < 2; ++i)
        #pragma unroll
        for (int j = 0; j < 2; ++j) acc[i][j] = {0.f, 0.f, 0.f, 0.f};

    const bool wok = (n0 + sr) < N;
    for (int k0 = 0; k0 < K; k0 += 64) {
        // stage W: straight 32B bf16 copy
        uint4 wa = make_uint4(0u, 0u, 0u, 0u), wb = make_uint4(0u, 0u, 0u, 0u);
        if (wok) {
            const __hip_bfloat16* wp = W + (long long)(n0 + sr) * K + k0 + sk;
            wa = *(const uint4*)wp;
            wb = *(const uint4*)(wp + 8);
        }
        if (amode) {
            const __hip_bfloat16* ap = (const __hip_bfloat16*)Avp
                + (long long)blockIdx.z * sA + (long long)(m0 + sr) * K + k0 + sk;
            uint4 aa = *(const uint4*)ap;
            uint4 ab = *(const uint4*)(ap + 8);
            __syncthreads();
            *(uint4*)&As[sr][sk] = aa;
            *(uint4*)&As[sr][sk + 8] = ab;
            *(uint4*)&Ws[sr][sk] = wa;
            *(uint4*)&Ws[sr][sk + 8] = wb;
        } else {
            const float* ap = (const float*)Avp
                + (long long)blockIdx.z * sA + (long long)(m0 + sr) * K + k0 + sk;
            float av[16];
            #pragma unroll
            for (int q = 0; q < 4; ++q) {
                float4 v = *(const float4*)(ap + q * 4);
                av[q * 4 + 0] = v.x; av[q * 4 + 1] = v.y; av[q * 4 + 2] = v.z; av[q * 4 + 3] = v.w;
            }
            __syncthreads();
            #pragma unroll
            for (int q = 0; q < 16; ++q) As[sr][sk + q] = __float2bfloat16(av[q]);
            *(uint4*)&Ws[sr][sk] = wa;
            *(uint4*)&Ws[sr][sk + 8] = wb;
        }
        __syncthreads();
        #pragma unroll
        for (int kk = 0; kk < 64; kk += 32) {
            bf16x8 a0 = *(const bf16x8*)&As[mw + fr][kk + fk];
            bf16x8 a1 = *(const bf16x8*)&As[mw + 16 + fr][kk + fk];
            bf16x8 b0 = *(const bf16x8*)&Ws[nw + fr][kk + fk];
            bf16x8 b1 = *(const bf16x8*)&Ws[nw + 16 + fr][kk + fk];
            acc[0][0] = __builtin_amdgcn_mfma_f32_16x16x32_bf16(a0, b0, acc[0][0], 0, 0, 0);
            acc[0][1] = __builtin_amdgcn_mfma_f32_16x16x32_bf16(a0, b1, acc[0][1], 0, 0, 0);
            acc[1][0] = __builtin_amdgcn_mfma_f32_16x16x32_bf16(a1, b0, acc[1][0], 0, 0, 0);
            acc[1][1] = __builtin_amdgcn_mfma_f32_16x16x32_bf16(a1, b1, acc[1][1], 0, 0, 0);
        }
    }
    const int crow = (lane >> 4) * 4;
    #pragma unroll
    for (int mi = 0; mi < 2; ++mi) {
        #pragma unroll
        for (int ni = 0; ni < 2; ++ni) {
            const int col = n0 + nw + ni * 16 + fr;
            if (col < N) {
                const float bv = bias ? bias[col] : 0.f;
                #pragma unroll
                for (int r = 0; r < 4; ++r) {
                    const int row = m0 + mw + mi * 16 + crow + r;
                    float v = acc[mi][ni][r] + bv;
                    if (relu) v = fmaxf(v, 0.f);
                    if (omode == 0) {
                        C[zoff + (long long)row * N + col] = v;
                    } else if (omode == 1) {
                        ((__hip_bfloat16*)C)[zoff + (long long)row * N + col] = __float2bfloat16(v);
                    } else if (omode == 2) {
                        ((__hip_bfloat16*)C)[zoff + (long long)col * M + row] = __float2bfloat16(v);
                    } else {
                        ((__hip_bfloat16*)C)[zoff + ((long long)(col >> 5) * 16384 + row) * 32 + (col & 31)]
                            = __float2bfloat16(v);
                    }
                }
            }
        }
    }
}

// ---------------- MHA via MFMA: 16 queries/block, S & softmax in registers ----
// Output is bf16 (identical numerics: the consumer GEMM rounded to bf16 anyway).
extern "C" __global__ __launch_bounds__(256, 4)
void attn_kernel(const __hip_bfloat16* __restrict__ qkb,
                 const __hip_bfloat16* __restrict__ vT,
                 __hip_bfloat16* __restrict__ attout) {
    __shared__ float sbuf[8256];                 // 33024 B: pb (bf16 16x1032) / redo union
    __shared__ float redm[4][16];
    __shared__ float reds[4][16];
    __hip_bfloat16 (*pb)[1032] = (__hip_bfloat16 (*)[1032])sbuf;
    float (*redo)[16][33] = (float (*)[16][33])sbuf;
    const int t = threadIdx.x;
    const int qt = blockIdx.x, h = blockIdx.y, bb = blockIdx.z;
    const int q0 = qt * 16;
    const int lane = t & 63, wv = t >> 6;
    const int fr = lane & 15, g = lane >> 4;
    const int kbase = wv * 256;
    const float scale = 0.17677669529663687f;

    bf16x8 qfrag = *(const bf16x8*)(qkb + ((long long)(bb * NQ + q0 + fr)) * 512 + h * HD + g * 8);

    f32x4 sfr[16];
    #pragma unroll
    for (int half = 0; half < 2; ++half) {
        bf16x8 kf[8];
        #pragma unroll
        for (int j = 0; j < 8; ++j) {
            const int key0 = kbase + (half * 8 + j) * 16;
            kf[j] = *(const bf16x8*)(qkb + ((long long)(bb * NQ + key0 + fr)) * 512 + 256 + h * HD + g * 8);
        }
        __builtin_amdgcn_sched_barrier(0);   // all 8 loads in flight before first use
        #pragma unroll
        for (int j = 0; j < 8; ++j) {
            f32x4 z = {0.f, 0.f, 0.f, 0.f};
            sfr[half * 8 + j] = __builtin_amdgcn_mfma_f32_16x16x32_bf16(qfrag, kf[j], z, 0, 0, 0);
        }
    }
    #pragma unroll
    for (int kt = 0; kt < 16; ++kt)
        #pragma unroll
        for (int r = 0; r < 4; ++r) sfr[kt][r] *= scale;

    float mxr[4];
    #pragma unroll
    for (int r = 0; r < 4; ++r) {
        float mx = -1e30f;
        #pragma unroll
        for (int kt = 0; kt < 16; ++kt) mx = fmaxf(mx, sfr[kt][r]);
        #pragma unroll
        for (int mm = 1; mm <= 8; mm <<= 1) mx = fmaxf(mx, __shfl_xor(mx, mm, 64));
        float sm = 0.f;
        #pragma unroll
        for (int kt = 0; kt < 16; ++kt) {
            float e = __expf(sfr[kt][r] - mx);
            sfr[kt][r] = e;                 // keep e, rescale later
            sm += e;
        }
        #pragma unroll
        for (int mm = 1; mm <= 8; mm <<= 1) sm += __shfl_xor(sm, mm, 64);
        mxr[r] = mx;
        if (fr == 0) { redm[wv][4 * g + r] = mx; reds[wv][4 * g + r] = sm; }
    }
    __syncthreads();

    float scl[4];
    #pragma unroll
    for (int r = 0; r < 4; ++r) {
        const int q = 4 * g + r;
        float mm = fmaxf(fmaxf(redm[0][q], redm[1][q]), fmaxf(redm[2][q], redm[3][q]));
        float ll = 0.f;
        #pragma unroll
        for (int w2 = 0; w2 < 4; ++w2) ll += reds[w2][q] * __expf(redm[w2][q] - mm);
        scl[r] = __expf(mxr[r] - mm) / ll;   // e * scl == exp(s-gm)*gl
    }
    #pragma unroll
    for (int kt = 0; kt < 16; ++kt) {
        #pragma unroll
        for (int r = 0; r < 4; ++r) {
            pb[4 * g + r][kbase + kt * 16 + fr] = __float2bfloat16(sfr[kt][r] * scl[r]);
        }
    }

    f32x4 o0 = {0.f, 0.f, 0.f, 0.f}, o1 = {0.f, 0.f, 0.f, 0.f};
    const __hip_bfloat16* vbase = vT + ((long long)bb * DIM + h * HD) * 1024;
    #pragma unroll
    for (int ksb = 0; ksb < 2; ++ksb) {
        bf16x8 pf[4], v0[4], v1[4];
        #pragma unroll
        for (int j = 0; j < 4; ++j) {
            const int key0 = kbase + (ksb * 4 + j) * 32 + g * 8;
            pf[j] = *(const bf16x8*)&pb[fr][key0];
            v0[j] = *(const bf16x8*)(vbase + (long long)fr * 1024 + key0);
            v1[j] = *(const bf16x8*)(vbase + (long long)(16 + fr) * 1024 + key0);
        }
        __builtin_amdgcn_sched_barrier(0);   // 8 global + 4 LDS loads in flight
        #pragma unroll
        for (int j = 0; j < 4; ++j) {
            o0 = __builtin_amdgcn_mfma_f32_16x16x32_bf16(pf[j], v0[j], o0, 0, 0, 0);
            o1 = __builtin_amdgcn_mfma_f32_16x16x32_bf16(pf[j], v1[j], o1, 0, 0, 0);
        }
    }

    __syncthreads();   // all waves done reading pb before redo overwrites it
    #pragma unroll
    for (int r = 0; r < 4; ++r) {
        redo[wv][4 * g + r][fr] = o0[r];
        redo[wv][4 * g + r][16 + fr] = o1[r];
    }
    __syncthreads();
    #pragma unroll
    for (int i = 0; i < 2; ++i) {
        const int idx = t + i * 256;
        const int q = idx >> 5, d = idx & 31;
        float v = redo[0][q][d] + redo[1][q][d] + redo[2][q][d] + redo[3][q][d];
        attout[((long long)(bb * NQ + q0 + q)) * DIM + h * HD + d] = __float2bfloat16(v);
    }
}

// ---------------- residual + LayerNorm (in-place capable, optional bf16 copy) --
extern "C" __global__ __launch_bounds__(256)
void ln_kernel(const float* __restrict__ X, long long sx,
               const float* __restrict__ R, long long sr,
               const float* __restrict__ g, const float* __restrict__ bta,
               float* __restrict__ O, long long so,
               __hip_bfloat16* __restrict__ Ob) {
    __shared__ float red[4];
    const int row = blockIdx.x, bb = blockIdx.y, t = threadIdx.x;
    float x = X[(long long)bb * sx + (long long)row * DIM + t]
            + R[(long long)bb * sr + (long long)row * DIM + t];
    float v = x;
    #pragma unroll
    for (int m = 32; m >= 1; m >>= 1) v += __shfl_xor(v, m, 64);
    if ((t & 63) == 0) red[t >> 6] = v;
    __syncthreads();
    float mean = (red[0] + red[1] + red[2] + red[3]) * (1.f / 256.f);
    __syncthreads();
    float d = x - mean;
    v = d * d;
    #pragma unroll
    for (int m = 32; m >= 1; m >>= 1) v += __shfl_xor(v, m, 64);
    if ((t & 63) == 0) red[t >> 6] = v;
    __syncthreads();
    float var = (red[0] + red[1] + red[2] + red[3]) * (1.f / 256.f);
    float o = d * rsqrtf(var + 1e-5f) * g[t] + bta[t];
    O[(long long)bb * so + (long long)row * DIM + t] = o;
    if (Ob) Ob[(long long)bb * so + (long long)row * DIM + t] = __float2bfloat16(o);
}

// ---------------- query = selsrc + selpos (bf16 out for GEMM A) ----------------
extern "C" __global__ __launch_bounds__(256)
void addq_kernel(const float* __restrict__ a, const float* __restrict__ b2,
                 __hip_bfloat16* __restrict__ o) {
    long long i = (long long)blockIdx.x * 256 + threadIdx.x;
    o[i] = __float2bfloat16(a[i] + b2[i]);
}

// ---------------- box attention, L2-local (one head-plane per block) ----------
// See R6 notes: combo = b*8+h on blockIdx.x -> all 256 s-chunks of a combo on
// one XCD; FETCH_SIZE dropped 139->35 MB (verified R6). bf16 output.
extern "C" __global__ __launch_bounds__(256)
void boxattn_kernel(const float* __restrict__ aw, const float* __restrict__ ob,
                    const float* __restrict__ dgrid, const float* __restrict__ selref,
                    const __hip_bfloat16* __restrict__ vp, const float* __restrict__ kidx,
                    __hip_bfloat16* __restrict__ boxout) {
    __shared__ float aw_s[400];
    __shared__ float ob_s[64];
    __shared__ float ref_s[112];
    __shared__ float ki_s[50];
    __shared__ float dg_s[800];
    __shared__ float box_s[16][6];
    __shared__ float mx_s[16];
    __shared__ float inv_s[16];
    __shared__ float wq_s[400];
    __shared__ int   i4_s[1600];
    __shared__ float w4_s[1600];
    const int t = threadIdx.x;
    const int combo = blockIdx.x;            // b*8 + h
    const int bb = combo >> 3, h = combo & 7;
    const int s0 = blockIdx.y * 16;
    const long long base = (long long)bb * NSEL + s0;   // global row of local s=0

    // loads (per-head slices)
    #pragma unroll
    for (int e = t; e < 400; e += 256) {
        const int s = e / 25, p = e - s * 25;
        aw_s[e] = aw[(base + s) * 200 + h * 25 + p];
    }
    if (t < 64)  ob_s[t] = ob[(base + (t >> 2)) * 32 + h * 4 + (t & 3)];
    if (t < 112) ref_s[t] = selref[base * 7 + t];       // 16 rows x 7, contiguous
    if (t < 50)  ki_s[t] = kidx[t];
    #pragma unroll
    for (int e = t; e < 800; e += 256) {
        const int s = e / 50, r = e - s * 50;
        dg_s[e] = dgrid[(base + s) * 400 + h * 50 + r];
    }
    __syncthreads();

    if (t < 16) {
        float mx = -1e30f;
        #pragma unroll
        for (int p = 0; p < NP_; ++p) mx = fmaxf(mx, aw_s[t * NP_ + p]);
        mx_s[t] = mx;
        const float r0 = ref_s[t * 7 + 0], r1 = ref_s[t * 7 + 1];
        const float r3 = ref_s[t * 7 + 3], r4 = ref_s[t * 7 + 4], r6 = ref_s[t * 7 + 6];
        box_s[t][0] = r0 + ob_s[t * 4 + 0] * 0.125f * r3;
        box_s[t][1] = r1 + ob_s[t * 4 + 1] * 0.125f * r4;
        box_s[t][2] = fmaxf(r3 + ob_s[t * 4 + 2] * 0.125f * r3, 0.f);
        box_s[t][3] = fmaxf(r4 + ob_s[t * 4 + 3] * 0.125f * r4, 0.f);
        box_s[t][4] = cosf(r6);
        box_s[t][5] = sinf(r6);
    }
    __syncthreads();

    #pragma unroll
    for (int e = t; e < 400; e += 256) {
        const int s = e / 25, p = e - s * 25;
        const float w = __expf(aw_s[e] - mx_s[s]);
        wq_s[e] = w;
        const float cx = box_s[s][0], cy = box_s[s][1];
        const float sw = box_s[s][2], sh = box_s[s][3];
        const float ca = box_s[s][4], sa = box_s[s][5];
        const float fx = ki_s[p * 2 + 0] * sw;
        const float fy = ki_s[p * 2 + 1] * sh;
        const float gx = cx + ca * fx - sa * fy + dg_s[s * 50 + 2 * p + 0] * (1.f / 188.f);
        const float gy = cy + sa * fx + ca * fy + dg_s[s * 50 + 2 * p + 1] * (1.f / 188.f);
        const float x = gx * 128.f - 0.5f;
        const float y = gy * 128.f - 0.5f;
        const float x0f = floorf(x), y0f = floorf(y);
        const float lx = x - x0f, ly = y - y0f;
        const int x0 = (int)x0f, y0 = (int)y0f;
        #pragma unroll
        for (int c = 0; c < 4; ++c) {
            const int xi = x0 + (c & 1);
            const int yi = y0 + (c >> 1);
            const float wgt = ((c & 1) ? lx : 1.f - lx) * ((c >> 1) ? ly : 1.f - ly);
            const bool valid = (xi >= 0) & (xi < 128) & (yi >= 0) & (yi < 128);
            const int cxi = min(max(xi, 0), 127);
            const int cyi = min(max(yi, 0), 127);
            i4_s[e * 4 + c] = cyi * 128 + cxi;
            w4_s[e * 4 + c] = w * (valid ? wgt : 0.f);
        }
    }
    __syncthreads();

    // denominators overlap phase B; visibility guaranteed by the barrier below
    if (t < 16) {
        float sm = 0.f;
        #pragma unroll
        for (int p = 0; p < NP_; ++p) sm += wq_s[t * NP_ + p];
        inv_s[t] = 1.f / sm;
    }

    // phase B: 25 x 16B gathers per thread, one head-plane (L2-resident)
    {
        const int lane = t & 63;
        const int s_loc = t >> 4;            // 0..15
        const int j2 = (lane >> 2) & 3;      // corner stream
        const int q2 = lane & 3;             // 16B chunk of the 64B row
        const __hip_bfloat16* vb = vp + ((long long)(bb * 8 + h) * 16384) * 32 + q2 * 8;
        const int ebase = s_loc * 100;
        float a[8] = {0.f, 0.f, 0.f, 0.f, 0.f, 0.f, 0.f, 0.f};
        #pragma unroll
        for (int u = 0; u < 25; ++u) {
            const int ii = ebase + j2 + 4 * u;
            bf16x8 v = *(const bf16x8*)(vb + (long long)i4_s[ii] * 32);
            const float w = w4_s[ii];
            #pragma unroll
            for (int k = 0; k < 8; ++k) a[k] += w * (float)v[k];
        }
        #pragma unroll
        for (int k = 0; k < 8; ++k) a[k] += __shfl_xor(a[k], 4, 64);
        #pragma unroll
        for (int k = 0; k < 8; ++k) a[k] += __shfl_xor(a[k], 8, 64);
        __syncthreads();   // inv_s visible to all
        if (j2 == 0) {
            const float inv = inv_s[s_loc];
            __hip_bfloat16* op = boxout + (base + s_loc) * DIM + h * HD + q2 * 8;
            bf16x8 o;
            #pragma unroll
            for (int k = 0; k < 8; ++k) o[k] = __float2bfloat16(a[k] * inv);
            *(bf16x8*)op = o;
        }
    }
}

// ---------------- scatter final rows back into out ----------------
extern "C" __global__ __launch_bounds__(256)
void scatter_kernel(const int* __restrict__ idx, const float* __restrict__ sel,
                    float* __restrict__ out) {
    const int s = blockIdx.x, bb = blockIdx.y, t = threadIdx.x;
    const int i = idx[bb * NSEL + s];
    out[((long long)(bb * HW_N + i)) * DIM + t] = sel[((long long)(bb * NSEL + s)) * DIM + t];
}

extern "C" void kernel_launch(void* const* d_in, const int* in_sizes, int n_in,
                              void* d_out, int out_size, void* d_ws, size_t ws_size,
                              hipStream_t stream) {
    const float* src          = (const float*)d_in[0];
    const float* pos          = (const float*)d_in[1];
    const float* refw         = (const float*)d_in[4];
    const float* score        = (const float*)d_in[5];
    const float* in_proj_w    = (const float*)d_in[6];
    const float* in_proj_b    = (const float*)d_in[7];
    const float* mha_out_w    = (const float*)d_in[8];
    const float* mha_out_b    = (const float*)d_in[9];
    const float* value_proj_w = (const float*)d_in[10];
    const float* value_proj_b = (const float*)d_in[11];
    const float* lin_attn_w   = (const float*)d_in[12];
    const float* lin_attn_b   = (const float*)d_in[13];
    const float* lin_box_w    = (const float*)d_in[14];
    const float* lin_box_b    = (const float*)d_in[15];
    const float* samp_off_w   = (const float*)d_in[16];
    const float* samp_off_b   = (const float*)d_in[17];
    const float* ca_out_w     = (const float*)d_in[18];
    const float* ca_out_b     = (const float*)d_in[19];
    const float* lin1_w       = (const float*)d_in[20];
    const float* lin1_b       = (const float*)d_in[21];
    const float* lin2_w       = (const float*)d_in[22];
    const float* lin2_b       = (const float*)d_in[23];
    const float* qn_g         = (const float*)d_in[24];
    const float* qn_b         = (const float*)d_in[25];
    const float* n1_g         = (const float*)d_in[26];
    const float* n1_b         = (const float*)d_in[27];
    const float* n2_g         = (const float*)d_in[28];
    const float* n2_b         = (const float*)d_in[29];
    const float* kidx         = (const float*)d_in[30];

    float* w = (float*)d_ws;
    int* idxp = (int*)d_ws;
    float* selref = w + OFF_SELREF;
    float* selsrc = w + OFF_SELSRC;
    float* selpos = w + OFF_SELPOS;
    __hip_bfloat16* boxoutb = (__hip_bfloat16*)(w + OFF_SELPOS);  // reuse after selpos dead
    __hip_bfloat16* queryb  = (__hip_bfloat16*)(w + OFF_QUERY);   // bf16 query
    float* src2   = w + OFF_QUERY;    // reuse after queryb dead
    __hip_bfloat16* vproj  = (__hip_bfloat16*)(w + OFF_BIG);   // head-planar bf16
    __hip_bfloat16* ffntb  = (__hip_bfloat16*)(w + OFF_BIG);   // reuse after vproj dead
    __hip_bfloat16* wbf    = (__hip_bfloat16*)(w + OFF_WBF);   // bf16 weight pool
    // OFF_F multi-use region
    __hip_bfloat16* qkbin   = (__hip_bfloat16*)(w + OFF_F);            // qk bf16 (A of qkv gemm)
    __hip_bfloat16* selsrcb = (__hip_bfloat16*)(w + OFF_F + 262144);   // selsrc bf16 rows 0..NQ
    __hip_bfloat16* qkb = (__hip_bfloat16*)(w + OFF_F + 524288);       // qkv gemm out
    __hip_bfloat16* vT  = (__hip_bfloat16*)(w + OFF_F + 1572864);
    __hip_bfloat16* attoutb = (__hip_bfloat16*)(w + OFF_F + 2097152);  // attn out bf16
    float* q2     = w + OFF_F + 2621440;
    float* aw     = w + OFF_F;              // reuse after MHA dead
    float* obuf   = w + OFF_F + 1638400;
    float* dgrid  = w + OFF_F + 1900544;
    float* ff     = w + OFF_F;              // reuse after box-attn dead
    __hip_bfloat16* selsrcb2 = (__hip_bfloat16*)(w + OFF_F + 1048576); // n1-LN bf16 out (A of lin1)
    unsigned int* hist2 = (unsigned int*)(w + OFF_F);          // topk scratch
    unsigned int* ctrl2 = hist2 + 16384;
    unsigned long long* list1 = (unsigned long long*)(hist2 + 16448);
    unsigned long long* list2 = list1 + 2 * 2048;
    float* out    = (float*)d_out;

    // bf16 weight pool offsets
    const long long W_INPROJ = 0, W_MHAOUT = 196608, W_VALUE = 262144,
                    W_LATTN = 327680, W_LBOX = 378880, W_SOFF = 387072,
                    W_CAOUT = 489472, W_LIN1 = 555008, W_LIN2 = 817152;

    hipMemcpyAsync(d_out, src, (size_t)2 * HW_N * DIM * sizeof(float),
                   hipMemcpyDeviceToDevice, stream);

    wcvt_kernel<<<4216, 256, 0, stream>>>(in_proj_w, mha_out_w, value_proj_w,
                                          lin_attn_w, lin_box_w, samp_off_w,
                                          ca_out_w, lin1_w, lin2_w, wbf);

    hipMemsetAsync(hist2, 0, 16448 * sizeof(unsigned int), stream);
    topk_hist_kernel<<<dim3(32, 2), 512, 0, stream>>>(score, hist2);
    topk_scan_kernel<<<2, 1024, 0, stream>>>(hist2, ctrl2);
    topk_collect_kernel<<<dim3(16, 2), 1024, 0, stream>>>(score, ctrl2, list1, list2);
    topk_classify_kernel<<<dim3(16, 2), 1024, 0, stream>>>(score, ctrl2, list1, list2, idxp);

    gather_kernel<<<dim3(NSEL, 2), 256, 0, stream>>>(src, pos, refw, idxp,
                                                     selsrc, selpos, selref,
                                                     qkbin, selsrcb);
    gemm_kernel<<<dim3(8, 16, 2), 256, 0, stream>>>(qkbin, 262144LL, wbf + W_INPROJ, in_proj_b,
                                                    (float*)qkb, 524288LL, NQ, 512, 256, 0, 1, 1);
    gemm_kernel<<<dim3(4, 16, 2), 256, 0, stream>>>(selsrcb, 262144LL, wbf + W_INPROJ + 512 * 256,
                                                    in_proj_b + 512, (float*)vT, 262144LL, NQ, 256, 256, 0, 2, 1);
    attn_kernel<<<dim3(64, 8, 2), 256, 0, stream>>>(qkb, vT, attoutb);
    gemm_kernel<<<dim3(4, 16, 2), 256, 0, stream>>>(attoutb, 262144LL, wbf + W_MHAOUT, mha_out_b,
                                                    q2, 262144LL, NQ, 256, 256, 0, 0, 1);
    ln_kernel<<<dim3(NQ, 2), 256, 0, stream>>>(selsrc, 1048576LL, q2, 262144LL,
                                               qn_g, qn_b, selsrc, 1048576LL, nullptr);
    addq_kernel<<<8192, 256, 0, stream>>>(selsrc, selpos, queryb);
    gemm_kernel<<<dim3(4, 256, 2), 256, 0, stream>>>(src, 4194304LL, wbf + W_VALUE, value_proj_b,
                                                     (float*)vproj, 4194304LL, HW_N, 256, 256, 0, 3, 0);
    gemm_kernel<<<dim3(4, 64, 2), 256, 0, stream>>>(queryb, 1048576LL, wbf + W_LATTN, lin_attn_b,
                                                    aw, 819200LL, NSEL, 200, 256, 0, 0, 1);
    gemm_kernel<<<dim3(1, 64, 2), 256, 0, stream>>>(queryb, 1048576LL, wbf + W_LBOX, lin_box_b,
                                                    obuf, 131072LL, NSEL, 32, 256, 0, 0, 1);
    gemm_kernel<<<dim3(7, 64, 2), 256, 0, stream>>>(queryb, 1048576LL, wbf + W_SOFF, samp_off_b,
                                                    dgrid, 1638400LL, NSEL, 400, 256, 0, 0, 1);
    boxattn_kernel<<<dim3(16, 256), 256, 0, stream>>>(aw, obuf, dgrid, selref, vproj, kidx, boxoutb);
    gemm_kernel<<<dim3(4, 64, 2), 256, 0, stream>>>(boxoutb, 1048576LL, wbf + W_CAOUT, ca_out_b,
                                                    src2, 1048576LL, NSEL, 256, 256, 0, 0, 1);
    ln_kernel<<<dim3(NSEL, 2), 256, 0, stream>>>(selsrc, 1048576LL, src2, 1048576LL,
                                                 n1_g, n1_b, selsrc, 1048576LL, selsrcb2);
    gemm_kernel<<<dim3(16, 64, 2), 256, 0, stream>>>(selsrcb2, 1048576LL, wbf + W_LIN1, lin1_b,
                                                     (float*)ffntb, 4194304LL, NSEL, DFF_, 256, 1, 1, 1);
    gemm_kernel<<<dim3(4, 64, 2), 256, 0, stream>>>(ffntb, 4194304LL, wbf + W_LIN2, lin2_b,
                                                    ff, 1048576LL, NSEL, 256, DFF_, 0, 0, 1);
    ln_kernel<<<dim3(NSEL, 2), 256, 0, stream>>>(selsrc, 1048576LL, ff, 1048576LL,
                                                 n2_g, n2_b, selsrc, 1048576LL, nullptr);
    scatter_kernel<<<dim3(NSEL, 2), 256, 0, stream>>>(idxp, selsrc, out);
}